// Round 2
// baseline (641.418 us; speedup 1.0000x reference)
//
#include <hip/hip_runtime.h>

// SimplifiedHAFE on MI355X — round 8: algebraic fusion of the FE tail.
//  (a) k_fe2 DELETED: hfe is affine in t1, so W2@outw is folded into the
//      GAT-1 projection B-matrices (precomputed by k_fuse1/k_fuse2 into
//      frag-order bf16) and the (type,pos,bias) terms become per-node add
//      tables applied in k_prep's epilogue.
//  (b) bf16 intermediates: k_fe1 writes t1 as bf16, k_gat1 writes hid1 as
//      bf16 (their only consumers are MFMA kernels that quantized anyway).
//      k_prep A-staging is now conversion-free uint4 copies.
//  (c) k_fe1 fp32->bf16 pack via v_cvt_pk_bf16_f32 (1 VALU per pair, was 3).
//  (d) Round-7 wide gathers retained in k_gat1/k_gat2.

#define LRELU(x) ((x) > 0.f ? (x) : 0.2f * (x))

typedef __attribute__((ext_vector_type(8))) short short8;
typedef __attribute__((ext_vector_type(4))) float floatx4;

__device__ __forceinline__ unsigned short f2bf(float x) {
    union { float f; unsigned int u; } v; v.f = x;
    unsigned int r = (v.u + 0x7FFFu + ((v.u >> 16) & 1u)) >> 16;  // RNE
    return (unsigned short)r;
}
// pack 2 fp32 -> 2 bf16 (RNE) in one VALU
__device__ __forceinline__ unsigned int cvtpk(float lo, float hi) {
    unsigned int r;
    asm("v_cvt_pk_bf16_f32 %0, %1, %2" : "=v"(r) : "v"(lo), "v"(hi));
    return r;
}
__device__ __forceinline__ float bflo(unsigned int u) {
    return __uint_as_float(u << 16);
}
__device__ __forceinline__ float bfhi(unsigned int u) {
    return __uint_as_float(u & 0xFFFF0000u);
}
__device__ __forceinline__ float bf1(unsigned short u) {
    return __uint_as_float(((unsigned int)u) << 16);
}

// ---------------------------------------------------------------- tiny tables
__global__ __launch_bounds__(64) void k_tables(
    const float* __restrict__ e_emb1, const float* __restrict__ lew1,
    const float* __restrict__ ae1,
    const float* __restrict__ e_emb2, const float* __restrict__ lew2,
    const float* __restrict__ ae2,
    float* __restrict__ aet1, float* __restrict__ aet2)
{
    __shared__ float M1[16];
    __shared__ float M2[4];
    int t = threadIdx.x;
    if (t < 16) {
        int d = t >> 2, h = t & 3;
        float s = 0.f;
        for (int c = 0; c < 64; ++c) s += lew1[d * 256 + h * 64 + c] * ae1[h * 64 + c];
        M1[d * 4 + h] = s;
    }
    if (t < 4) {
        float s = 0.f;
        for (int c = 0; c < 64; ++c) s += lew2[t * 64 + c] * ae2[c];
        M2[t] = s;
    }
    __syncthreads();
    if (t < 16) {
        int ty = t >> 2, h = t & 3;
        float s = 0.f;
        for (int d = 0; d < 4; ++d) s += e_emb1[ty * 4 + d] * M1[d * 4 + h];
        aet1[ty * 4 + h] = s;
    }
    if (t < 4) {
        float s = 0.f;
        for (int d = 0; d < 4; ++d) s += e_emb2[t * 4 + d] * M2[d];
        aet2[t] = s;
    }
}

// ----------------- B pre-swizzle: fe1 weight (768x64) -> frag-order bf16
__global__ __launch_bounds__(256) void k_bswz_fe1(
    const float* __restrict__ w1, unsigned short* __restrict__ out)
{
    for (int idx = blockIdx.x * 256 + threadIdx.x; idx < 768 * 64;
         idx += gridDim.x * 256) {
        int k = idx >> 6, col = idx & 63;
        int c = k >> 6, kl = k & 63, kg = kl >> 3, j = kl & 7;
        out[((c * 8 + kg) * 64 + col) * 8 + j] = f2bf(w1[k * 64 + col]);
    }
}

// --------- B pre-swizzle: concat [B1|B2] (Kx2NH) -> frag-order, 128-col tiles
template<int K, int NH>
__global__ __launch_bounds__(256) void k_bswz2(
    const float* __restrict__ B1, const float* __restrict__ B2,
    unsigned short* __restrict__ out)
{
    const int NC = 2 * NH;
    for (int idx = blockIdx.x * 256 + threadIdx.x; idx < K * NC;
         idx += gridDim.x * 256) {
        int k = idx / NC, col = idx % NC;
        float v = (col < NH) ? B1[k * NH + col] : B2[k * NH + col - NH];
        int c = k >> 6, kl = k & 63, kg = kl >> 3, j = kl & 7;
        int ct = col >> 7, cl = col & 127;
        out[(((c * (NC / 128) + ct) * 8 + kg) * 128 + cl) * 8 + j] = f2bf(v);
    }
}

// ---- fuse stage 1: W2p = fe_w2 @ fe_out_w (64x64) + affine add-vectors
//   h0 = (b2+posb)@outw + outb ; tadd[ty] = temb[ty]@outw ; padd = posw@outw
__global__ __launch_bounds__(256) void k_fuse1(
    const float* __restrict__ w2, const float* __restrict__ outw,
    const float* __restrict__ b2, const float* __restrict__ posb,
    const float* __restrict__ outb, const float* __restrict__ temb,
    const float* __restrict__ posw,
    float* __restrict__ W2p, float* __restrict__ h0,
    float* __restrict__ tadd, float* __restrict__ padd)
{
    int t = threadIdx.x;
    int i = t >> 2, jq = (t & 3) * 16;
    float a16[16];
#pragma unroll
    for (int u = 0; u < 16; ++u) a16[u] = 0.f;
    for (int k = 0; k < 64; ++k) {
        float a = w2[i * 64 + k];
        const float* op = outw + k * 64 + jq;
        float4 o0 = *(const float4*)op;
        float4 o1 = *(const float4*)(op + 4);
        float4 o2 = *(const float4*)(op + 8);
        float4 o3 = *(const float4*)(op + 12);
        a16[0] += a * o0.x;  a16[1] += a * o0.y;  a16[2] += a * o0.z;  a16[3] += a * o0.w;
        a16[4] += a * o1.x;  a16[5] += a * o1.y;  a16[6] += a * o1.z;  a16[7] += a * o1.w;
        a16[8] += a * o2.x;  a16[9] += a * o2.y;  a16[10] += a * o2.z; a16[11] += a * o2.w;
        a16[12] += a * o3.x; a16[13] += a * o3.y; a16[14] += a * o3.z; a16[15] += a * o3.w;
    }
#pragma unroll
    for (int u = 0; u < 16; ++u) W2p[i * 64 + jq + u] = a16[u];
    for (int e = t; e < 320; e += 256) {
        int g = e >> 6, j = e & 63;
        float s = 0.f;
        for (int k = 0; k < 64; ++k) {
            float v;
            if (g == 0) v = b2[k] + posb[k];
            else if (g <= 3) v = temb[(g - 1) * 64 + k];
            else v = posw[k];
            s += v * outw[k * 64 + j];
        }
        if (g == 0) h0[j] = s + outb[j];
        else if (g <= 3) tadd[(g - 1) * 64 + j] = s;
        else padd[j] = s;
    }
}

// ---- fuse stage 2: BLR = W2p @ [lin_w|res_w] -> frag-order bf16 (64x512),
//      plus projected add tables C0[512], T[3][512], P[512].
__global__ __launch_bounds__(64) void k_fuse2(
    const float* __restrict__ W2p, const float* __restrict__ h0,
    const float* __restrict__ tadd, const float* __restrict__ padd,
    const float* __restrict__ lin_w, const float* __restrict__ res_w,
    const float* __restrict__ bias, const float* __restrict__ res_b,
    unsigned short* __restrict__ bz, float* __restrict__ C0,
    float* __restrict__ T, float* __restrict__ P)
{
    __shared__ float bcol[64];
    int c = blockIdx.x;           // 0..511
    int j = threadIdx.x;          // 0..63
    int cL = c & 255;
    const float* Bsrc = (c < 256) ? lin_w : res_w;
    float bv = Bsrc[j * 256 + cL];
    bcol[j] = bv;
    __syncthreads();
    float s = 0.f;
#pragma unroll 8
    for (int k = 0; k < 64; ++k) s += W2p[j * 64 + k] * bcol[k];
    int kg = j >> 3, jj = j & 7, ct = c >> 7, cl = c & 127;
    bz[((ct * 8 + kg) * 128 + cl) * 8 + jj] = f2bf(s);
    float pc = h0[j] * bv;
    float p0 = tadd[j] * bv, p1 = tadd[64 + j] * bv, p2 = tadd[128 + j] * bv;
    float pp = padd[j] * bv;
#pragma unroll
    for (int k = 32; k; k >>= 1) {
        pc += __shfl_xor(pc, k, 64); p0 += __shfl_xor(p0, k, 64);
        p1 += __shfl_xor(p1, k, 64); p2 += __shfl_xor(p2, k, 64);
        pp += __shfl_xor(pp, k, 64);
    }
    if (j == 0) {
        C0[c] = pc + ((c >= 256) ? (bias[cL] + res_b[cL]) : 0.f);
        T[c] = p0; T[512 + c] = p1; T[1024 + c] = p2;
        P[c] = pp;
    }
}

// ------------------ FE stage 1: relu(X@W1+b1) -> bf16, pre-swizzled B
__global__ __launch_bounds__(256) void k_fe1(
    const float* __restrict__ feat, const unsigned short* __restrict__ bswz,
    const float* __restrict__ b1, unsigned short* __restrict__ t1b, int N)
{
    __shared__ __align__(16) unsigned short A_lds[8 * 64 * 8];  // 8 KiB
    int t = threadIdx.x;
    int wv = t >> 6, lane = t & 63;
    int quad = lane >> 4, l16 = lane & 15;
    long n0 = (long)blockIdx.x * 64;

    floatx4 acc[4];
#pragma unroll
    for (int i = 0; i < 4; ++i) acc[i] = (floatx4){0.f, 0.f, 0.f, 0.f};

    int srow = t >> 2, sf4 = t & 3;
    long arow = n0 + srow;
    if (arow >= N) arow = N - 1;
    const float* fbase = feat + arow * 768 + sf4 * 16;
    int col = wv * 16 + l16;

    float4 v0 = *(const float4*)(fbase);
    float4 v1 = *(const float4*)(fbase + 4);
    float4 v2 = *(const float4*)(fbase + 8);
    float4 v3 = *(const float4*)(fbase + 12);

    for (int kc = 0; kc < 768; kc += 64) {
        uint4 w0 = {cvtpk(v0.x, v0.y), cvtpk(v0.z, v0.w),
                    cvtpk(v1.x, v1.y), cvtpk(v1.z, v1.w)};
        uint4 w1p = {cvtpk(v2.x, v2.y), cvtpk(v2.z, v2.w),
                     cvtpk(v3.x, v3.y), cvtpk(v3.z, v3.w)};
        __syncthreads();
        *(uint4*)&A_lds[((2 * sf4) * 64 + srow) * 8] = w0;
        *(uint4*)&A_lds[((2 * sf4 + 1) * 64 + srow) * 8] = w1p;
        if (kc + 64 < 768) {
            v0 = *(const float4*)(fbase + kc + 64);
            v1 = *(const float4*)(fbase + kc + 68);
            v2 = *(const float4*)(fbase + kc + 72);
            v3 = *(const float4*)(fbase + kc + 76);
        }
        __syncthreads();
        int ci = kc >> 6;
#pragma unroll
        for (int s = 0; s < 2; ++s) {
            int kg0 = s * 4 + quad;
            short8 bfrag = *(const short8*)&bswz[((ci * 8 + kg0) * 64 + col) * 8];
#pragma unroll
            for (int mt = 0; mt < 4; ++mt) {
                short8 afrag = *(const short8*)&A_lds[(kg0 * 64 + mt * 16 + l16) * 8];
                acc[mt] = __builtin_amdgcn_mfma_f32_16x16x32_bf16(
                    afrag, bfrag, acc[mt], 0, 0, 0);
            }
        }
    }
    float bb = b1[col];
#pragma unroll
    for (int mt = 0; mt < 4; ++mt) {
#pragma unroll
        for (int r = 0; r < 4; ++r) {
            long m = n0 + mt * 16 + quad * 4 + r;
            if (m < N) t1b[m * 64 + col] = f2bf(fmaxf(acc[mt][r] + bb, 0.f));
        }
    }
}

// ------- prep GEMM: bf16 A[NxK] @ preswizzled B[Kx2NH] -> xs bf16 + res fp32
// FADD: epilogue adds C0[gc] + T[nt[m]][gc] + pos[m]*P[gc] (fused fe2 tail).
// else: res path adds bias+res_b.
template<int K, int NH, bool FADD>
__global__ __launch_bounds__(256) void k_prep(
    const unsigned short* __restrict__ A, const unsigned short* __restrict__ bswz,
    const float* __restrict__ c0_or_bias, const float* __restrict__ t_or_resb,
    const float* __restrict__ Ptab, const int* __restrict__ ntypes,
    const float* __restrict__ pos,
    unsigned short* __restrict__ xsb, float* __restrict__ resp, int N)
{
    constexpr int CT = (2 * NH) / 128;
    __shared__ __align__(16) unsigned short A_lds[8 * 64 * 8];  // 8 KB
    int t = threadIdx.x;
    int wv = t >> 6, lane = t & 63;
    int quad = lane >> 4, l16 = lane & 15;
    long n0 = (long)blockIdx.x * 64;
    int by = blockIdx.y;

    floatx4 acc[4][2];
#pragma unroll
    for (int i = 0; i < 4; ++i)
#pragma unroll
        for (int j = 0; j < 2; ++j) acc[i][j] = (floatx4){0.f, 0.f, 0.f, 0.f};

    int srow = t >> 2, sf4 = t & 3;
    long arow = n0 + srow;
    if (arow >= N) arow = N - 1;
    const unsigned short* abase = A + arow * (long)K + sf4 * 16;

    uint4 q0 = *(const uint4*)(abase);
    uint4 q1 = *(const uint4*)(abase + 8);

    for (int kc = 0; kc < K; kc += 64) {
        __syncthreads();
        *(uint4*)&A_lds[((2 * sf4) * 64 + srow) * 8] = q0;
        *(uint4*)&A_lds[((2 * sf4 + 1) * 64 + srow) * 8] = q1;
        if (kc + 64 < K) {
            q0 = *(const uint4*)(abase + kc + 64);
            q1 = *(const uint4*)(abase + kc + 64 + 8);
        }
        __syncthreads();
        int ci = kc >> 6;
#pragma unroll
        for (int s = 0; s < 2; ++s) {
            int kg0 = s * 4 + quad;
#pragma unroll
            for (int nt = 0; nt < 2; ++nt) {
                short8 bfrag = *(const short8*)&bswz[
                    (((ci * CT + by) * 8 + kg0) * 128 + wv * 32 + nt * 16 + l16) * 8];
#pragma unroll
                for (int mt = 0; mt < 4; ++mt) {
                    short8 afrag = *(const short8*)&A_lds[(kg0 * 64 + mt * 16 + l16) * 8];
                    acc[mt][nt] = __builtin_amdgcn_mfma_f32_16x16x32_bf16(
                        afrag, bfrag, acc[mt][nt], 0, 0, 0);
                }
            }
        }
    }

    int nta[4][4];
    float posa[4][4];
    if constexpr (FADD) {
#pragma unroll
        for (int mt = 0; mt < 4; ++mt)
#pragma unroll
            for (int r = 0; r < 4; ++r) {
                long m = n0 + mt * 16 + quad * 4 + r;
                if (m < N) { nta[mt][r] = ntypes[m]; posa[mt][r] = pos[m]; }
                else       { nta[mt][r] = 0; posa[mt][r] = 0.f; }
            }
    }
#pragma unroll
    for (int nt = 0; nt < 2; ++nt) {
        int gc = by * 128 + wv * 32 + nt * 16 + l16;
        bool isl = gc < NH;
        int oc = isl ? gc : gc - NH;
        if constexpr (FADD) {
            float c0 = c0_or_bias[gc];
            float pcf = Ptab[gc];
#pragma unroll
            for (int mt = 0; mt < 4; ++mt) {
#pragma unroll
                for (int r = 0; r < 4; ++r) {
                    long m = n0 + mt * 16 + quad * 4 + r;
                    if (m < N) {
                        float val = acc[mt][nt][r] + c0 +
                                    t_or_resb[nta[mt][r] * (2 * NH) + gc] +
                                    posa[mt][r] * pcf;
                        if (isl) xsb[m * NH + oc] = f2bf(val);
                        else     resp[m * NH + oc] = val;
                    }
                }
            }
        } else {
            float badd = isl ? 0.f : (c0_or_bias[oc] + t_or_resb[oc]);
#pragma unroll
            for (int mt = 0; mt < 4; ++mt) {
#pragma unroll
                for (int r = 0; r < 4; ++r) {
                    long m = n0 + mt * 16 + quad * 4 + r;
                    if (m < N) {
                        float val = acc[mt][nt][r];
                        if (isl) xsb[m * NH + oc] = f2bf(val);
                        else     resp[m * NH + oc] = val + badd;
                    }
                }
            }
        }
    }
}

// --------- attention scalars: a_src/a_dst[n,h] = dot(xs[n,h*64:+64], att)
template<int H>
__global__ __launch_bounds__(256) void k_att(
    const unsigned short* __restrict__ xsb, const float* __restrict__ att_s,
    const float* __restrict__ att_d, float* __restrict__ a_src,
    float* __restrict__ a_dst, int N)
{
    int t = threadIdx.x;
    int wv = t >> 6, lane = t & 63;
    long n = (long)blockIdx.x * 4 + wv;
    if (n >= N) return;
    if (H == 4) {
        ushort4 u = *(const ushort4*)&xsb[n * 256 + lane * 4];
        float4 as = *(const float4*)&att_s[lane * 4];
        float4 ad = *(const float4*)&att_d[lane * 4];
        float x0 = bf1(u.x), x1 = bf1(u.y), x2 = bf1(u.z), x3 = bf1(u.w);
        float p = x0 * as.x + x1 * as.y + x2 * as.z + x3 * as.w;
        float q = x0 * ad.x + x1 * ad.y + x2 * ad.z + x3 * ad.w;
#pragma unroll
        for (int k = 8; k; k >>= 1) {
            p += __shfl_xor(p, k, 64);
            q += __shfl_xor(q, k, 64);
        }
        if ((lane & 15) == 0) {
            a_src[n * 4 + (lane >> 4)] = p;
            a_dst[n * 4 + (lane >> 4)] = q;
        }
    } else {
        float x = bf1(xsb[n * 64 + lane]);
        float p = x * att_s[lane];
        float q = x * att_d[lane];
#pragma unroll
        for (int k = 32; k; k >>= 1) {
            p += __shfl_xor(p, k, 64);
            q += __shfl_xor(q, k, 64);
        }
        if (lane == 0) { a_src[n] = p; a_dst[n] = q; }
    }
}

// ---------------------------------------------------------------- CSR build
__global__ __launch_bounds__(256) void k_count(
    const int* __restrict__ dst, const int* __restrict__ et,
    int* __restrict__ cnt_t, int E)
{
    int e = blockIdx.x * 256 + threadIdx.x;
    if (e < E) atomicAdd(&cnt_t[dst[e] * 4 + et[e]], 1);
}

__global__ __launch_bounds__(256) void k_scan1(
    const int* __restrict__ cnt_t, int* __restrict__ row_off,
    int* __restrict__ blk_sums, int N)
{
    __shared__ int s[256];
    int t = threadIdx.x;
    int i = blockIdx.x * 256 + t;
    int v = 0;
    if (i < N) v = cnt_t[4 * i] + cnt_t[4 * i + 1] + cnt_t[4 * i + 2] + cnt_t[4 * i + 3];
    s[t] = v;
    __syncthreads();
    for (int off = 1; off < 256; off <<= 1) {
        int x = 0;
        if (t >= off) x = s[t - off];
        __syncthreads();
        s[t] += x;
        __syncthreads();
    }
    if (i < N) row_off[i] = s[t] - v;
    if (t == 255) blk_sums[blockIdx.x] = s[255];
}

__global__ __launch_bounds__(256) void k_scan2(int* __restrict__ blk_sums, int nb)
{
    __shared__ int s[256];
    int t = threadIdx.x;
    int v = (t < nb) ? blk_sums[t] : 0;
    s[t] = v;
    __syncthreads();
    for (int off = 1; off < 256; off <<= 1) {
        int x = 0;
        if (t >= off) x = s[t - off];
        __syncthreads();
        s[t] += x;
        __syncthreads();
    }
    if (t < nb) blk_sums[t] = s[t] - v;
}

__global__ __launch_bounds__(256) void k_scan3(
    int* __restrict__ row_off, int* __restrict__ cursor,
    const int* __restrict__ blk_sums, int N, int E)
{
    int t = threadIdx.x;
    int i = blockIdx.x * 256 + t;
    if (i < N) {
        int o = row_off[i] + blk_sums[blockIdx.x];
        row_off[i] = o;
        cursor[i] = o;
    }
    if (i == 0) row_off[N] = E;
}

__global__ __launch_bounds__(256) void k_scatter(
    const int* __restrict__ src, const int* __restrict__ dst,
    const int* __restrict__ et, int* __restrict__ cursor,
    int* __restrict__ csr_pack, int E)
{
    int e = blockIdx.x * 256 + threadIdx.x;
    if (e < E) {
        int d = dst[e];
        int pos = atomicAdd(&cursor[d], 1);
        csr_pack[pos] = src[e] | (et[e] << 28);
    }
}

// ---------------- GAT layer 1: 128 thr = 2 waves; wave w owns heads 2w,2w+1.
// Reads residual rp1 fp32, writes hid1 bf16 (only consumer is k_prep<256,64>).
__global__ __launch_bounds__(128) void k_gat1(
    const unsigned short* __restrict__ xs1b, const float* __restrict__ a_src,
    const float* __restrict__ a_dst, const int* __restrict__ row_off,
    const int* __restrict__ csr_pack,
    const int* __restrict__ cnt_t, const float* __restrict__ aet1,
    const float* __restrict__ ln_g, const float* __restrict__ ln_b,
    const float* __restrict__ res, unsigned short* __restrict__ out)
{
    __shared__ __align__(16) float4 ws[2][64];
    __shared__ float2 aetp[2][4];
    __shared__ float red[4];
    int n = blockIdx.x;
    int t = threadIdx.x;
    int w = t >> 6, c = t & 63;
    int lc = c & 15, g = c >> 4;
    int h0 = 2 * w;
    if (t < 8) {
        int w2 = t >> 2, ty = t & 3;
        aetp[w2][ty] = make_float2(aet1[ty * 4 + 2 * w2], aet1[ty * 4 + 2 * w2 + 1]);
    }
    int off = row_off[n], deg = row_off[n + 1] - off;
    float2 a_d = *(const float2*)&a_dst[n * 4 + h0];
    __syncthreads();
    float ael0 = 0.f, ael1 = 0.f;
    int degc = 0;
#pragma unroll
    for (int ty = 0; ty < 4; ++ty) {
        int ct = cnt_t[n * 4 + ty];
        degc += ct;
        float2 ae = aetp[w][ty];
        ael0 += (float)ct * ae.x;
        ael1 += (float)ct * ae.y;
    }
    float inv = (degc > 0) ? 1.f / (float)degc : 1.f;
    float2 a_s_self = *(const float2*)&a_src[n * 4 + h0];
    float al0 = a_s_self.x + a_d.x + ael0 * inv;
    float al1 = a_s_self.y + a_d.y + ael1 * inv;
    al0 = LRELU(al0); al1 = LRELU(al1);
    float wself0 = expf(al0), wself1 = expf(al1);

    int col0 = w * 128 + lc * 8;                    // 8 cols per lane
    const unsigned short* xrow = xs1b + col0;       // + s*256 per gather
    float acc[8];
#pragma unroll
    for (int j = 0; j < 8; ++j) acc[j] = 0.f;
    float dp0 = 0.f, dp1 = 0.f;

    for (int base = 0; base < deg; base += 64) {
        int cnt = min(64, deg - base);
        float w0 = 0.f, w1 = 0.f;
        int s = 0;
        if (c < cnt) {
            int pk = csr_pack[off + base + c];
            s = pk & 0x0FFFFFFF;
            int ty = ((unsigned)pk) >> 28;
            float2 as2 = *(const float2*)&a_src[s * 4 + h0];
            float2 ae = aetp[w][ty];
            float a0 = as2.x + a_d.x + ae.x;
            float a1 = as2.y + a_d.y + ae.y;
            a0 = LRELU(a0); a1 = LRELU(a1);
            w0 = expf(a0); w1 = expf(a1);
        }
        dp0 += w0; dp1 += w1;
        ws[w][c] = make_float4(w0, w1, __int_as_float(s), 0.f);
        int cr = (cnt + 7) & ~7;
        for (int i = 0; i < cr; i += 8) {
#pragma unroll
            for (int u = 0; u < 2; ++u) {
                float4 p = ws[w][i + u * 4 + g];
                float wl = (lc < 8) ? p.x : p.y;
                uint4 q = *(const uint4*)&xrow[(long)__float_as_int(p.z) * 256];
                acc[0] += wl * bflo(q.x); acc[1] += wl * bfhi(q.x);
                acc[2] += wl * bflo(q.y); acc[3] += wl * bfhi(q.y);
                acc[4] += wl * bflo(q.z); acc[5] += wl * bfhi(q.z);
                acc[6] += wl * bflo(q.w); acc[7] += wl * bfhi(q.w);
            }
        }
    }
#pragma unroll
    for (int k = 32; k; k >>= 1) {
        dp0 += __shfl_xor(dp0, k, 64);
        dp1 += __shfl_xor(dp1, k, 64);
    }
#pragma unroll
    for (int j = 0; j < 8; ++j) {
        acc[j] += __shfl_xor(acc[j], 16, 64);
        acc[j] += __shfl_xor(acc[j], 32, 64);
    }
    uint4 us = *(const uint4*)&xrow[(long)n * 256];
    float wself_l = (lc < 8) ? wself0 : wself1;
    acc[0] += wself_l * bflo(us.x); acc[1] += wself_l * bfhi(us.x);
    acc[2] += wself_l * bflo(us.y); acc[3] += wself_l * bfhi(us.y);
    acc[4] += wself_l * bflo(us.z); acc[5] += wself_l * bfhi(us.z);
    acc[6] += wself_l * bflo(us.w); acc[7] += wself_l * bfhi(us.w);
    float dsum = ((lc < 8) ? dp0 + wself0 : dp1 + wself1) + 1e-16f;
    float rd = 1.f / dsum;
    float4 r0 = *(const float4*)&res[(long)n * 256 + col0];
    float4 r1 = *(const float4*)&res[(long)n * 256 + col0 + 4];
    float v[8];
    v[0] = acc[0] * rd + r0.x; v[1] = acc[1] * rd + r0.y;
    v[2] = acc[2] * rd + r0.z; v[3] = acc[3] * rd + r0.w;
    v[4] = acc[4] * rd + r1.x; v[5] = acc[5] * rd + r1.y;
    v[6] = acc[6] * rd + r1.z; v[7] = acc[7] * rd + r1.w;
    float s1 = 0.f, s2 = 0.f;
#pragma unroll
    for (int j = 0; j < 8; ++j) { s1 += v[j]; s2 += v[j] * v[j]; }
#pragma unroll
    for (int k = 32; k; k >>= 1) {
        s1 += __shfl_xor(s1, k, 64);
        s2 += __shfl_xor(s2, k, 64);
    }
    if (c == 0) { red[w] = s1 * 0.25f; red[2 + w] = s2 * 0.25f; }
    __syncthreads();
    float mu = (red[0] + red[1]) * (1.f / 256.f);
    float var = (red[2] + red[3]) * (1.f / 256.f) - mu * mu;
    float rs = rsqrtf(var + 1e-5f);
    if (g == 0) {
        float4 lg0 = *(const float4*)&ln_g[col0];
        float4 lg1 = *(const float4*)&ln_g[col0 + 4];
        float4 lb0 = *(const float4*)&ln_b[col0];
        float4 lb1 = *(const float4*)&ln_b[col0 + 4];
        float y[8];
        y[0] = fmaxf((v[0] - mu) * rs * lg0.x + lb0.x, 0.f);
        y[1] = fmaxf((v[1] - mu) * rs * lg0.y + lb0.y, 0.f);
        y[2] = fmaxf((v[2] - mu) * rs * lg0.z + lb0.z, 0.f);
        y[3] = fmaxf((v[3] - mu) * rs * lg0.w + lb0.w, 0.f);
        y[4] = fmaxf((v[4] - mu) * rs * lg1.x + lb1.x, 0.f);
        y[5] = fmaxf((v[5] - mu) * rs * lg1.y + lb1.y, 0.f);
        y[6] = fmaxf((v[6] - mu) * rs * lg1.z + lb1.z, 0.f);
        y[7] = fmaxf((v[7] - mu) * rs * lg1.w + lb1.w, 0.f);
        uint4 o;
        o.x = cvtpk(y[0], y[1]); o.y = cvtpk(y[2], y[3]);
        o.z = cvtpk(y[4], y[5]); o.w = cvtpk(y[6], y[7]);
        *(uint4*)&out[(long)n * 256 + col0] = o;
    }
}

// --------------------------------- GAT layer 2 (H=1, C=64): one wave per node
__global__ __launch_bounds__(64) void k_gat2(
    const unsigned short* __restrict__ xs2b, const float* __restrict__ a_src,
    const float* __restrict__ a_dst, const int* __restrict__ row_off,
    const int* __restrict__ csr_pack,
    const int* __restrict__ cnt_t, const float* __restrict__ aet2,
    const float* __restrict__ ln_g, const float* __restrict__ ln_b,
    float* io)
{
    __shared__ __align__(8) float2 ws[64];
    __shared__ float aetl[4];
    int n = blockIdx.x;
    int c = threadIdx.x;
    int lc = c & 15, g = c >> 4;
    if (c < 4) aetl[c] = aet2[c];
    int off = row_off[n], deg = row_off[n + 1] - off;
    float a_d = a_dst[n];
    float ael = 0.f;
    int degc = 0;
#pragma unroll
    for (int ty = 0; ty < 4; ++ty) {
        int ct = cnt_t[n * 4 + ty];
        degc += ct;
        ael += (float)ct * aet2[ty];
    }
    ael *= (degc > 0 ? 1.f / (float)degc : 1.f);
    float al = a_src[n] + a_d + ael;
    al = LRELU(al);
    float wself = expf(al);

    int colb = lc * 4;
    const unsigned short* xrow = xs2b + colb;
    float acc[4] = {0.f, 0.f, 0.f, 0.f};
    float dp = 0.f;
    for (int base = 0; base < deg; base += 64) {
        int cnt = min(64, deg - base);
        float we = 0.f;
        int s = 0;
        if (c < cnt) {
            int pk = csr_pack[off + base + c];
            s = pk & 0x0FFFFFFF;
            int ty = ((unsigned)pk) >> 28;
            float a = a_src[s] + a_d + aetl[ty];
            a = LRELU(a);
            we = expf(a);
        }
        dp += we;
        ws[c] = make_float2(we, __int_as_float(s));
        int cr = (cnt + 7) & ~7;
        for (int i = 0; i < cr; i += 8) {
#pragma unroll
            for (int u = 0; u < 2; ++u) {
                float2 p = ws[i + u * 4 + g];
                uint2 q = *(const uint2*)&xrow[(long)__float_as_int(p.y) * 64];
                acc[0] += p.x * bflo(q.x); acc[1] += p.x * bfhi(q.x);
                acc[2] += p.x * bflo(q.y); acc[3] += p.x * bfhi(q.y);
            }
        }
    }
#pragma unroll
    for (int k = 32; k; k >>= 1) dp += __shfl_xor(dp, k, 64);
#pragma unroll
    for (int j = 0; j < 4; ++j) {
        acc[j] += __shfl_xor(acc[j], 16, 64);
        acc[j] += __shfl_xor(acc[j], 32, 64);
    }
    uint2 us = *(const uint2*)&xrow[(long)n * 64];
    acc[0] += wself * bflo(us.x); acc[1] += wself * bfhi(us.x);
    acc[2] += wself * bflo(us.y); acc[3] += wself * bfhi(us.y);
    float dsum = dp + wself + 1e-16f;
    float rd = 1.f / dsum;
    float4 r = *(const float4*)&io[(long)n * 64 + colb];
    float v[4];
    v[0] = acc[0] * rd + r.x; v[1] = acc[1] * rd + r.y;
    v[2] = acc[2] * rd + r.z; v[3] = acc[3] * rd + r.w;
    float s1 = v[0] + v[1] + v[2] + v[3];
    float s2 = v[0] * v[0] + v[1] * v[1] + v[2] * v[2] + v[3] * v[3];
#pragma unroll
    for (int k = 32; k; k >>= 1) {
        s1 += __shfl_xor(s1, k, 64);
        s2 += __shfl_xor(s2, k, 64);
    }
    float mu = s1 * (1.f / 256.f);
    float var = s2 * (1.f / 256.f) - mu * mu;
    float rs = rsqrtf(var + 1e-5f);
    if (g == 0) {
        float4 lg = *(const float4*)&ln_g[colb];
        float4 lb = *(const float4*)&ln_b[colb];
        float4 y;
        y.x = (v[0] - mu) * rs * lg.x + lb.x;
        y.y = (v[1] - mu) * rs * lg.y + lb.y;
        y.z = (v[2] - mu) * rs * lg.z + lb.z;
        y.w = (v[3] - mu) * rs * lg.w + lb.w;
        *(float4*)&io[(long)n * 64 + colb] = y;
    }
}

// --------------------------------------------------------------- classifier
__global__ __launch_bounds__(256) void k_cls(
    const float* __restrict__ hid2, const int* __restrict__ asp,
    const float* __restrict__ w, const float* __restrict__ b,
    float* __restrict__ out)
{
    int g = blockIdx.x * 256 + threadIdx.x;
    int i = g / 3, j = g - i * 3;
    int a = asp[i];
    float acc = b[j];
#pragma unroll 8
    for (int cc = 0; cc < 64; ++cc) acc += hid2[(long)a * 64 + cc] * w[cc * 3 + j];
    out[i * 3 + j] = acc;
}

extern "C" void kernel_launch(void* const* d_in, const int* in_sizes, int n_in,
                              void* d_out, int out_size, void* d_ws, size_t ws_size,
                              hipStream_t stream)
{
    const float* features    = (const float*)d_in[0];
    const int*   edge_index  = (const int*)d_in[1];
    const int*   aspect      = (const int*)d_in[2];
    const int*   etypes      = (const int*)d_in[3];
    const int*   ntypes      = (const int*)d_in[4];
    const float* pos         = (const float*)d_in[5];
    const float* fe_w1       = (const float*)d_in[6];
    const float* fe_b1       = (const float*)d_in[7];
    const float* fe_w2       = (const float*)d_in[8];
    const float* fe_b2       = (const float*)d_in[9];
    const float* fe_pos_w    = (const float*)d_in[10];
    const float* fe_pos_b    = (const float*)d_in[11];
    const float* fe_type_emb = (const float*)d_in[12];
    const float* fe_out_w    = (const float*)d_in[13];
    const float* fe_out_b    = (const float*)d_in[14];
    const float* g1_lin_w    = (const float*)d_in[15];
    const float* g1_att_src  = (const float*)d_in[16];
    const float* g1_att_dst  = (const float*)d_in[17];
    const float* g1_edge_emb = (const float*)d_in[18];
    const float* g1_lin_edge = (const float*)d_in[19];
    const float* g1_att_edge = (const float*)d_in[20];
    const float* g1_bias     = (const float*)d_in[21];
    const float* g1_res_w    = (const float*)d_in[22];
    const float* g1_res_b    = (const float*)d_in[23];
    const float* g1_ln_g     = (const float*)d_in[24];
    const float* g1_ln_b     = (const float*)d_in[25];
    const float* g2_lin_w    = (const float*)d_in[26];
    const float* g2_att_src  = (const float*)d_in[27];
    const float* g2_att_dst  = (const float*)d_in[28];
    const float* g2_edge_emb = (const float*)d_in[29];
    const float* g2_lin_edge = (const float*)d_in[30];
    const float* g2_att_edge = (const float*)d_in[31];
    const float* g2_bias     = (const float*)d_in[32];
    const float* g2_res_w    = (const float*)d_in[33];
    const float* g2_res_b    = (const float*)d_in[34];
    const float* g2_ln_g     = (const float*)d_in[35];
    const float* g2_ln_b     = (const float*)d_in[36];
    const float* cls_w       = (const float*)d_in[37];
    const float* cls_b       = (const float*)d_in[38];

    const int N = in_sizes[0] / 768;   // 50000
    const int E = in_sizes[1] / 2;     // 800000
    const int* src = edge_index;
    const int* dst = edge_index + E;

    char* wsb = (char*)d_ws;
    size_t off = 0;
    auto alloc = [&](size_t bytes) -> char* {
        char* p = wsb + off;
        off += (bytes + 255) & ~(size_t)255;
        return p;
    };
    unsigned short* t1b  = (unsigned short*)alloc((size_t)N * 64 * 2);
    unsigned short* xs1b = (unsigned short*)alloc((size_t)N * 256 * 2);
    unsigned short* xs2b = (unsigned short*)alloc((size_t)N * 64 * 2);
    unsigned short* hid1b= (unsigned short*)alloc((size_t)N * 256 * 2);
    float* rp1     = (float*)alloc((size_t)N * 256 * 4);  // res_pre1
    float* rp2     = (float*)alloc((size_t)N * 64 * 4);   // res_pre2, then hid2
    float* a_src1  = (float*)alloc((size_t)N * 4 * 4);
    float* a_dst1  = (float*)alloc((size_t)N * 4 * 4);
    float* a_src2  = (float*)alloc((size_t)N * 4);
    float* a_dst2  = (float*)alloc((size_t)N * 4);
    int*   cnt_t   = (int*)alloc((size_t)N * 4 * 4);
    int*   row_off = (int*)alloc((size_t)(N + 1) * 4);
    int*   cursor  = (int*)alloc((size_t)N * 4);
    int*   blk     = (int*)alloc(1024);
    int*   csr_pack= (int*)alloc((size_t)E * 4);
    float* aet1    = (float*)alloc(64);
    float* aet2    = (float*)alloc(64);
    unsigned short* bz_fe1 = (unsigned short*)alloc(768 * 64 * 2);
    unsigned short* bz_p1  = (unsigned short*)alloc(64 * 512 * 2);
    unsigned short* bz_p2  = (unsigned short*)alloc(256 * 128 * 2);
    float* W2p     = (float*)alloc(64 * 64 * 4);
    float* h0v     = (float*)alloc(64 * 4);
    float* taddv   = (float*)alloc(192 * 4);
    float* paddv   = (float*)alloc(64 * 4);
    float* C0t     = (float*)alloc(512 * 4);
    float* Tt      = (float*)alloc(3 * 512 * 4);
    float* Pt      = (float*)alloc(512 * 4);

    hipMemsetAsync(cnt_t, 0, (size_t)N * 4 * 4, stream);

    int mb = (N + 63) / 64;   // 782 row-tiles
    int ab = (N + 3) / 4;     // k_att blocks

    k_tables<<<1, 64, 0, stream>>>(g1_edge_emb, g1_lin_edge, g1_att_edge,
                                   g2_edge_emb, g2_lin_edge, g2_att_edge, aet1, aet2);
    k_bswz_fe1<<<48, 256, 0, stream>>>(fe_w1, bz_fe1);
    k_fuse1<<<1, 256, 0, stream>>>(fe_w2, fe_out_w, fe_b2, fe_pos_b, fe_out_b,
                                   fe_type_emb, fe_pos_w, W2p, h0v, taddv, paddv);
    k_fuse2<<<512, 64, 0, stream>>>(W2p, h0v, taddv, paddv, g1_lin_w, g1_res_w,
                                    g1_bias, g1_res_b, bz_p1, C0t, Tt, Pt);
    k_bswz2<256, 64><<<32, 256, 0, stream>>>(g2_lin_w, g2_res_w, bz_p2);
    k_fe1<<<mb, 256, 0, stream>>>(features, bz_fe1, fe_b1, t1b, N);
    k_prep<64, 256, true><<<dim3(mb, 4), 256, 0, stream>>>(
        t1b, bz_p1, C0t, Tt, Pt, ntypes, pos, xs1b, rp1, N);
    k_att<4><<<ab, 256, 0, stream>>>(xs1b, g1_att_src, g1_att_dst, a_src1, a_dst1, N);
    int eblk = (E + 255) / 256;
    int nb = (N + 255) / 256;
    k_count<<<eblk, 256, 0, stream>>>(dst, etypes, cnt_t, E);
    k_scan1<<<nb, 256, 0, stream>>>(cnt_t, row_off, blk, N);
    k_scan2<<<1, 256, 0, stream>>>(blk, nb);
    k_scan3<<<nb, 256, 0, stream>>>(row_off, cursor, blk, N, E);
    k_scatter<<<eblk, 256, 0, stream>>>(src, dst, etypes, cursor, csr_pack, E);
    k_gat1<<<N, 128, 0, stream>>>(xs1b, a_src1, a_dst1, row_off, csr_pack,
                                  cnt_t, aet1, g1_ln_g, g1_ln_b, rp1, hid1b);
    k_prep<256, 64, false><<<dim3(mb, 1), 256, 0, stream>>>(
        hid1b, bz_p2, g2_bias, g2_res_b, nullptr, nullptr, nullptr, xs2b, rp2, N);
    k_att<1><<<ab, 256, 0, stream>>>(xs2b, g2_att_src, g2_att_dst, a_src2, a_dst2, N);
    k_gat2<<<N, 64, 0, stream>>>(xs2b, a_src2, a_dst2, row_off, csr_pack,
                                 cnt_t, aet2, g2_ln_g, g2_ln_b, rp2);
    k_cls<<<(out_size + 255) / 256, 256, 0, stream>>>(rp2, aspect, cls_w, cls_b,
                                                      (float*)d_out);
}

// Round 3
// 620.933 us; speedup vs baseline: 1.0330x; 1.0330x over previous
//
#include <hip/hip_runtime.h>

// SimplifiedHAFE on MI355X — round 9: LDS-free skinny GEMMs.
//  (a) k_fe1/k_prep1/k_prep2 rewritten with NO LDS and NO barriers: in these
//      skinny GEMMs each A element is consumed by exactly one lane (rows
//      partitioned per wave, k by (quad,j)), so each lane loads its MFMA
//      A-fragment directly from global (identical line-access pattern as the
//      old staging loads, minus the LDS round trip and 2 barriers/chunk).
//      B fragments come from pre-swizzled frag-order bf16 tables in L2.
//  (b) rp1 residual stored bf16 (was fp32): -25.6 MB HBM round trip.
//  (c) Front-matter kernels merged: k_pre0 = tables+fuse1, k_bswz =
//      bswz_fe1+bswz_p2. (k_fe2 remains deleted via affine folding.)
//  (d) Round-7 wide gathers retained in k_gat1/k_gat2.

#define LRELU(x) ((x) > 0.f ? (x) : 0.2f * (x))

typedef __attribute__((ext_vector_type(8))) short short8;
typedef __attribute__((ext_vector_type(4))) float floatx4;

__device__ __forceinline__ unsigned short f2bf(float x) {
    union { float f; unsigned int u; } v; v.f = x;
    unsigned int r = (v.u + 0x7FFFu + ((v.u >> 16) & 1u)) >> 16;  // RNE
    return (unsigned short)r;
}
// pack 2 fp32 -> 2 bf16 (RNE) in one VALU; lo in low 16 bits
__device__ __forceinline__ unsigned int cvtpk(float lo, float hi) {
    unsigned int r;
    asm("v_cvt_pk_bf16_f32 %0, %1, %2" : "=v"(r) : "v"(lo), "v"(hi));
    return r;
}
__device__ __forceinline__ float bflo(unsigned int u) {
    return __uint_as_float(u << 16);
}
__device__ __forceinline__ float bfhi(unsigned int u) {
    return __uint_as_float(u & 0xFFFF0000u);
}
__device__ __forceinline__ float bf1(unsigned short u) {
    return __uint_as_float(((unsigned int)u) << 16);
}

// ---------------- front matter A: edge-type tables (block 0) + fe2 affine
// fold stage 1 (block 1)
__global__ __launch_bounds__(256) void k_pre0(
    const float* __restrict__ e_emb1, const float* __restrict__ lew1,
    const float* __restrict__ ae1,
    const float* __restrict__ e_emb2, const float* __restrict__ lew2,
    const float* __restrict__ ae2,
    float* __restrict__ aet1, float* __restrict__ aet2,
    const float* __restrict__ w2, const float* __restrict__ outw,
    const float* __restrict__ b2, const float* __restrict__ posb,
    const float* __restrict__ outb, const float* __restrict__ temb,
    const float* __restrict__ posw,
    float* __restrict__ W2p, float* __restrict__ h0,
    float* __restrict__ tadd, float* __restrict__ padd)
{
    __shared__ float M1[16];
    __shared__ float M2[4];
    int t = threadIdx.x;
    if (blockIdx.x == 0) {
        if (t < 16) {
            int d = t >> 2, h = t & 3;
            float s = 0.f;
            for (int c = 0; c < 64; ++c) s += lew1[d * 256 + h * 64 + c] * ae1[h * 64 + c];
            M1[d * 4 + h] = s;
        }
        if (t < 4) {
            float s = 0.f;
            for (int c = 0; c < 64; ++c) s += lew2[t * 64 + c] * ae2[c];
            M2[t] = s;
        }
        __syncthreads();
        if (t < 16) {
            int ty = t >> 2, h = t & 3;
            float s = 0.f;
            for (int d = 0; d < 4; ++d) s += e_emb1[ty * 4 + d] * M1[d * 4 + h];
            aet1[ty * 4 + h] = s;
        }
        if (t < 4) {
            float s = 0.f;
            for (int d = 0; d < 4; ++d) s += e_emb2[t * 4 + d] * M2[d];
            aet2[t] = s;
        }
    } else {
        // fuse1: W2p = w2 @ outw, plus projected affine add-vectors
        int i = t >> 2, jq = (t & 3) * 16;
        float a16[16];
#pragma unroll
        for (int u = 0; u < 16; ++u) a16[u] = 0.f;
        for (int k = 0; k < 64; ++k) {
            float a = w2[i * 64 + k];
            const float* op = outw + k * 64 + jq;
            float4 o0 = *(const float4*)op;
            float4 o1 = *(const float4*)(op + 4);
            float4 o2 = *(const float4*)(op + 8);
            float4 o3 = *(const float4*)(op + 12);
            a16[0] += a * o0.x;  a16[1] += a * o0.y;  a16[2] += a * o0.z;  a16[3] += a * o0.w;
            a16[4] += a * o1.x;  a16[5] += a * o1.y;  a16[6] += a * o1.z;  a16[7] += a * o1.w;
            a16[8] += a * o2.x;  a16[9] += a * o2.y;  a16[10] += a * o2.z; a16[11] += a * o2.w;
            a16[12] += a * o3.x; a16[13] += a * o3.y; a16[14] += a * o3.z; a16[15] += a * o3.w;
        }
#pragma unroll
        for (int u = 0; u < 16; ++u) W2p[i * 64 + jq + u] = a16[u];
        for (int e = t; e < 320; e += 256) {
            int g = e >> 6, j = e & 63;
            float s = 0.f;
            for (int k = 0; k < 64; ++k) {
                float v;
                if (g == 0) v = b2[k] + posb[k];
                else if (g <= 3) v = temb[(g - 1) * 64 + k];
                else v = posw[k];
                s += v * outw[k * 64 + j];
            }
            if (g == 0) h0[j] = s + outb[j];
            else if (g <= 3) tadd[(g - 1) * 64 + j] = s;
            else padd[j] = s;
        }
    }
}

// ---------------- front matter B: B pre-swizzles for fe1 (768x64) and
// prep2 ([lin|res] 256x128), frag-order bf16. grid = 320 blocks exactly.
__global__ __launch_bounds__(256) void k_bswz(
    const float* __restrict__ w1, const float* __restrict__ B1,
    const float* __restrict__ B2,
    unsigned short* __restrict__ out_fe1, unsigned short* __restrict__ out_p2)
{
    int idx = blockIdx.x * 256 + threadIdx.x;
    if (idx < 768 * 64) {
        int k = idx >> 6, col = idx & 63;
        int c = k >> 6, kl = k & 63, kg = kl >> 3, j = kl & 7;
        out_fe1[((c * 8 + kg) * 64 + col) * 8 + j] = f2bf(w1[k * 64 + col]);
    } else {
        int i2 = idx - 768 * 64;          // 256*128 elements
        int k = i2 >> 7, col = i2 & 127;
        float v = (col < 64) ? B1[k * 64 + col] : B2[k * 64 + col - 64];
        int c = k >> 6, kl = k & 63, kg = kl >> 3, j = kl & 7;
        out_p2[((c * 8 + kg) * 128 + col) * 8 + j] = f2bf(v);
    }
}

// ---- fuse stage 2: BLR = W2p @ [lin_w|res_w] -> frag-order bf16 (64x512),
//      plus projected add tables C0[512], T[3][512], P[512].
__global__ __launch_bounds__(64) void k_fuse2(
    const float* __restrict__ W2p, const float* __restrict__ h0,
    const float* __restrict__ tadd, const float* __restrict__ padd,
    const float* __restrict__ lin_w, const float* __restrict__ res_w,
    const float* __restrict__ bias, const float* __restrict__ res_b,
    unsigned short* __restrict__ bz, float* __restrict__ C0,
    float* __restrict__ T, float* __restrict__ P)
{
    __shared__ float bcol[64];
    int c = blockIdx.x;           // 0..511
    int j = threadIdx.x;          // 0..63
    int cL = c & 255;
    const float* Bsrc = (c < 256) ? lin_w : res_w;
    float bv = Bsrc[j * 256 + cL];
    bcol[j] = bv;
    __syncthreads();
    float s = 0.f;
#pragma unroll 8
    for (int k = 0; k < 64; ++k) s += W2p[j * 64 + k] * bcol[k];
    int kg = j >> 3, jj = j & 7, ct = c >> 7, cl = c & 127;
    bz[((ct * 8 + kg) * 128 + cl) * 8 + jj] = f2bf(s);
    float pc = h0[j] * bv;
    float p0 = tadd[j] * bv, p1 = tadd[64 + j] * bv, p2 = tadd[128 + j] * bv;
    float pp = padd[j] * bv;
#pragma unroll
    for (int k = 32; k; k >>= 1) {
        pc += __shfl_xor(pc, k, 64); p0 += __shfl_xor(p0, k, 64);
        p1 += __shfl_xor(p1, k, 64); p2 += __shfl_xor(p2, k, 64);
        pp += __shfl_xor(pp, k, 64);
    }
    if (j == 0) {
        C0[c] = pc + ((c >= 256) ? (bias[cL] + res_b[cL]) : 0.f);
        T[c] = p0; T[512 + c] = p1; T[1024 + c] = p2;
        P[c] = pp;
    }
}

// ------------- FE stage 1: relu(X@W1+b1) -> bf16. LDS-free: each lane loads
// its own MFMA A-fragment (rows = wave-local l16, k = quad*8+j) from global.
// Block = 64 rows (4 waves x 16 rows), 64 cols.
__global__ __launch_bounds__(256) void k_fe1(
    const float* __restrict__ feat, const unsigned short* __restrict__ bswz,
    const float* __restrict__ b1, unsigned short* __restrict__ t1b, int N)
{
    int t = threadIdx.x;
    int wv = t >> 6, lane = t & 63;
    int quad = lane >> 4, l16 = lane & 15;
    long rw = (long)blockIdx.x * 64 + wv * 16;
    long ra = rw + l16;
    if (ra >= N) ra = N - 1;
    const float* fbase = feat + ra * 768 + quad * 8;

    floatx4 acc[4];
#pragma unroll
    for (int i = 0; i < 4; ++i) acc[i] = (floatx4){0.f, 0.f, 0.f, 0.f};

    for (int ci = 0; ci < 12; ++ci) {
        const float* fc = fbase + ci * 64;
        short8 af[2];
#pragma unroll
        for (int s = 0; s < 2; ++s) {
            float4 x = *(const float4*)(fc + s * 32);
            float4 y = *(const float4*)(fc + s * 32 + 4);
            uint4 u = {cvtpk(x.x, x.y), cvtpk(x.z, x.w),
                       cvtpk(y.x, y.y), cvtpk(y.z, y.w)};
            af[s] = *(short8*)&u;
        }
#pragma unroll
        for (int s = 0; s < 2; ++s) {
            int kg = s * 4 + quad;
#pragma unroll
            for (int ct = 0; ct < 4; ++ct) {
                short8 bfrag = *(const short8*)&bswz[
                    ((ci * 8 + kg) * 64 + ct * 16 + l16) * 8];
                acc[ct] = __builtin_amdgcn_mfma_f32_16x16x32_bf16(
                    af[s], bfrag, acc[ct], 0, 0, 0);
            }
        }
    }
#pragma unroll
    for (int ct = 0; ct < 4; ++ct) {
        float bb = b1[ct * 16 + l16];
#pragma unroll
        for (int r = 0; r < 4; ++r) {
            long m = rw + quad * 4 + r;
            if (m < N)
                t1b[m * 64 + ct * 16 + l16] = f2bf(fmaxf(acc[ct][r] + bb, 0.f));
        }
    }
}

// ------------- prep1: t1b[Nx64] @ BLR[64x512] + fused fe2-tail adds.
// Block = 64 rows x 128 cols (by = col quarter). by<2 -> xs bf16, by>=2 ->
// residual bf16. LDS-free.
__global__ __launch_bounds__(256) void k_prep1(
    const unsigned short* __restrict__ A, const unsigned short* __restrict__ bswz,
    const float* __restrict__ C0, const float* __restrict__ T,
    const float* __restrict__ P, const int* __restrict__ ntypes,
    const float* __restrict__ pos,
    unsigned short* __restrict__ xsb, unsigned short* __restrict__ resp, int N)
{
    int t = threadIdx.x;
    int wv = t >> 6, lane = t & 63;
    int quad = lane >> 4, l16 = lane & 15;
    long rw = (long)blockIdx.x * 64 + wv * 16;
    int by = blockIdx.y;
    long ra = rw + l16;
    if (ra >= N) ra = N - 1;
    const unsigned short* abase = A + ra * 64 + quad * 8;

    floatx4 acc[8];
#pragma unroll
    for (int i = 0; i < 8; ++i) acc[i] = (floatx4){0.f, 0.f, 0.f, 0.f};

    short8 af[2];
    af[0] = *(const short8*)(abase);
    af[1] = *(const short8*)(abase + 32);
#pragma unroll
    for (int s = 0; s < 2; ++s) {
        int kg = s * 4 + quad;
#pragma unroll
        for (int c8 = 0; c8 < 8; ++c8) {
            short8 bfrag = *(const short8*)&bswz[
                ((by * 8 + kg) * 128 + c8 * 16 + l16) * 8];
            acc[c8] = __builtin_amdgcn_mfma_f32_16x16x32_bf16(
                af[s], bfrag, acc[c8], 0, 0, 0);
        }
    }
    int nta[4];
    float posa[4];
#pragma unroll
    for (int r = 0; r < 4; ++r) {
        long m = rw + quad * 4 + r;
        if (m < N) { nta[r] = ntypes[m]; posa[r] = pos[m]; }
        else       { nta[r] = 0; posa[r] = 0.f; }
    }
    bool isl = (by < 2);
    int cb = by * 128;
#pragma unroll
    for (int c8 = 0; c8 < 8; ++c8) {
        int gc = cb + c8 * 16 + l16;
        float c0 = C0[gc], pcf = P[gc];
#pragma unroll
        for (int r = 0; r < 4; ++r) {
            long m = rw + quad * 4 + r;
            if (m < N) {
                float val = acc[c8][r] + c0 + T[nta[r] * 512 + gc] + posa[r] * pcf;
                if (isl) xsb[m * 256 + gc] = f2bf(val);
                else     resp[m * 256 + gc - 256] = f2bf(val);
            }
        }
    }
}

// ------------- prep2: hid1b[Nx256] @ [lin|res][256x128]. Block = 64 rows x
// 128 cols. cols<64 -> xs2 bf16; cols>=64 -> res fp32 (+bias+res_b). LDS-free.
__global__ __launch_bounds__(256) void k_prep2(
    const unsigned short* __restrict__ A, const unsigned short* __restrict__ bswz,
    const float* __restrict__ bias, const float* __restrict__ res_b,
    unsigned short* __restrict__ xsb, float* __restrict__ resp, int N)
{
    int t = threadIdx.x;
    int wv = t >> 6, lane = t & 63;
    int quad = lane >> 4, l16 = lane & 15;
    long rw = (long)blockIdx.x * 64 + wv * 16;
    long ra = rw + l16;
    if (ra >= N) ra = N - 1;
    const unsigned short* abase = A + ra * 256 + quad * 8;

    floatx4 acc[8];
#pragma unroll
    for (int i = 0; i < 8; ++i) acc[i] = (floatx4){0.f, 0.f, 0.f, 0.f};

    for (int ci = 0; ci < 4; ++ci) {
        short8 af[2];
        af[0] = *(const short8*)(abase + ci * 64);
        af[1] = *(const short8*)(abase + ci * 64 + 32);
#pragma unroll
        for (int s = 0; s < 2; ++s) {
            int kg = s * 4 + quad;
#pragma unroll
            for (int c8 = 0; c8 < 8; ++c8) {
                short8 bfrag = *(const short8*)&bswz[
                    ((ci * 8 + kg) * 128 + c8 * 16 + l16) * 8];
                acc[c8] = __builtin_amdgcn_mfma_f32_16x16x32_bf16(
                    af[s], bfrag, acc[c8], 0, 0, 0);
            }
        }
    }
#pragma unroll
    for (int c8 = 0; c8 < 8; ++c8) {
        int gc = c8 * 16 + l16;
        bool isl = gc < 64;
        float badd = isl ? 0.f : (bias[gc - 64] + res_b[gc - 64]);
#pragma unroll
        for (int r = 0; r < 4; ++r) {
            long m = rw + quad * 4 + r;
            if (m < N) {
                float val = acc[c8][r];
                if (isl) xsb[m * 64 + gc] = f2bf(val);
                else     resp[m * 64 + gc - 64] = val + badd;
            }
        }
    }
}

// --------- attention scalars: a_src/a_dst[n,h] = dot(xs[n,h*64:+64], att)
template<int H>
__global__ __launch_bounds__(256) void k_att(
    const unsigned short* __restrict__ xsb, const float* __restrict__ att_s,
    const float* __restrict__ att_d, float* __restrict__ a_src,
    float* __restrict__ a_dst, int N)
{
    int t = threadIdx.x;
    int wv = t >> 6, lane = t & 63;
    long n = (long)blockIdx.x * 4 + wv;
    if (n >= N) return;
    if (H == 4) {
        ushort4 u = *(const ushort4*)&xsb[n * 256 + lane * 4];
        float4 as = *(const float4*)&att_s[lane * 4];
        float4 ad = *(const float4*)&att_d[lane * 4];
        float x0 = bf1(u.x), x1 = bf1(u.y), x2 = bf1(u.z), x3 = bf1(u.w);
        float p = x0 * as.x + x1 * as.y + x2 * as.z + x3 * as.w;
        float q = x0 * ad.x + x1 * ad.y + x2 * ad.z + x3 * ad.w;
#pragma unroll
        for (int k = 8; k; k >>= 1) {
            p += __shfl_xor(p, k, 64);
            q += __shfl_xor(q, k, 64);
        }
        if ((lane & 15) == 0) {
            a_src[n * 4 + (lane >> 4)] = p;
            a_dst[n * 4 + (lane >> 4)] = q;
        }
    } else {
        float x = bf1(xsb[n * 64 + lane]);
        float p = x * att_s[lane];
        float q = x * att_d[lane];
#pragma unroll
        for (int k = 32; k; k >>= 1) {
            p += __shfl_xor(p, k, 64);
            q += __shfl_xor(q, k, 64);
        }
        if (lane == 0) { a_src[n] = p; a_dst[n] = q; }
    }
}

// ---------------------------------------------------------------- CSR build
__global__ __launch_bounds__(256) void k_count(
    const int* __restrict__ dst, const int* __restrict__ et,
    int* __restrict__ cnt_t, int E)
{
    int e = blockIdx.x * 256 + threadIdx.x;
    if (e < E) atomicAdd(&cnt_t[dst[e] * 4 + et[e]], 1);
}

__global__ __launch_bounds__(256) void k_scan1(
    const int* __restrict__ cnt_t, int* __restrict__ row_off,
    int* __restrict__ blk_sums, int N)
{
    __shared__ int s[256];
    int t = threadIdx.x;
    int i = blockIdx.x * 256 + t;
    int v = 0;
    if (i < N) v = cnt_t[4 * i] + cnt_t[4 * i + 1] + cnt_t[4 * i + 2] + cnt_t[4 * i + 3];
    s[t] = v;
    __syncthreads();
    for (int off = 1; off < 256; off <<= 1) {
        int x = 0;
        if (t >= off) x = s[t - off];
        __syncthreads();
        s[t] += x;
        __syncthreads();
    }
    if (i < N) row_off[i] = s[t] - v;
    if (t == 255) blk_sums[blockIdx.x] = s[255];
}

__global__ __launch_bounds__(256) void k_scan2(int* __restrict__ blk_sums, int nb)
{
    __shared__ int s[256];
    int t = threadIdx.x;
    int v = (t < nb) ? blk_sums[t] : 0;
    s[t] = v;
    __syncthreads();
    for (int off = 1; off < 256; off <<= 1) {
        int x = 0;
        if (t >= off) x = s[t - off];
        __syncthreads();
        s[t] += x;
        __syncthreads();
    }
    if (t < nb) blk_sums[t] = s[t] - v;
}

__global__ __launch_bounds__(256) void k_scan3(
    int* __restrict__ row_off, int* __restrict__ cursor,
    const int* __restrict__ blk_sums, int N, int E)
{
    int t = threadIdx.x;
    int i = blockIdx.x * 256 + t;
    if (i < N) {
        int o = row_off[i] + blk_sums[blockIdx.x];
        row_off[i] = o;
        cursor[i] = o;
    }
    if (i == 0) row_off[N] = E;
}

__global__ __launch_bounds__(256) void k_scatter(
    const int* __restrict__ src, const int* __restrict__ dst,
    const int* __restrict__ et, int* __restrict__ cursor,
    int* __restrict__ csr_pack, int E)
{
    int e = blockIdx.x * 256 + threadIdx.x;
    if (e < E) {
        int d = dst[e];
        int pos = atomicAdd(&cursor[d], 1);
        csr_pack[pos] = src[e] | (et[e] << 28);
    }
}

// ---------------- GAT layer 1: 128 thr = 2 waves; wave w owns heads 2w,2w+1.
// Gather: 4 edges / wave-iter, 16 lanes x dwordx4. res read bf16, out bf16.
__global__ __launch_bounds__(128) void k_gat1(
    const unsigned short* __restrict__ xs1b, const float* __restrict__ a_src,
    const float* __restrict__ a_dst, const int* __restrict__ row_off,
    const int* __restrict__ csr_pack,
    const int* __restrict__ cnt_t, const float* __restrict__ aet1,
    const float* __restrict__ ln_g, const float* __restrict__ ln_b,
    const unsigned short* __restrict__ res, unsigned short* __restrict__ out)
{
    __shared__ __align__(16) float4 ws[2][64];
    __shared__ float2 aetp[2][4];
    __shared__ float red[4];
    int n = blockIdx.x;
    int t = threadIdx.x;
    int w = t >> 6, c = t & 63;
    int lc = c & 15, g = c >> 4;
    int h0 = 2 * w;
    if (t < 8) {
        int w2 = t >> 2, ty = t & 3;
        aetp[w2][ty] = make_float2(aet1[ty * 4 + 2 * w2], aet1[ty * 4 + 2 * w2 + 1]);
    }
    int off = row_off[n], deg = row_off[n + 1] - off;
    float2 a_d = *(const float2*)&a_dst[n * 4 + h0];
    __syncthreads();
    float ael0 = 0.f, ael1 = 0.f;
    int degc = 0;
#pragma unroll
    for (int ty = 0; ty < 4; ++ty) {
        int ct = cnt_t[n * 4 + ty];
        degc += ct;
        float2 ae = aetp[w][ty];
        ael0 += (float)ct * ae.x;
        ael1 += (float)ct * ae.y;
    }
    float inv = (degc > 0) ? 1.f / (float)degc : 1.f;
    float2 a_s_self = *(const float2*)&a_src[n * 4 + h0];
    float al0 = a_s_self.x + a_d.x + ael0 * inv;
    float al1 = a_s_self.y + a_d.y + ael1 * inv;
    al0 = LRELU(al0); al1 = LRELU(al1);
    float wself0 = expf(al0), wself1 = expf(al1);

    int col0 = w * 128 + lc * 8;                    // 8 cols per lane
    const unsigned short* xrow = xs1b + col0;       // + s*256 per gather
    float acc[8];
#pragma unroll
    for (int j = 0; j < 8; ++j) acc[j] = 0.f;
    float dp0 = 0.f, dp1 = 0.f;

    for (int base = 0; base < deg; base += 64) {
        int cnt = min(64, deg - base);
        float w0 = 0.f, w1 = 0.f;
        int s = 0;
        if (c < cnt) {
            int pk = csr_pack[off + base + c];
            s = pk & 0x0FFFFFFF;
            int ty = ((unsigned)pk) >> 28;
            float2 as2 = *(const float2*)&a_src[s * 4 + h0];
            float2 ae = aetp[w][ty];
            float a0 = as2.x + a_d.x + ae.x;
            float a1 = as2.y + a_d.y + ae.y;
            a0 = LRELU(a0); a1 = LRELU(a1);
            w0 = expf(a0); w1 = expf(a1);
        }
        dp0 += w0; dp1 += w1;
        ws[w][c] = make_float4(w0, w1, __int_as_float(s), 0.f);
        int cr = (cnt + 7) & ~7;
        for (int i = 0; i < cr; i += 8) {
#pragma unroll
            for (int u = 0; u < 2; ++u) {
                float4 p = ws[w][i + u * 4 + g];
                float wl = (lc < 8) ? p.x : p.y;
                uint4 q = *(const uint4*)&xrow[(long)__float_as_int(p.z) * 256];
                acc[0] += wl * bflo(q.x); acc[1] += wl * bfhi(q.x);
                acc[2] += wl * bflo(q.y); acc[3] += wl * bfhi(q.y);
                acc[4] += wl * bflo(q.z); acc[5] += wl * bfhi(q.z);
                acc[6] += wl * bflo(q.w); acc[7] += wl * bfhi(q.w);
            }
        }
    }
#pragma unroll
    for (int k = 32; k; k >>= 1) {
        dp0 += __shfl_xor(dp0, k, 64);
        dp1 += __shfl_xor(dp1, k, 64);
    }
#pragma unroll
    for (int j = 0; j < 8; ++j) {
        acc[j] += __shfl_xor(acc[j], 16, 64);
        acc[j] += __shfl_xor(acc[j], 32, 64);
    }
    uint4 us = *(const uint4*)&xrow[(long)n * 256];
    float wself_l = (lc < 8) ? wself0 : wself1;
    acc[0] += wself_l * bflo(us.x); acc[1] += wself_l * bfhi(us.x);
    acc[2] += wself_l * bflo(us.y); acc[3] += wself_l * bfhi(us.y);
    acc[4] += wself_l * bflo(us.z); acc[5] += wself_l * bfhi(us.z);
    acc[6] += wself_l * bflo(us.w); acc[7] += wself_l * bfhi(us.w);
    float dsum = ((lc < 8) ? dp0 + wself0 : dp1 + wself1) + 1e-16f;
    float rd = 1.f / dsum;
    uint4 ur = *(const uint4*)&res[(long)n * 256 + col0];
    float v[8];
    v[0] = acc[0] * rd + bflo(ur.x); v[1] = acc[1] * rd + bfhi(ur.x);
    v[2] = acc[2] * rd + bflo(ur.y); v[3] = acc[3] * rd + bfhi(ur.y);
    v[4] = acc[4] * rd + bflo(ur.z); v[5] = acc[5] * rd + bfhi(ur.z);
    v[6] = acc[6] * rd + bflo(ur.w); v[7] = acc[7] * rd + bfhi(ur.w);
    float s1 = 0.f, s2 = 0.f;
#pragma unroll
    for (int j = 0; j < 8; ++j) { s1 += v[j]; s2 += v[j] * v[j]; }
#pragma unroll
    for (int k = 32; k; k >>= 1) {
        s1 += __shfl_xor(s1, k, 64);
        s2 += __shfl_xor(s2, k, 64);
    }
    if (c == 0) { red[w] = s1 * 0.25f; red[2 + w] = s2 * 0.25f; }
    __syncthreads();
    float mu = (red[0] + red[1]) * (1.f / 256.f);
    float var = (red[2] + red[3]) * (1.f / 256.f) - mu * mu;
    float rs = rsqrtf(var + 1e-5f);
    if (g == 0) {
        float4 lg0 = *(const float4*)&ln_g[col0];
        float4 lg1 = *(const float4*)&ln_g[col0 + 4];
        float4 lb0 = *(const float4*)&ln_b[col0];
        float4 lb1 = *(const float4*)&ln_b[col0 + 4];
        float y[8];
        y[0] = fmaxf((v[0] - mu) * rs * lg0.x + lb0.x, 0.f);
        y[1] = fmaxf((v[1] - mu) * rs * lg0.y + lb0.y, 0.f);
        y[2] = fmaxf((v[2] - mu) * rs * lg0.z + lb0.z, 0.f);
        y[3] = fmaxf((v[3] - mu) * rs * lg0.w + lb0.w, 0.f);
        y[4] = fmaxf((v[4] - mu) * rs * lg1.x + lb1.x, 0.f);
        y[5] = fmaxf((v[5] - mu) * rs * lg1.y + lb1.y, 0.f);
        y[6] = fmaxf((v[6] - mu) * rs * lg1.z + lb1.z, 0.f);
        y[7] = fmaxf((v[7] - mu) * rs * lg1.w + lb1.w, 0.f);
        uint4 o;
        o.x = cvtpk(y[0], y[1]); o.y = cvtpk(y[2], y[3]);
        o.z = cvtpk(y[4], y[5]); o.w = cvtpk(y[6], y[7]);
        *(uint4*)&out[(long)n * 256 + col0] = o;
    }
}

// --------------------------------- GAT layer 2 (H=1, C=64): one wave per node
__global__ __launch_bounds__(64) void k_gat2(
    const unsigned short* __restrict__ xs2b, const float* __restrict__ a_src,
    const float* __restrict__ a_dst, const int* __restrict__ row_off,
    const int* __restrict__ csr_pack,
    const int* __restrict__ cnt_t, const float* __restrict__ aet2,
    const float* __restrict__ ln_g, const float* __restrict__ ln_b,
    float* io)
{
    __shared__ __align__(8) float2 ws[64];
    __shared__ float aetl[4];
    int n = blockIdx.x;
    int c = threadIdx.x;
    int lc = c & 15, g = c >> 4;
    if (c < 4) aetl[c] = aet2[c];
    int off = row_off[n], deg = row_off[n + 1] - off;
    float a_d = a_dst[n];
    float ael = 0.f;
    int degc = 0;
#pragma unroll
    for (int ty = 0; ty < 4; ++ty) {
        int ct = cnt_t[n * 4 + ty];
        degc += ct;
        ael += (float)ct * aet2[ty];
    }
    ael *= (degc > 0 ? 1.f / (float)degc : 1.f);
    float al = a_src[n] + a_d + ael;
    al = LRELU(al);
    float wself = expf(al);

    int colb = lc * 4;
    const unsigned short* xrow = xs2b + colb;
    float acc[4] = {0.f, 0.f, 0.f, 0.f};
    float dp = 0.f;
    for (int base = 0; base < deg; base += 64) {
        int cnt = min(64, deg - base);
        float we = 0.f;
        int s = 0;
        if (c < cnt) {
            int pk = csr_pack[off + base + c];
            s = pk & 0x0FFFFFFF;
            int ty = ((unsigned)pk) >> 28;
            float a = a_src[s] + a_d + aetl[ty];
            a = LRELU(a);
            we = expf(a);
        }
        dp += we;
        ws[c] = make_float2(we, __int_as_float(s));
        int cr = (cnt + 7) & ~7;
        for (int i = 0; i < cr; i += 8) {
#pragma unroll
            for (int u = 0; u < 2; ++u) {
                float2 p = ws[i + u * 4 + g];
                uint2 q = *(const uint2*)&xrow[(long)__float_as_int(p.y) * 64];
                acc[0] += p.x * bflo(q.x); acc[1] += p.x * bfhi(q.x);
                acc[2] += p.x * bflo(q.y); acc[3] += p.x * bfhi(q.y);
            }
        }
    }
#pragma unroll
    for (int k = 32; k; k >>= 1) dp += __shfl_xor(dp, k, 64);
#pragma unroll
    for (int j = 0; j < 4; ++j) {
        acc[j] += __shfl_xor(acc[j], 16, 64);
        acc[j] += __shfl_xor(acc[j], 32, 64);
    }
    uint2 us = *(const uint2*)&xrow[(long)n * 64];
    acc[0] += wself * bflo(us.x); acc[1] += wself * bfhi(us.x);
    acc[2] += wself * bflo(us.y); acc[3] += wself * bfhi(us.y);
    float dsum = dp + wself + 1e-16f;
    float rd = 1.f / dsum;
    float4 r = *(const float4*)&io[(long)n * 64 + colb];
    float v[4];
    v[0] = acc[0] * rd + r.x; v[1] = acc[1] * rd + r.y;
    v[2] = acc[2] * rd + r.z; v[3] = acc[3] * rd + r.w;
    float s1 = v[0] + v[1] + v[2] + v[3];
    float s2 = v[0] * v[0] + v[1] * v[1] + v[2] * v[2] + v[3] * v[3];
#pragma unroll
    for (int k = 32; k; k >>= 1) {
        s1 += __shfl_xor(s1, k, 64);
        s2 += __shfl_xor(s2, k, 64);
    }
    float mu = s1 * (1.f / 256.f);
    float var = s2 * (1.f / 256.f) - mu * mu;
    float rs = rsqrtf(var + 1e-5f);
    if (g == 0) {
        float4 lg = *(const float4*)&ln_g[colb];
        float4 lb = *(const float4*)&ln_b[colb];
        float4 y;
        y.x = (v[0] - mu) * rs * lg.x + lb.x;
        y.y = (v[1] - mu) * rs * lg.y + lb.y;
        y.z = (v[2] - mu) * rs * lg.z + lb.z;
        y.w = (v[3] - mu) * rs * lg.w + lb.w;
        *(float4*)&io[(long)n * 64 + colb] = y;
    }
}

// --------------------------------------------------------------- classifier
__global__ __launch_bounds__(256) void k_cls(
    const float* __restrict__ hid2, const int* __restrict__ asp,
    const float* __restrict__ w, const float* __restrict__ b,
    float* __restrict__ out)
{
    int g = blockIdx.x * 256 + threadIdx.x;
    int i = g / 3, j = g - i * 3;
    int a = asp[i];
    float acc = b[j];
#pragma unroll 8
    for (int cc = 0; cc < 64; ++cc) acc += hid2[(long)a * 64 + cc] * w[cc * 3 + j];
    out[i * 3 + j] = acc;
}

extern "C" void kernel_launch(void* const* d_in, const int* in_sizes, int n_in,
                              void* d_out, int out_size, void* d_ws, size_t ws_size,
                              hipStream_t stream)
{
    const float* features    = (const float*)d_in[0];
    const int*   edge_index  = (const int*)d_in[1];
    const int*   aspect      = (const int*)d_in[2];
    const int*   etypes      = (const int*)d_in[3];
    const int*   ntypes      = (const int*)d_in[4];
    const float* pos         = (const float*)d_in[5];
    const float* fe_w1       = (const float*)d_in[6];
    const float* fe_b1       = (const float*)d_in[7];
    const float* fe_w2       = (const float*)d_in[8];
    const float* fe_b2       = (const float*)d_in[9];
    const float* fe_pos_w    = (const float*)d_in[10];
    const float* fe_pos_b    = (const float*)d_in[11];
    const float* fe_type_emb = (const float*)d_in[12];
    const float* fe_out_w    = (const float*)d_in[13];
    const float* fe_out_b    = (const float*)d_in[14];
    const float* g1_lin_w    = (const float*)d_in[15];
    const float* g1_att_src  = (const float*)d_in[16];
    const float* g1_att_dst  = (const float*)d_in[17];
    const float* g1_edge_emb = (const float*)d_in[18];
    const float* g1_lin_edge = (const float*)d_in[19];
    const float* g1_att_edge = (const float*)d_in[20];
    const float* g1_bias     = (const float*)d_in[21];
    const float* g1_res_w    = (const float*)d_in[22];
    const float* g1_res_b    = (const float*)d_in[23];
    const float* g1_ln_g     = (const float*)d_in[24];
    const float* g1_ln_b     = (const float*)d_in[25];
    const float* g2_lin_w    = (const float*)d_in[26];
    const float* g2_att_src  = (const float*)d_in[27];
    const float* g2_att_dst  = (const float*)d_in[28];
    const float* g2_edge_emb = (const float*)d_in[29];
    const float* g2_lin_edge = (const float*)d_in[30];
    const float* g2_att_edge = (const float*)d_in[31];
    const float* g2_bias     = (const float*)d_in[32];
    const float* g2_res_w    = (const float*)d_in[33];
    const float* g2_res_b    = (const float*)d_in[34];
    const float* g2_ln_g     = (const float*)d_in[35];
    const float* g2_ln_b     = (const float*)d_in[36];
    const float* cls_w       = (const float*)d_in[37];
    const float* cls_b       = (const float*)d_in[38];

    const int N = in_sizes[0] / 768;   // 50000
    const int E = in_sizes[1] / 2;     // 800000
    const int* src = edge_index;
    const int* dst = edge_index + E;

    char* wsb = (char*)d_ws;
    size_t off = 0;
    auto alloc = [&](size_t bytes) -> char* {
        char* p = wsb + off;
        off += (bytes + 255) & ~(size_t)255;
        return p;
    };
    unsigned short* t1b  = (unsigned short*)alloc((size_t)N * 64 * 2);
    unsigned short* xs1b = (unsigned short*)alloc((size_t)N * 256 * 2);
    unsigned short* xs2b = (unsigned short*)alloc((size_t)N * 64 * 2);
    unsigned short* hid1b= (unsigned short*)alloc((size_t)N * 256 * 2);
    unsigned short* rp1  = (unsigned short*)alloc((size_t)N * 256 * 2);  // res1 bf16
    float* rp2     = (float*)alloc((size_t)N * 64 * 4);   // res_pre2, then hid2
    float* a_src1  = (float*)alloc((size_t)N * 4 * 4);
    float* a_dst1  = (float*)alloc((size_t)N * 4 * 4);
    float* a_src2  = (float*)alloc((size_t)N * 4);
    float* a_dst2  = (float*)alloc((size_t)N * 4);
    int*   cnt_t   = (int*)alloc((size_t)N * 4 * 4);
    int*   row_off = (int*)alloc((size_t)(N + 1) * 4);
    int*   cursor  = (int*)alloc((size_t)N * 4);
    int*   blk     = (int*)alloc(1024);
    int*   csr_pack= (int*)alloc((size_t)E * 4);
    float* aet1    = (float*)alloc(64);
    float* aet2    = (float*)alloc(64);
    unsigned short* bz_fe1 = (unsigned short*)alloc(768 * 64 * 2);
    unsigned short* bz_p1  = (unsigned short*)alloc(64 * 512 * 2);
    unsigned short* bz_p2  = (unsigned short*)alloc(256 * 128 * 2);
    float* W2p     = (float*)alloc(64 * 64 * 4);
    float* h0v     = (float*)alloc(64 * 4);
    float* taddv   = (float*)alloc(192 * 4);
    float* paddv   = (float*)alloc(64 * 4);
    float* C0t     = (float*)alloc(512 * 4);
    float* Tt      = (float*)alloc(3 * 512 * 4);
    float* Pt      = (float*)alloc(512 * 4);

    hipMemsetAsync(cnt_t, 0, (size_t)N * 4 * 4, stream);

    int mb = (N + 63) / 64;   // 782 row-tiles
    int ab = (N + 3) / 4;     // k_att blocks

    k_pre0<<<2, 256, 0, stream>>>(g1_edge_emb, g1_lin_edge, g1_att_edge,
                                  g2_edge_emb, g2_lin_edge, g2_att_edge, aet1, aet2,
                                  fe_w2, fe_out_w, fe_b2, fe_pos_b, fe_out_b,
                                  fe_type_emb, fe_pos_w, W2p, h0v, taddv, paddv);
    k_bswz<<<320, 256, 0, stream>>>(fe_w1, g2_lin_w, g2_res_w, bz_fe1, bz_p2);
    k_fuse2<<<512, 64, 0, stream>>>(W2p, h0v, taddv, paddv, g1_lin_w, g1_res_w,
                                    g1_bias, g1_res_b, bz_p1, C0t, Tt, Pt);
    k_fe1<<<mb, 256, 0, stream>>>(features, bz_fe1, fe_b1, t1b, N);
    k_prep1<<<dim3(mb, 4), 256, 0, stream>>>(
        t1b, bz_p1, C0t, Tt, Pt, ntypes, pos, xs1b, rp1, N);
    k_att<4><<<ab, 256, 0, stream>>>(xs1b, g1_att_src, g1_att_dst, a_src1, a_dst1, N);
    int eblk = (E + 255) / 256;
    int nb = (N + 255) / 256;
    k_count<<<eblk, 256, 0, stream>>>(dst, etypes, cnt_t, E);
    k_scan1<<<nb, 256, 0, stream>>>(cnt_t, row_off, blk, N);
    k_scan2<<<1, 256, 0, stream>>>(blk, nb);
    k_scan3<<<nb, 256, 0, stream>>>(row_off, cursor, blk, N, E);
    k_scatter<<<eblk, 256, 0, stream>>>(src, dst, etypes, cursor, csr_pack, E);
    k_gat1<<<N, 128, 0, stream>>>(xs1b, a_src1, a_dst1, row_off, csr_pack,
                                  cnt_t, aet1, g1_ln_g, g1_ln_b, rp1, hid1b);
    k_prep2<<<mb, 256, 0, stream>>>(hid1b, bz_p2, g2_bias, g2_res_b, xs2b, rp2, N);
    k_att<1><<<ab, 256, 0, stream>>>(xs2b, g2_att_src, g2_att_dst, a_src2, a_dst2, N);
    k_gat2<<<N, 64, 0, stream>>>(xs2b, a_src2, a_dst2, row_off, csr_pack,
                                 cnt_t, aet2, g2_ln_g, g2_ln_b, rp2);
    k_cls<<<(out_size + 255) / 256, 256, 0, stream>>>(rp2, aspect, cls_w, cls_b,
                                                      (float*)d_out);
}

// Round 4
// 605.035 us; speedup vs baseline: 1.0601x; 1.0263x over previous
//
#include <hip/hip_runtime.h>

// SimplifiedHAFE on MI355X — round 10: launch diet + edge-weight hoisting.
//  (a) k_att<4>/k_att<1> folded into k_prep1/k_prep2 epilogues (attention
//      dots from in-register fp32 vals + 16-lane shfl reduce). -2 kernels,
//      -32 MB re-reads.
//  (b) gat1 per-edge softmax weights precomputed in k_scatter (edge-parallel,
//      coalesced, full-wave) into wbuf[E][4] fp32 — bitwise-identical exp
//      values. k_gat1's weight phase is now 2 coalesced loads, no divergent
//      exp/LRELU, no random a_src gathers.
//  (c) k_pre0+k_bswz merged into k_front; k_scan2 absorbed into k_scan3
//      (per-block re-sum of <=196 block sums); k_gat2 packs 2 nodes/block.
//      19 -> 14 dispatches.
//  (d) Round-9 LDS-free GEMMs + bf16 intermediates retained.

#define LRELU(x) ((x) > 0.f ? (x) : 0.2f * (x))

typedef __attribute__((ext_vector_type(8))) short short8;
typedef __attribute__((ext_vector_type(4))) float floatx4;

__device__ __forceinline__ unsigned short f2bf(float x) {
    union { float f; unsigned int u; } v; v.f = x;
    unsigned int r = (v.u + 0x7FFFu + ((v.u >> 16) & 1u)) >> 16;  // RNE
    return (unsigned short)r;
}
// pack 2 fp32 -> 2 bf16 (RNE) in one VALU; lo in low 16 bits
__device__ __forceinline__ unsigned int cvtpk(float lo, float hi) {
    unsigned int r;
    asm("v_cvt_pk_bf16_f32 %0, %1, %2" : "=v"(r) : "v"(lo), "v"(hi));
    return r;
}
__device__ __forceinline__ float bflo(unsigned int u) {
    return __uint_as_float(u << 16);
}
__device__ __forceinline__ float bfhi(unsigned int u) {
    return __uint_as_float(u & 0xFFFF0000u);
}
__device__ __forceinline__ float bf1(unsigned short u) {
    return __uint_as_float(((unsigned int)u) << 16);
}

// ---------------- front matter: b0 = edge-type tables, b1 = fe2 affine fold,
// b2..321 = B pre-swizzles for fe1 (768x64) and prep2 (256x128).
__global__ __launch_bounds__(256) void k_front(
    const float* __restrict__ e_emb1, const float* __restrict__ lew1,
    const float* __restrict__ ae1,
    const float* __restrict__ e_emb2, const float* __restrict__ lew2,
    const float* __restrict__ ae2,
    float* __restrict__ aet1, float* __restrict__ aet2,
    const float* __restrict__ w2, const float* __restrict__ outw,
    const float* __restrict__ b2, const float* __restrict__ posb,
    const float* __restrict__ outb, const float* __restrict__ temb,
    const float* __restrict__ posw,
    float* __restrict__ W2p, float* __restrict__ h0,
    float* __restrict__ tadd, float* __restrict__ padd,
    const float* __restrict__ w1, const float* __restrict__ B1,
    const float* __restrict__ B2,
    unsigned short* __restrict__ out_fe1, unsigned short* __restrict__ out_p2)
{
    __shared__ float M1[16];
    __shared__ float M2[4];
    int t = threadIdx.x;
    int b = blockIdx.x;
    if (b == 0) {
        if (t < 16) {
            int d = t >> 2, h = t & 3;
            float s = 0.f;
            for (int c = 0; c < 64; ++c) s += lew1[d * 256 + h * 64 + c] * ae1[h * 64 + c];
            M1[d * 4 + h] = s;
        }
        if (t < 4) {
            float s = 0.f;
            for (int c = 0; c < 64; ++c) s += lew2[t * 64 + c] * ae2[c];
            M2[t] = s;
        }
        __syncthreads();
        if (t < 16) {
            int ty = t >> 2, h = t & 3;
            float s = 0.f;
            for (int d = 0; d < 4; ++d) s += e_emb1[ty * 4 + d] * M1[d * 4 + h];
            aet1[ty * 4 + h] = s;
        }
        if (t < 4) {
            float s = 0.f;
            for (int d = 0; d < 4; ++d) s += e_emb2[t * 4 + d] * M2[d];
            aet2[t] = s;
        }
    } else if (b == 1) {
        // fuse1: W2p = w2 @ outw, plus projected affine add-vectors
        int i = t >> 2, jq = (t & 3) * 16;
        float a16[16];
#pragma unroll
        for (int u = 0; u < 16; ++u) a16[u] = 0.f;
        for (int k = 0; k < 64; ++k) {
            float a = w2[i * 64 + k];
            const float* op = outw + k * 64 + jq;
            float4 o0 = *(const float4*)op;
            float4 o1 = *(const float4*)(op + 4);
            float4 o2 = *(const float4*)(op + 8);
            float4 o3 = *(const float4*)(op + 12);
            a16[0] += a * o0.x;  a16[1] += a * o0.y;  a16[2] += a * o0.z;  a16[3] += a * o0.w;
            a16[4] += a * o1.x;  a16[5] += a * o1.y;  a16[6] += a * o1.z;  a16[7] += a * o1.w;
            a16[8] += a * o2.x;  a16[9] += a * o2.y;  a16[10] += a * o2.z; a16[11] += a * o2.w;
            a16[12] += a * o3.x; a16[13] += a * o3.y; a16[14] += a * o3.z; a16[15] += a * o3.w;
        }
#pragma unroll
        for (int u = 0; u < 16; ++u) W2p[i * 64 + jq + u] = a16[u];
        for (int e = t; e < 320; e += 256) {
            int g = e >> 6, j = e & 63;
            float s = 0.f;
            for (int k = 0; k < 64; ++k) {
                float v;
                if (g == 0) v = b2[k] + posb[k];
                else if (g <= 3) v = temb[(g - 1) * 64 + k];
                else v = posw[k];
                s += v * outw[k * 64 + j];
            }
            if (g == 0) h0[j] = s + outb[j];
            else if (g <= 3) tadd[(g - 1) * 64 + j] = s;
            else padd[j] = s;
        }
    } else {
        int idx = (b - 2) * 256 + t;
        if (idx < 768 * 64) {
            int k = idx >> 6, col = idx & 63;
            int c = k >> 6, kl = k & 63, kg = kl >> 3, j = kl & 7;
            out_fe1[((c * 8 + kg) * 64 + col) * 8 + j] = f2bf(w1[k * 64 + col]);
        } else {
            int i2 = idx - 768 * 64;          // 256*128 elements
            int k = i2 >> 7, col = i2 & 127;
            float v = (col < 64) ? B1[k * 64 + col] : B2[k * 64 + col - 64];
            int c = k >> 6, kl = k & 63, kg = kl >> 3, j = kl & 7;
            out_p2[((c * 8 + kg) * 128 + col) * 8 + j] = f2bf(v);
        }
    }
}

// ---- fuse stage 2: BLR = W2p @ [lin_w|res_w] -> frag-order bf16 (64x512),
//      plus projected add tables C0[512], T[3][512], P[512].
__global__ __launch_bounds__(64) void k_fuse2(
    const float* __restrict__ W2p, const float* __restrict__ h0,
    const float* __restrict__ tadd, const float* __restrict__ padd,
    const float* __restrict__ lin_w, const float* __restrict__ res_w,
    const float* __restrict__ bias, const float* __restrict__ res_b,
    unsigned short* __restrict__ bz, float* __restrict__ C0,
    float* __restrict__ T, float* __restrict__ P)
{
    __shared__ float bcol[64];
    int c = blockIdx.x;           // 0..511
    int j = threadIdx.x;          // 0..63
    int cL = c & 255;
    const float* Bsrc = (c < 256) ? lin_w : res_w;
    float bv = Bsrc[j * 256 + cL];
    bcol[j] = bv;
    __syncthreads();
    float s = 0.f;
#pragma unroll 8
    for (int k = 0; k < 64; ++k) s += W2p[j * 64 + k] * bcol[k];
    int kg = j >> 3, jj = j & 7, ct = c >> 7, cl = c & 127;
    bz[((ct * 8 + kg) * 128 + cl) * 8 + jj] = f2bf(s);
    float pc = h0[j] * bv;
    float p0 = tadd[j] * bv, p1 = tadd[64 + j] * bv, p2 = tadd[128 + j] * bv;
    float pp = padd[j] * bv;
#pragma unroll
    for (int k = 32; k; k >>= 1) {
        pc += __shfl_xor(pc, k, 64); p0 += __shfl_xor(p0, k, 64);
        p1 += __shfl_xor(p1, k, 64); p2 += __shfl_xor(p2, k, 64);
        pp += __shfl_xor(pp, k, 64);
    }
    if (j == 0) {
        C0[c] = pc + ((c >= 256) ? (bias[cL] + res_b[cL]) : 0.f);
        T[c] = p0; T[512 + c] = p1; T[1024 + c] = p2;
        P[c] = pp;
    }
}

// ------------- FE stage 1: relu(X@W1+b1) -> bf16. LDS-free direct fragment
// loads; block = 64 rows (4 waves x 16), 64 cols.
__global__ __launch_bounds__(256) void k_fe1(
    const float* __restrict__ feat, const unsigned short* __restrict__ bswz,
    const float* __restrict__ b1, unsigned short* __restrict__ t1b, int N)
{
    int t = threadIdx.x;
    int wv = t >> 6, lane = t & 63;
    int quad = lane >> 4, l16 = lane & 15;
    long rw = (long)blockIdx.x * 64 + wv * 16;
    long ra = rw + l16;
    if (ra >= N) ra = N - 1;
    const float* fbase = feat + ra * 768 + quad * 8;

    floatx4 acc[4];
#pragma unroll
    for (int i = 0; i < 4; ++i) acc[i] = (floatx4){0.f, 0.f, 0.f, 0.f};

    for (int ci = 0; ci < 12; ++ci) {
        const float* fc = fbase + ci * 64;
        short8 af[2];
#pragma unroll
        for (int s = 0; s < 2; ++s) {
            float4 x = *(const float4*)(fc + s * 32);
            float4 y = *(const float4*)(fc + s * 32 + 4);
            uint4 u = {cvtpk(x.x, x.y), cvtpk(x.z, x.w),
                       cvtpk(y.x, y.y), cvtpk(y.z, y.w)};
            af[s] = *(short8*)&u;
        }
#pragma unroll
        for (int s = 0; s < 2; ++s) {
            int kg = s * 4 + quad;
#pragma unroll
            for (int ct = 0; ct < 4; ++ct) {
                short8 bfrag = *(const short8*)&bswz[
                    ((ci * 8 + kg) * 64 + ct * 16 + l16) * 8];
                acc[ct] = __builtin_amdgcn_mfma_f32_16x16x32_bf16(
                    af[s], bfrag, acc[ct], 0, 0, 0);
            }
        }
    }
#pragma unroll
    for (int ct = 0; ct < 4; ++ct) {
        float bb = b1[ct * 16 + l16];
#pragma unroll
        for (int r = 0; r < 4; ++r) {
            long m = rw + quad * 4 + r;
            if (m < N)
                t1b[m * 64 + ct * 16 + l16] = f2bf(fmaxf(acc[ct][r] + bb, 0.f));
        }
    }
}

// ------------- prep1: t1b[Nx64] @ BLR[64x512] + fused fe2-tail adds + fused
// attention dots (a_src1/a_dst1 from in-register fp32 vals).
__global__ __launch_bounds__(256) void k_prep1(
    const unsigned short* __restrict__ A, const unsigned short* __restrict__ bswz,
    const float* __restrict__ C0, const float* __restrict__ T,
    const float* __restrict__ P, const int* __restrict__ ntypes,
    const float* __restrict__ pos,
    const float* __restrict__ att_s, const float* __restrict__ att_d,
    unsigned short* __restrict__ xsb, unsigned short* __restrict__ resp,
    float* __restrict__ a_src, float* __restrict__ a_dst, int N)
{
    int t = threadIdx.x;
    int wv = t >> 6, lane = t & 63;
    int quad = lane >> 4, l16 = lane & 15;
    long rw = (long)blockIdx.x * 64 + wv * 16;
    int by = blockIdx.y;
    long ra = rw + l16;
    if (ra >= N) ra = N - 1;
    const unsigned short* abase = A + ra * 64 + quad * 8;

    floatx4 acc[8];
#pragma unroll
    for (int i = 0; i < 8; ++i) acc[i] = (floatx4){0.f, 0.f, 0.f, 0.f};

    short8 af[2];
    af[0] = *(const short8*)(abase);
    af[1] = *(const short8*)(abase + 32);
#pragma unroll
    for (int s = 0; s < 2; ++s) {
        int kg = s * 4 + quad;
#pragma unroll
        for (int c8 = 0; c8 < 8; ++c8) {
            short8 bfrag = *(const short8*)&bswz[
                ((by * 8 + kg) * 128 + c8 * 16 + l16) * 8];
            acc[c8] = __builtin_amdgcn_mfma_f32_16x16x32_bf16(
                af[s], bfrag, acc[c8], 0, 0, 0);
        }
    }
    int nta[4];
    float posa[4];
#pragma unroll
    for (int r = 0; r < 4; ++r) {
        long m = rw + quad * 4 + r;
        if (m < N) { nta[r] = ntypes[m]; posa[r] = pos[m]; }
        else       { nta[r] = 0; posa[r] = 0.f; }
    }
    bool isl = (by < 2);
    int cb = by * 128;
    float ps[2][4] = {{0.f,0.f,0.f,0.f},{0.f,0.f,0.f,0.f}};
    float pd[2][4] = {{0.f,0.f,0.f,0.f},{0.f,0.f,0.f,0.f}};
#pragma unroll
    for (int c8 = 0; c8 < 8; ++c8) {
        int gc = cb + c8 * 16 + l16;
        float c0 = C0[gc], pcf = P[gc];
        float as = 0.f, ad = 0.f;
        if (isl) { as = att_s[gc]; ad = att_d[gc]; }
        int hh = c8 >> 2;
#pragma unroll
        for (int r = 0; r < 4; ++r) {
            long m = rw + quad * 4 + r;
            float val = acc[c8][r] + c0 + T[nta[r] * 512 + gc] + posa[r] * pcf;
            if (m < N) {
                if (isl) xsb[m * 256 + gc] = f2bf(val);
                else     resp[m * 256 + gc - 256] = f2bf(val);
            }
            ps[hh][r] += val * as;
            pd[hh][r] += val * ad;
        }
    }
    if (isl) {
#pragma unroll
        for (int h = 0; h < 2; ++h)
#pragma unroll
            for (int r = 0; r < 4; ++r) {
                float a = ps[h][r], b = pd[h][r];
#pragma unroll
                for (int k = 1; k < 16; k <<= 1) {
                    a += __shfl_xor(a, k, 64);
                    b += __shfl_xor(b, k, 64);
                }
                long m = rw + quad * 4 + r;
                if (l16 == 0 && m < N) {
                    int h4 = by * 2 + h;
                    a_src[m * 4 + h4] = a;
                    a_dst[m * 4 + h4] = b;
                }
            }
    }
}

// ------------- prep2: hid1b[Nx256] @ [lin|res][256x128] + fused attention
// dots for layer 2. cols<64 -> xs2 bf16; cols>=64 -> res fp32 (+bias+res_b).
__global__ __launch_bounds__(256) void k_prep2(
    const unsigned short* __restrict__ A, const unsigned short* __restrict__ bswz,
    const float* __restrict__ bias, const float* __restrict__ res_b,
    const float* __restrict__ att_s, const float* __restrict__ att_d,
    unsigned short* __restrict__ xsb, float* __restrict__ resp,
    float* __restrict__ a_src, float* __restrict__ a_dst, int N)
{
    int t = threadIdx.x;
    int wv = t >> 6, lane = t & 63;
    int quad = lane >> 4, l16 = lane & 15;
    long rw = (long)blockIdx.x * 64 + wv * 16;
    long ra = rw + l16;
    if (ra >= N) ra = N - 1;
    const unsigned short* abase = A + ra * 256 + quad * 8;

    floatx4 acc[8];
#pragma unroll
    for (int i = 0; i < 8; ++i) acc[i] = (floatx4){0.f, 0.f, 0.f, 0.f};

    for (int ci = 0; ci < 4; ++ci) {
        short8 af[2];
        af[0] = *(const short8*)(abase + ci * 64);
        af[1] = *(const short8*)(abase + ci * 64 + 32);
#pragma unroll
        for (int s = 0; s < 2; ++s) {
            int kg = s * 4 + quad;
#pragma unroll
            for (int c8 = 0; c8 < 8; ++c8) {
                short8 bfrag = *(const short8*)&bswz[
                    ((ci * 8 + kg) * 128 + c8 * 16 + l16) * 8];
                acc[c8] = __builtin_amdgcn_mfma_f32_16x16x32_bf16(
                    af[s], bfrag, acc[c8], 0, 0, 0);
            }
        }
    }
    float ps[4] = {0.f,0.f,0.f,0.f}, pd[4] = {0.f,0.f,0.f,0.f};
#pragma unroll
    for (int c8 = 0; c8 < 8; ++c8) {
        int gc = c8 * 16 + l16;
        bool isl = gc < 64;
        float badd = isl ? 0.f : (bias[gc - 64] + res_b[gc - 64]);
        float as = isl ? att_s[gc] : 0.f;
        float ad = isl ? att_d[gc] : 0.f;
#pragma unroll
        for (int r = 0; r < 4; ++r) {
            long m = rw + quad * 4 + r;
            float val = acc[c8][r];
            if (m < N) {
                if (isl) xsb[m * 64 + gc] = f2bf(val);
                else     resp[m * 64 + gc - 64] = val + badd;
            }
            if (isl) { ps[r] += val * as; pd[r] += val * ad; }
        }
    }
#pragma unroll
    for (int r = 0; r < 4; ++r) {
        float a = ps[r], b = pd[r];
#pragma unroll
        for (int k = 1; k < 16; k <<= 1) {
            a += __shfl_xor(a, k, 64);
            b += __shfl_xor(b, k, 64);
        }
        long m = rw + quad * 4 + r;
        if (l16 == 0 && m < N) { a_src[m] = a; a_dst[m] = b; }
    }
}

// ---------------------------------------------------------------- CSR build
__global__ __launch_bounds__(256) void k_count(
    const int* __restrict__ dst, const int* __restrict__ et,
    int* __restrict__ cnt_t, int E)
{
    int e = blockIdx.x * 256 + threadIdx.x;
    if (e < E) atomicAdd(&cnt_t[dst[e] * 4 + et[e]], 1);
}

__global__ __launch_bounds__(256) void k_scan1(
    const int* __restrict__ cnt_t, int* __restrict__ row_off,
    int* __restrict__ blk_sums, int N)
{
    __shared__ int s[256];
    int t = threadIdx.x;
    int i = blockIdx.x * 256 + t;
    int v = 0;
    if (i < N) v = cnt_t[4 * i] + cnt_t[4 * i + 1] + cnt_t[4 * i + 2] + cnt_t[4 * i + 3];
    s[t] = v;
    __syncthreads();
    for (int off = 1; off < 256; off <<= 1) {
        int x = 0;
        if (t >= off) x = s[t - off];
        __syncthreads();
        s[t] += x;
        __syncthreads();
    }
    if (i < N) row_off[i] = s[t] - v;
    if (t == 255) blk_sums[blockIdx.x] = s[255];
}

// scan3 with scan2 absorbed: each block re-sums blk_sums[0..bid-1] (nb<=256).
__global__ __launch_bounds__(256) void k_scan3(
    int* __restrict__ row_off, int* __restrict__ cursor,
    const int* __restrict__ blk_sums, int N, int E)
{
    __shared__ int s[256];
    int t = threadIdx.x;
    int bid = blockIdx.x;
    s[t] = (t < bid) ? blk_sums[t] : 0;
    __syncthreads();
    for (int off = 128; off; off >>= 1) {
        if (t < off) s[t] += s[t + off];
        __syncthreads();
    }
    int prev = s[0];
    int i = bid * 256 + t;
    if (i < N) {
        int o = row_off[i] + prev;
        row_off[i] = o;
        cursor[i] = o;
    }
    if (i == 0) row_off[N] = E;
}

// scatter + gat1 edge-weight precompute: w[pos][h] = exp(lrelu(a_src[s,h] +
// a_dst[d,h] + aet1[ty,h])), fp32 (bitwise identical to the old in-gat1 calc).
__global__ __launch_bounds__(256) void k_scatter(
    const int* __restrict__ src, const int* __restrict__ dst,
    const int* __restrict__ et, int* __restrict__ cursor,
    int* __restrict__ csr_pack,
    const float* __restrict__ a_src, const float* __restrict__ a_dst,
    const float* __restrict__ aet1, float* __restrict__ wbuf, int E)
{
    int e = blockIdx.x * 256 + threadIdx.x;
    if (e < E) {
        int d = dst[e];
        int s = src[e];
        int ty = et[e];
        int pos = atomicAdd(&cursor[d], 1);
        csr_pack[pos] = s | (ty << 28);
        float4 as4 = *(const float4*)&a_src[s * 4];
        float4 ad4 = *(const float4*)&a_dst[d * 4];
        float4 ae = *(const float4*)&aet1[ty * 4];
        float a0 = as4.x + ad4.x + ae.x;
        float a1 = as4.y + ad4.y + ae.y;
        float a2 = as4.z + ad4.z + ae.z;
        float a3 = as4.w + ad4.w + ae.w;
        a0 = LRELU(a0); a1 = LRELU(a1); a2 = LRELU(a2); a3 = LRELU(a3);
        float4 w4 = make_float4(expf(a0), expf(a1), expf(a2), expf(a3));
        *(float4*)&wbuf[(long)pos * 4] = w4;
    }
}

// ---------------- GAT layer 1: 128 thr = 2 waves; wave w owns heads 2w,2w+1.
// Edge weights preloaded from wbuf; gather 4 edges/wave-iter dwordx4.
__global__ __launch_bounds__(128) void k_gat1(
    const unsigned short* __restrict__ xs1b, const float* __restrict__ a_src,
    const float* __restrict__ a_dst, const int* __restrict__ row_off,
    const int* __restrict__ csr_pack, const float* __restrict__ wbuf,
    const int* __restrict__ cnt_t, const float* __restrict__ aet1,
    const float* __restrict__ ln_g, const float* __restrict__ ln_b,
    const unsigned short* __restrict__ res, unsigned short* __restrict__ out)
{
    __shared__ __align__(16) float4 ws[2][64];
    __shared__ float2 aetp[2][4];
    __shared__ float red[4];
    int n = blockIdx.x;
    int t = threadIdx.x;
    int w = t >> 6, c = t & 63;
    int lc = c & 15, g = c >> 4;
    int h0 = 2 * w;
    if (t < 8) {
        int w2 = t >> 2, ty = t & 3;
        aetp[w2][ty] = make_float2(aet1[ty * 4 + 2 * w2], aet1[ty * 4 + 2 * w2 + 1]);
    }
    int off = row_off[n], deg = row_off[n + 1] - off;
    float2 a_d = *(const float2*)&a_dst[n * 4 + h0];
    __syncthreads();
    float ael0 = 0.f, ael1 = 0.f;
    int degc = 0;
#pragma unroll
    for (int ty = 0; ty < 4; ++ty) {
        int ct = cnt_t[n * 4 + ty];
        degc += ct;
        float2 ae = aetp[w][ty];
        ael0 += (float)ct * ae.x;
        ael1 += (float)ct * ae.y;
    }
    float inv = (degc > 0) ? 1.f / (float)degc : 1.f;
    float2 a_s_self = *(const float2*)&a_src[n * 4 + h0];
    float al0 = a_s_self.x + a_d.x + ael0 * inv;
    float al1 = a_s_self.y + a_d.y + ael1 * inv;
    al0 = LRELU(al0); al1 = LRELU(al1);
    float wself0 = expf(al0), wself1 = expf(al1);

    int col0 = w * 128 + lc * 8;                    // 8 cols per lane
    const unsigned short* xrow = xs1b + col0;       // + s*256 per gather
    float acc[8];
#pragma unroll
    for (int j = 0; j < 8; ++j) acc[j] = 0.f;
    float dp0 = 0.f, dp1 = 0.f;

    for (int base = 0; base < deg; base += 64) {
        int cnt = min(64, deg - base);
        float w0 = 0.f, w1 = 0.f;
        int s = 0;
        if (c < cnt) {
            int idx = off + base + c;
            int pk = csr_pack[idx];
            s = pk & 0x0FFFFFFF;
            float2 wv = *(const float2*)&wbuf[(long)idx * 4 + 2 * w];
            w0 = wv.x; w1 = wv.y;
        }
        dp0 += w0; dp1 += w1;
        ws[w][c] = make_float4(w0, w1, __int_as_float(s), 0.f);
        int cr = (cnt + 7) & ~7;
        for (int i = 0; i < cr; i += 8) {
#pragma unroll
            for (int u = 0; u < 2; ++u) {
                float4 p = ws[w][i + u * 4 + g];
                float wl = (lc < 8) ? p.x : p.y;
                uint4 q = *(const uint4*)&xrow[(long)__float_as_int(p.z) * 256];
                acc[0] += wl * bflo(q.x); acc[1] += wl * bfhi(q.x);
                acc[2] += wl * bflo(q.y); acc[3] += wl * bfhi(q.y);
                acc[4] += wl * bflo(q.z); acc[5] += wl * bfhi(q.z);
                acc[6] += wl * bflo(q.w); acc[7] += wl * bfhi(q.w);
            }
        }
    }
#pragma unroll
    for (int k = 32; k; k >>= 1) {
        dp0 += __shfl_xor(dp0, k, 64);
        dp1 += __shfl_xor(dp1, k, 64);
    }
#pragma unroll
    for (int j = 0; j < 8; ++j) {
        acc[j] += __shfl_xor(acc[j], 16, 64);
        acc[j] += __shfl_xor(acc[j], 32, 64);
    }
    uint4 us = *(const uint4*)&xrow[(long)n * 256];
    float wself_l = (lc < 8) ? wself0 : wself1;
    acc[0] += wself_l * bflo(us.x); acc[1] += wself_l * bfhi(us.x);
    acc[2] += wself_l * bflo(us.y); acc[3] += wself_l * bfhi(us.y);
    acc[4] += wself_l * bflo(us.z); acc[5] += wself_l * bfhi(us.z);
    acc[6] += wself_l * bflo(us.w); acc[7] += wself_l * bfhi(us.w);
    float dsum = ((lc < 8) ? dp0 + wself0 : dp1 + wself1) + 1e-16f;
    float rd = 1.f / dsum;
    uint4 ur = *(const uint4*)&res[(long)n * 256 + col0];
    float v[8];
    v[0] = acc[0] * rd + bflo(ur.x); v[1] = acc[1] * rd + bfhi(ur.x);
    v[2] = acc[2] * rd + bflo(ur.y); v[3] = acc[3] * rd + bfhi(ur.y);
    v[4] = acc[4] * rd + bflo(ur.z); v[5] = acc[5] * rd + bfhi(ur.z);
    v[6] = acc[6] * rd + bflo(ur.w); v[7] = acc[7] * rd + bfhi(ur.w);
    float s1 = 0.f, s2 = 0.f;
#pragma unroll
    for (int j = 0; j < 8; ++j) { s1 += v[j]; s2 += v[j] * v[j]; }
#pragma unroll
    for (int k = 32; k; k >>= 1) {
        s1 += __shfl_xor(s1, k, 64);
        s2 += __shfl_xor(s2, k, 64);
    }
    if (c == 0) { red[w] = s1 * 0.25f; red[2 + w] = s2 * 0.25f; }
    __syncthreads();
    float mu = (red[0] + red[1]) * (1.f / 256.f);
    float var = (red[2] + red[3]) * (1.f / 256.f) - mu * mu;
    float rs = rsqrtf(var + 1e-5f);
    if (g == 0) {
        float4 lg0 = *(const float4*)&ln_g[col0];
        float4 lg1 = *(const float4*)&ln_g[col0 + 4];
        float4 lb0 = *(const float4*)&ln_b[col0];
        float4 lb1 = *(const float4*)&ln_b[col0 + 4];
        float y[8];
        y[0] = fmaxf((v[0] - mu) * rs * lg0.x + lb0.x, 0.f);
        y[1] = fmaxf((v[1] - mu) * rs * lg0.y + lb0.y, 0.f);
        y[2] = fmaxf((v[2] - mu) * rs * lg0.z + lb0.z, 0.f);
        y[3] = fmaxf((v[3] - mu) * rs * lg0.w + lb0.w, 0.f);
        y[4] = fmaxf((v[4] - mu) * rs * lg1.x + lb1.x, 0.f);
        y[5] = fmaxf((v[5] - mu) * rs * lg1.y + lb1.y, 0.f);
        y[6] = fmaxf((v[6] - mu) * rs * lg1.z + lb1.z, 0.f);
        y[7] = fmaxf((v[7] - mu) * rs * lg1.w + lb1.w, 0.f);
        uint4 o;
        o.x = cvtpk(y[0], y[1]); o.y = cvtpk(y[2], y[3]);
        o.z = cvtpk(y[4], y[5]); o.w = cvtpk(y[6], y[7]);
        *(uint4*)&out[(long)n * 256 + col0] = o;
    }
}

// ------------------- GAT layer 2 (H=1, C=64): 2 nodes per 128-thread block.
__global__ __launch_bounds__(128) void k_gat2(
    const unsigned short* __restrict__ xs2b, const float* __restrict__ a_src,
    const float* __restrict__ a_dst, const int* __restrict__ row_off,
    const int* __restrict__ csr_pack,
    const int* __restrict__ cnt_t, const float* __restrict__ aet2,
    const float* __restrict__ ln_g, const float* __restrict__ ln_b,
    float* io, int N)
{
    __shared__ __align__(8) float2 ws[2][64];
    int v_ = threadIdx.x >> 6, c = threadIdx.x & 63;
    int n = blockIdx.x * 2 + v_;
    if (n >= N) return;
    int lc = c & 15, g = c >> 4;
    int off = row_off[n], deg = row_off[n + 1] - off;
    float a_d = a_dst[n];
    float ael = 0.f;
    int degc = 0;
#pragma unroll
    for (int ty = 0; ty < 4; ++ty) {
        int ct = cnt_t[n * 4 + ty];
        degc += ct;
        ael += (float)ct * aet2[ty];
    }
    ael *= (degc > 0 ? 1.f / (float)degc : 1.f);
    float al = a_src[n] + a_d + ael;
    al = LRELU(al);
    float wself = expf(al);

    int colb = lc * 4;
    const unsigned short* xrow = xs2b + colb;
    float acc[4] = {0.f, 0.f, 0.f, 0.f};
    float dp = 0.f;
    for (int base = 0; base < deg; base += 64) {
        int cnt = min(64, deg - base);
        float we = 0.f;
        int s = 0;
        if (c < cnt) {
            int pk = csr_pack[off + base + c];
            s = pk & 0x0FFFFFFF;
            int ty = ((unsigned)pk) >> 28;
            float a = a_src[s] + a_d + aet2[ty];
            a = LRELU(a);
            we = expf(a);
        }
        dp += we;
        ws[v_][c] = make_float2(we, __int_as_float(s));
        int cr = (cnt + 7) & ~7;
        for (int i = 0; i < cr; i += 8) {
#pragma unroll
            for (int u = 0; u < 2; ++u) {
                float2 p = ws[v_][i + u * 4 + g];
                uint2 q = *(const uint2*)&xrow[(long)__float_as_int(p.y) * 64];
                acc[0] += p.x * bflo(q.x); acc[1] += p.x * bfhi(q.x);
                acc[2] += p.x * bflo(q.y); acc[3] += p.x * bfhi(q.y);
            }
        }
    }
#pragma unroll
    for (int k = 32; k; k >>= 1) dp += __shfl_xor(dp, k, 64);
#pragma unroll
    for (int j = 0; j < 4; ++j) {
        acc[j] += __shfl_xor(acc[j], 16, 64);
        acc[j] += __shfl_xor(acc[j], 32, 64);
    }
    uint2 us = *(const uint2*)&xrow[(long)n * 64];
    acc[0] += wself * bflo(us.x); acc[1] += wself * bfhi(us.x);
    acc[2] += wself * bflo(us.y); acc[3] += wself * bfhi(us.y);
    float dsum = dp + wself + 1e-16f;
    float rd = 1.f / dsum;
    float4 r = *(const float4*)&io[(long)n * 64 + colb];
    float v[4];
    v[0] = acc[0] * rd + r.x; v[1] = acc[1] * rd + r.y;
    v[2] = acc[2] * rd + r.z; v[3] = acc[3] * rd + r.w;
    float s1 = v[0] + v[1] + v[2] + v[3];
    float s2 = v[0] * v[0] + v[1] * v[1] + v[2] * v[2] + v[3] * v[3];
#pragma unroll
    for (int k = 32; k; k >>= 1) {
        s1 += __shfl_xor(s1, k, 64);
        s2 += __shfl_xor(s2, k, 64);
    }
    float mu = s1 * (1.f / 256.f);
    float var = s2 * (1.f / 256.f) - mu * mu;
    float rs = rsqrtf(var + 1e-5f);
    if (g == 0) {
        float4 lg = *(const float4*)&ln_g[colb];
        float4 lb = *(const float4*)&ln_b[colb];
        float4 y;
        y.x = (v[0] - mu) * rs * lg.x + lb.x;
        y.y = (v[1] - mu) * rs * lg.y + lb.y;
        y.z = (v[2] - mu) * rs * lg.z + lb.z;
        y.w = (v[3] - mu) * rs * lg.w + lb.w;
        *(float4*)&io[(long)n * 64 + colb] = y;
    }
}

// --------------------------------------------------------------- classifier
__global__ __launch_bounds__(256) void k_cls(
    const float* __restrict__ hid2, const int* __restrict__ asp,
    const float* __restrict__ w, const float* __restrict__ b,
    float* __restrict__ out)
{
    int g = blockIdx.x * 256 + threadIdx.x;
    int i = g / 3, j = g - i * 3;
    int a = asp[i];
    float acc = b[j];
#pragma unroll 8
    for (int cc = 0; cc < 64; ++cc) acc += hid2[(long)a * 64 + cc] * w[cc * 3 + j];
    out[i * 3 + j] = acc;
}

extern "C" void kernel_launch(void* const* d_in, const int* in_sizes, int n_in,
                              void* d_out, int out_size, void* d_ws, size_t ws_size,
                              hipStream_t stream)
{
    const float* features    = (const float*)d_in[0];
    const int*   edge_index  = (const int*)d_in[1];
    const int*   aspect      = (const int*)d_in[2];
    const int*   etypes      = (const int*)d_in[3];
    const int*   ntypes      = (const int*)d_in[4];
    const float* pos         = (const float*)d_in[5];
    const float* fe_w1       = (const float*)d_in[6];
    const float* fe_b1       = (const float*)d_in[7];
    const float* fe_w2       = (const float*)d_in[8];
    const float* fe_b2       = (const float*)d_in[9];
    const float* fe_pos_w    = (const float*)d_in[10];
    const float* fe_pos_b    = (const float*)d_in[11];
    const float* fe_type_emb = (const float*)d_in[12];
    const float* fe_out_w    = (const float*)d_in[13];
    const float* fe_out_b    = (const float*)d_in[14];
    const float* g1_lin_w    = (const float*)d_in[15];
    const float* g1_att_src  = (const float*)d_in[16];
    const float* g1_att_dst  = (const float*)d_in[17];
    const float* g1_edge_emb = (const float*)d_in[18];
    const float* g1_lin_edge = (const float*)d_in[19];
    const float* g1_att_edge = (const float*)d_in[20];
    const float* g1_bias     = (const float*)d_in[21];
    const float* g1_res_w    = (const float*)d_in[22];
    const float* g1_res_b    = (const float*)d_in[23];
    const float* g1_ln_g     = (const float*)d_in[24];
    const float* g1_ln_b     = (const float*)d_in[25];
    const float* g2_lin_w    = (const float*)d_in[26];
    const float* g2_att_src  = (const float*)d_in[27];
    const float* g2_att_dst  = (const float*)d_in[28];
    const float* g2_edge_emb = (const float*)d_in[29];
    const float* g2_lin_edge = (const float*)d_in[30];
    const float* g2_att_edge = (const float*)d_in[31];
    const float* g2_bias     = (const float*)d_in[32];
    const float* g2_res_w    = (const float*)d_in[33];
    const float* g2_res_b    = (const float*)d_in[34];
    const float* g2_ln_g     = (const float*)d_in[35];
    const float* g2_ln_b     = (const float*)d_in[36];
    const float* cls_w       = (const float*)d_in[37];
    const float* cls_b       = (const float*)d_in[38];

    const int N = in_sizes[0] / 768;   // 50000
    const int E = in_sizes[1] / 2;     // 800000
    const int* src = edge_index;
    const int* dst = edge_index + E;

    char* wsb = (char*)d_ws;
    size_t off = 0;
    auto alloc = [&](size_t bytes) -> char* {
        char* p = wsb + off;
        off += (bytes + 255) & ~(size_t)255;
        return p;
    };
    unsigned short* t1b  = (unsigned short*)alloc((size_t)N * 64 * 2);
    unsigned short* xs1b = (unsigned short*)alloc((size_t)N * 256 * 2);
    unsigned short* xs2b = (unsigned short*)alloc((size_t)N * 64 * 2);
    unsigned short* hid1b= (unsigned short*)alloc((size_t)N * 256 * 2);
    unsigned short* rp1  = (unsigned short*)alloc((size_t)N * 256 * 2);  // res1 bf16
    float* rp2     = (float*)alloc((size_t)N * 64 * 4);   // res_pre2, then hid2
    float* a_src1  = (float*)alloc((size_t)N * 4 * 4);
    float* a_dst1  = (float*)alloc((size_t)N * 4 * 4);
    float* a_src2  = (float*)alloc((size_t)N * 4);
    float* a_dst2  = (float*)alloc((size_t)N * 4);
    int*   cnt_t   = (int*)alloc((size_t)N * 4 * 4);
    int*   row_off = (int*)alloc((size_t)(N + 1) * 4);
    int*   cursor  = (int*)alloc((size_t)N * 4);
    int*   blk     = (int*)alloc(1024);
    int*   csr_pack= (int*)alloc((size_t)E * 4);
    float* wbuf    = (float*)alloc((size_t)E * 4 * 4);    // per-edge weights
    float* aet1    = (float*)alloc(64);
    float* aet2    = (float*)alloc(64);
    unsigned short* bz_fe1 = (unsigned short*)alloc(768 * 64 * 2);
    unsigned short* bz_p1  = (unsigned short*)alloc(64 * 512 * 2);
    unsigned short* bz_p2  = (unsigned short*)alloc(256 * 128 * 2);
    float* W2p     = (float*)alloc(64 * 64 * 4);
    float* h0v     = (float*)alloc(64 * 4);
    float* taddv   = (float*)alloc(192 * 4);
    float* paddv   = (float*)alloc(64 * 4);
    float* C0t     = (float*)alloc(512 * 4);
    float* Tt      = (float*)alloc(3 * 512 * 4);
    float* Pt      = (float*)alloc(512 * 4);

    hipMemsetAsync(cnt_t, 0, (size_t)N * 4 * 4, stream);

    int mb = (N + 63) / 64;   // 782 row-tiles
    int eblk = (E + 255) / 256;
    int nb = (N + 255) / 256;

    k_front<<<322, 256, 0, stream>>>(
        g1_edge_emb, g1_lin_edge, g1_att_edge,
        g2_edge_emb, g2_lin_edge, g2_att_edge, aet1, aet2,
        fe_w2, fe_out_w, fe_b2, fe_pos_b, fe_out_b, fe_type_emb, fe_pos_w,
        W2p, h0v, taddv, paddv,
        fe_w1, g2_lin_w, g2_res_w, bz_fe1, bz_p2);
    k_fuse2<<<512, 64, 0, stream>>>(W2p, h0v, taddv, paddv, g1_lin_w, g1_res_w,
                                    g1_bias, g1_res_b, bz_p1, C0t, Tt, Pt);
    k_count<<<eblk, 256, 0, stream>>>(dst, etypes, cnt_t, E);
    k_scan1<<<nb, 256, 0, stream>>>(cnt_t, row_off, blk, N);
    k_scan3<<<nb, 256, 0, stream>>>(row_off, cursor, blk, N, E);
    k_fe1<<<mb, 256, 0, stream>>>(features, bz_fe1, fe_b1, t1b, N);
    k_prep1<<<dim3(mb, 4), 256, 0, stream>>>(
        t1b, bz_p1, C0t, Tt, Pt, ntypes, pos, g1_att_src, g1_att_dst,
        xs1b, rp1, a_src1, a_dst1, N);
    k_scatter<<<eblk, 256, 0, stream>>>(src, dst, etypes, cursor, csr_pack,
                                        a_src1, a_dst1, aet1, wbuf, E);
    k_gat1<<<N, 128, 0, stream>>>(xs1b, a_src1, a_dst1, row_off, csr_pack, wbuf,
                                  cnt_t, aet1, g1_ln_g, g1_ln_b, rp1, hid1b);
    k_prep2<<<mb, 256, 0, stream>>>(hid1b, bz_p2, g2_bias, g2_res_b,
                                    g2_att_src, g2_att_dst, xs2b, rp2,
                                    a_src2, a_dst2, N);
    k_gat2<<<(N + 1) / 2, 128, 0, stream>>>(xs2b, a_src2, a_dst2, row_off,
                                            csr_pack, cnt_t, aet2,
                                            g2_ln_g, g2_ln_b, rp2, N);
    k_cls<<<(out_size + 255) / 256, 256, 0, stream>>>(rp2, aspect, cls_w, cls_b,
                                                      (float*)d_out);
}

// Round 5
// 593.031 us; speedup vs baseline: 1.0816x; 1.0202x over previous
//
#include <hip/hip_runtime.h>

// SimplifiedHAFE on MI355X — round 11: fe1+prep1 fusion + front consolidation.
//  (a) k_fp1 = fe1 GEMM -> LDS bf16 tile (64x72-padded) -> prep1's 4 column
//      quarters from registers. t1b round-trip (32 MB) + 1 launch deleted.
//  (b) k_front now also does fuse2 (via s=w2@(outw@bcol) identity — no W2p
//      stage, fuse1 deleted entirely) and k_count (grid-stride tail blocks).
//      Launch count 14 -> 10 (incl. memset).
//  (c) Rounds 7-10 retained: LDS-free prep2, wide gathers, hoisted gat1 edge
//      weights, fused attention dots, bf16 intermediates.

#define LRELU(x) ((x) > 0.f ? (x) : 0.2f * (x))

typedef __attribute__((ext_vector_type(8))) short short8;
typedef __attribute__((ext_vector_type(4))) float floatx4;

__device__ __forceinline__ unsigned short f2bf(float x) {
    union { float f; unsigned int u; } v; v.f = x;
    unsigned int r = (v.u + 0x7FFFu + ((v.u >> 16) & 1u)) >> 16;  // RNE
    return (unsigned short)r;
}
// pack 2 fp32 -> 2 bf16 (RNE) in one VALU; lo in low 16 bits
__device__ __forceinline__ unsigned int cvtpk(float lo, float hi) {
    unsigned int r;
    asm("v_cvt_pk_bf16_f32 %0, %1, %2" : "=v"(r) : "v"(lo), "v"(hi));
    return r;
}
__device__ __forceinline__ float bflo(unsigned int u) {
    return __uint_as_float(u << 16);
}
__device__ __forceinline__ float bfhi(unsigned int u) {
    return __uint_as_float(u & 0xFFFF0000u);
}
__device__ __forceinline__ float bf1(unsigned short u) {
    return __uint_as_float(((unsigned int)u) << 16);
}

// ---------------- front matter (grid = 705):
//   b0          : edge-type attention tables (aet1, aet2)
//   b1..320     : B pre-swizzles for fe1 (768x64) and prep2 (256x128)
//   b321..448   : fuse2 — bz_p1 = (w2@outw)@[lin|res] frag-order bf16 + C0/T/P
//                 (4 cols per block, 1 col per wave; W2p eliminated via
//                  y[m] = outw[m,:]@bcol, s_j = w2[j,:]@y)
//   b449..704   : edge count histogram (grid-stride; cnt_t pre-zeroed)
__global__ __launch_bounds__(256) void k_front(
    const float* __restrict__ e_emb1, const float* __restrict__ lew1,
    const float* __restrict__ ae1,
    const float* __restrict__ e_emb2, const float* __restrict__ lew2,
    const float* __restrict__ ae2,
    float* __restrict__ aet1, float* __restrict__ aet2,
    const float* __restrict__ w1, const float* __restrict__ B1,
    const float* __restrict__ B2,
    unsigned short* __restrict__ out_fe1, unsigned short* __restrict__ out_p2,
    const float* __restrict__ w2, const float* __restrict__ outw,
    const float* __restrict__ b2, const float* __restrict__ posb,
    const float* __restrict__ outb, const float* __restrict__ temb,
    const float* __restrict__ posw,
    const float* __restrict__ lin_w, const float* __restrict__ res_w,
    const float* __restrict__ bias, const float* __restrict__ res_b,
    unsigned short* __restrict__ bz, float* __restrict__ C0,
    float* __restrict__ T, float* __restrict__ P,
    const int* __restrict__ dst, const int* __restrict__ et,
    int* __restrict__ cnt_t, int E)
{
    int t = threadIdx.x;
    int b = blockIdx.x;
    if (b == 0) {
        __shared__ float M1[16];
        __shared__ float M2[4];
        if (t < 16) {
            int d = t >> 2, h = t & 3;
            float s = 0.f;
            for (int c = 0; c < 64; ++c) s += lew1[d * 256 + h * 64 + c] * ae1[h * 64 + c];
            M1[d * 4 + h] = s;
        }
        if (t < 4) {
            float s = 0.f;
            for (int c = 0; c < 64; ++c) s += lew2[t * 64 + c] * ae2[c];
            M2[t] = s;
        }
        __syncthreads();
        if (t < 16) {
            int ty = t >> 2, h = t & 3;
            float s = 0.f;
            for (int d = 0; d < 4; ++d) s += e_emb1[ty * 4 + d] * M1[d * 4 + h];
            aet1[ty * 4 + h] = s;
        }
        if (t < 4) {
            float s = 0.f;
            for (int d = 0; d < 4; ++d) s += e_emb2[t * 4 + d] * M2[d];
            aet2[t] = s;
        }
    } else if (b <= 320) {
        int idx = (b - 1) * 256 + t;
        if (idx < 768 * 64) {
            int k = idx >> 6, col = idx & 63;
            int c = k >> 6, kl = k & 63, kg = kl >> 3, j = kl & 7;
            out_fe1[((c * 8 + kg) * 64 + col) * 8 + j] = f2bf(w1[k * 64 + col]);
        } else {
            int i2 = idx - 768 * 64;          // 256*128 elements
            int k = i2 >> 7, col = i2 & 127;
            float v = (col < 64) ? B1[k * 64 + col] : B2[k * 64 + col - 64];
            int c = k >> 6, kl = k & 63, kg = kl >> 3, j = kl & 7;
            out_p2[((c * 8 + kg) * 128 + col) * 8 + j] = f2bf(v);
        }
    } else if (b <= 448) {
        __shared__ float sb[4][64];
        __shared__ float sy[4][64];
        int wv = t >> 6, j = t & 63;
        int c = (b - 321) * 4 + wv;       // 0..511
        int cL = c & 255;
        const float* Bsrc = (c < 256) ? lin_w : res_w;
        float bv = Bsrc[j * 256 + cL];
        sb[wv][j] = bv;
        __syncthreads();
        float yj = 0.f;
#pragma unroll 8
        for (int k = 0; k < 64; ++k) yj += outw[j * 64 + k] * sb[wv][k];
        sy[wv][j] = yj;
        __syncthreads();
        float s = 0.f;
#pragma unroll 8
        for (int m = 0; m < 64; ++m) s += w2[j * 64 + m] * sy[wv][m];
        int kg = j >> 3, jj = j & 7, ct = c >> 7, cl = c & 127;
        bz[((ct * 8 + kg) * 128 + cl) * 8 + jj] = f2bf(s);
        float pc = outb[j] * bv + (b2[j] + posb[j]) * yj;
        float p0 = temb[j] * yj, p1 = temb[64 + j] * yj, p2 = temb[128 + j] * yj;
        float pp = posw[j] * yj;
#pragma unroll
        for (int k = 32; k; k >>= 1) {
            pc += __shfl_xor(pc, k, 64); p0 += __shfl_xor(p0, k, 64);
            p1 += __shfl_xor(p1, k, 64); p2 += __shfl_xor(p2, k, 64);
            pp += __shfl_xor(pp, k, 64);
        }
        if (j == 0) {
            C0[c] = pc + ((c >= 256) ? (bias[cL] + res_b[cL]) : 0.f);
            T[c] = p0; T[512 + c] = p1; T[1024 + c] = p2;
            P[c] = pp;
        }
    } else {
        for (int e = (b - 449) * 256 + t; e < E; e += 256 * 256)
            atomicAdd(&cnt_t[dst[e] * 4 + et[e]], 1);
    }
}

// ------------- fp1: fused fe1 + prep1.
// Phase A: relu(X@W1+b1) -> bf16 tile in LDS (64 rows x 72-padded cols).
// Phase B: tile @ BLR[64x512] by column quarters + fe2-tail adds + att dots.
__global__ __launch_bounds__(256) void k_fp1(
    const float* __restrict__ feat, const unsigned short* __restrict__ bzfe,
    const float* __restrict__ b1,
    const unsigned short* __restrict__ bzp1,
    const float* __restrict__ C0, const float* __restrict__ T,
    const float* __restrict__ P, const int* __restrict__ ntypes,
    const float* __restrict__ pos,
    const float* __restrict__ att_s, const float* __restrict__ att_d,
    unsigned short* __restrict__ xsb, unsigned short* __restrict__ resp,
    float* __restrict__ a_src, float* __restrict__ a_dst, int N)
{
    __shared__ __align__(16) unsigned short tl[64 * 72];   // 9 KiB, pad 64->72
    int t = threadIdx.x;
    int wv = t >> 6, lane = t & 63;
    int quad = lane >> 4, l16 = lane & 15;
    long rb = (long)blockIdx.x * 64;

    // ---- phase A: fe1 GEMM (rows rb+wv*16 .. +15, cols 0..63)
    {
        long ra = rb + wv * 16 + l16;
        if (ra >= N) ra = N - 1;
        const float* fbase = feat + ra * 768 + quad * 8;
        floatx4 acc[4];
#pragma unroll
        for (int i = 0; i < 4; ++i) acc[i] = (floatx4){0.f, 0.f, 0.f, 0.f};
        for (int ci = 0; ci < 12; ++ci) {
            const float* fc = fbase + ci * 64;
            short8 af[2];
#pragma unroll
            for (int s = 0; s < 2; ++s) {
                float4 x = *(const float4*)(fc + s * 32);
                float4 y = *(const float4*)(fc + s * 32 + 4);
                uint4 u = {cvtpk(x.x, x.y), cvtpk(x.z, x.w),
                           cvtpk(y.x, y.y), cvtpk(y.z, y.w)};
                af[s] = *(short8*)&u;
            }
#pragma unroll
            for (int s = 0; s < 2; ++s) {
                int kg = s * 4 + quad;
#pragma unroll
                for (int ct = 0; ct < 4; ++ct) {
                    short8 bfrag = *(const short8*)&bzfe[
                        ((ci * 8 + kg) * 64 + ct * 16 + l16) * 8];
                    acc[ct] = __builtin_amdgcn_mfma_f32_16x16x32_bf16(
                        af[s], bfrag, acc[ct], 0, 0, 0);
                }
            }
        }
#pragma unroll
        for (int ct = 0; ct < 4; ++ct) {
            float bb = b1[ct * 16 + l16];
#pragma unroll
            for (int r = 0; r < 4; ++r) {
                int row = wv * 16 + quad * 4 + r;
                tl[row * 72 + ct * 16 + l16] = f2bf(fmaxf(acc[ct][r] + bb, 0.f));
            }
        }
    }
    __syncthreads();

    // ---- phase B: prep1 GEMM from LDS tile, 4 column quarters
    int rowB = wv * 16 + l16;
    short8 af0 = *(const short8*)&tl[rowB * 72 + quad * 8];
    short8 af1 = *(const short8*)&tl[rowB * 72 + quad * 8 + 32];
    long rwB = rb + wv * 16;
    int nta[4];
    float posa[4];
#pragma unroll
    for (int r = 0; r < 4; ++r) {
        long m = rwB + quad * 4 + r;
        if (m < N) { nta[r] = ntypes[m]; posa[r] = pos[m]; }
        else       { nta[r] = 0; posa[r] = 0.f; }
    }
    for (int by = 0; by < 4; ++by) {
        floatx4 acc[8];
#pragma unroll
        for (int i = 0; i < 8; ++i) acc[i] = (floatx4){0.f, 0.f, 0.f, 0.f};
#pragma unroll
        for (int s = 0; s < 2; ++s) {
            int kg = s * 4 + quad;
            short8 af = s ? af1 : af0;
#pragma unroll
            for (int c8 = 0; c8 < 8; ++c8) {
                short8 bfrag = *(const short8*)&bzp1[
                    ((by * 8 + kg) * 128 + c8 * 16 + l16) * 8];
                acc[c8] = __builtin_amdgcn_mfma_f32_16x16x32_bf16(
                    af, bfrag, acc[c8], 0, 0, 0);
            }
        }
        bool isl = (by < 2);
        int cb = by * 128;
        float ps[2][4] = {{0.f,0.f,0.f,0.f},{0.f,0.f,0.f,0.f}};
        float pd[2][4] = {{0.f,0.f,0.f,0.f},{0.f,0.f,0.f,0.f}};
#pragma unroll
        for (int c8 = 0; c8 < 8; ++c8) {
            int gc = cb + c8 * 16 + l16;
            float c0 = C0[gc], pcf = P[gc];
            float as = 0.f, ad = 0.f;
            if (isl) { as = att_s[gc]; ad = att_d[gc]; }
            int hh = c8 >> 2;
#pragma unroll
            for (int r = 0; r < 4; ++r) {
                long m = rwB + quad * 4 + r;
                float val = acc[c8][r] + c0 + T[nta[r] * 512 + gc] + posa[r] * pcf;
                if (m < N) {
                    if (isl) xsb[m * 256 + gc] = f2bf(val);
                    else     resp[m * 256 + gc - 256] = f2bf(val);
                }
                ps[hh][r] += val * as;
                pd[hh][r] += val * ad;
            }
        }
        if (isl) {
#pragma unroll
            for (int h = 0; h < 2; ++h)
#pragma unroll
                for (int r = 0; r < 4; ++r) {
                    float a = ps[h][r], bq = pd[h][r];
#pragma unroll
                    for (int k = 1; k < 16; k <<= 1) {
                        a += __shfl_xor(a, k, 64);
                        bq += __shfl_xor(bq, k, 64);
                    }
                    long m = rwB + quad * 4 + r;
                    if (l16 == 0 && m < N) {
                        int h4 = by * 2 + h;
                        a_src[m * 4 + h4] = a;
                        a_dst[m * 4 + h4] = bq;
                    }
                }
        }
    }
}

// ------------- prep2: hid1b[Nx256] @ [lin|res][256x128] + fused attention
// dots for layer 2. cols<64 -> xs2 bf16; cols>=64 -> res fp32 (+bias+res_b).
__global__ __launch_bounds__(256) void k_prep2(
    const unsigned short* __restrict__ A, const unsigned short* __restrict__ bswz,
    const float* __restrict__ bias, const float* __restrict__ res_b,
    const float* __restrict__ att_s, const float* __restrict__ att_d,
    unsigned short* __restrict__ xsb, float* __restrict__ resp,
    float* __restrict__ a_src, float* __restrict__ a_dst, int N)
{
    int t = threadIdx.x;
    int wv = t >> 6, lane = t & 63;
    int quad = lane >> 4, l16 = lane & 15;
    long rw = (long)blockIdx.x * 64 + wv * 16;
    long ra = rw + l16;
    if (ra >= N) ra = N - 1;
    const unsigned short* abase = A + ra * 256 + quad * 8;

    floatx4 acc[8];
#pragma unroll
    for (int i = 0; i < 8; ++i) acc[i] = (floatx4){0.f, 0.f, 0.f, 0.f};

    for (int ci = 0; ci < 4; ++ci) {
        short8 af[2];
        af[0] = *(const short8*)(abase + ci * 64);
        af[1] = *(const short8*)(abase + ci * 64 + 32);
#pragma unroll
        for (int s = 0; s < 2; ++s) {
            int kg = s * 4 + quad;
#pragma unroll
            for (int c8 = 0; c8 < 8; ++c8) {
                short8 bfrag = *(const short8*)&bswz[
                    ((ci * 8 + kg) * 128 + c8 * 16 + l16) * 8];
                acc[c8] = __builtin_amdgcn_mfma_f32_16x16x32_bf16(
                    af[s], bfrag, acc[c8], 0, 0, 0);
            }
        }
    }
    float ps[4] = {0.f,0.f,0.f,0.f}, pd[4] = {0.f,0.f,0.f,0.f};
#pragma unroll
    for (int c8 = 0; c8 < 8; ++c8) {
        int gc = c8 * 16 + l16;
        bool isl = gc < 64;
        float badd = isl ? 0.f : (bias[gc - 64] + res_b[gc - 64]);
        float as = isl ? att_s[gc] : 0.f;
        float ad = isl ? att_d[gc] : 0.f;
#pragma unroll
        for (int r = 0; r < 4; ++r) {
            long m = rw + quad * 4 + r;
            float val = acc[c8][r];
            if (m < N) {
                if (isl) xsb[m * 64 + gc] = f2bf(val);
                else     resp[m * 64 + gc - 64] = val + badd;
            }
            if (isl) { ps[r] += val * as; pd[r] += val * ad; }
        }
    }
#pragma unroll
    for (int r = 0; r < 4; ++r) {
        float a = ps[r], b = pd[r];
#pragma unroll
        for (int k = 1; k < 16; k <<= 1) {
            a += __shfl_xor(a, k, 64);
            b += __shfl_xor(b, k, 64);
        }
        long m = rw + quad * 4 + r;
        if (l16 == 0 && m < N) { a_src[m] = a; a_dst[m] = b; }
    }
}

// ---------------------------------------------------------------- CSR build
__global__ __launch_bounds__(256) void k_scan1(
    const int* __restrict__ cnt_t, int* __restrict__ row_off,
    int* __restrict__ blk_sums, int N)
{
    __shared__ int s[256];
    int t = threadIdx.x;
    int i = blockIdx.x * 256 + t;
    int v = 0;
    if (i < N) v = cnt_t[4 * i] + cnt_t[4 * i + 1] + cnt_t[4 * i + 2] + cnt_t[4 * i + 3];
    s[t] = v;
    __syncthreads();
    for (int off = 1; off < 256; off <<= 1) {
        int x = 0;
        if (t >= off) x = s[t - off];
        __syncthreads();
        s[t] += x;
        __syncthreads();
    }
    if (i < N) row_off[i] = s[t] - v;
    if (t == 255) blk_sums[blockIdx.x] = s[255];
}

// scan3 with scan2 absorbed: each block re-sums blk_sums[0..bid-1] (nb<=256).
__global__ __launch_bounds__(256) void k_scan3(
    int* __restrict__ row_off, int* __restrict__ cursor,
    const int* __restrict__ blk_sums, int N, int E)
{
    __shared__ int s[256];
    int t = threadIdx.x;
    int bid = blockIdx.x;
    s[t] = (t < bid) ? blk_sums[t] : 0;
    __syncthreads();
    for (int off = 128; off; off >>= 1) {
        if (t < off) s[t] += s[t + off];
        __syncthreads();
    }
    int prev = s[0];
    int i = bid * 256 + t;
    if (i < N) {
        int o = row_off[i] + prev;
        row_off[i] = o;
        cursor[i] = o;
    }
    if (i == 0) row_off[N] = E;
}

// scatter + gat1 edge-weight precompute: w[pos][h] = exp(lrelu(a_src[s,h] +
// a_dst[d,h] + aet1[ty,h])), fp32 (bitwise identical to the old in-gat1 calc).
__global__ __launch_bounds__(256) void k_scatter(
    const int* __restrict__ src, const int* __restrict__ dst,
    const int* __restrict__ et, int* __restrict__ cursor,
    int* __restrict__ csr_pack,
    const float* __restrict__ a_src, const float* __restrict__ a_dst,
    const float* __restrict__ aet1, float* __restrict__ wbuf, int E)
{
    int e = blockIdx.x * 256 + threadIdx.x;
    if (e < E) {
        int d = dst[e];
        int s = src[e];
        int ty = et[e];
        int pos = atomicAdd(&cursor[d], 1);
        csr_pack[pos] = s | (ty << 28);
        float4 as4 = *(const float4*)&a_src[s * 4];
        float4 ad4 = *(const float4*)&a_dst[d * 4];
        float4 ae = *(const float4*)&aet1[ty * 4];
        float a0 = as4.x + ad4.x + ae.x;
        float a1 = as4.y + ad4.y + ae.y;
        float a2 = as4.z + ad4.z + ae.z;
        float a3 = as4.w + ad4.w + ae.w;
        a0 = LRELU(a0); a1 = LRELU(a1); a2 = LRELU(a2); a3 = LRELU(a3);
        float4 w4 = make_float4(expf(a0), expf(a1), expf(a2), expf(a3));
        *(float4*)&wbuf[(long)pos * 4] = w4;
    }
}

// ---------------- GAT layer 1: 128 thr = 2 waves; wave w owns heads 2w,2w+1.
// Edge weights preloaded from wbuf; gather 4 edges/wave-iter dwordx4.
__global__ __launch_bounds__(128) void k_gat1(
    const unsigned short* __restrict__ xs1b, const float* __restrict__ a_src,
    const float* __restrict__ a_dst, const int* __restrict__ row_off,
    const int* __restrict__ csr_pack, const float* __restrict__ wbuf,
    const int* __restrict__ cnt_t, const float* __restrict__ aet1,
    const float* __restrict__ ln_g, const float* __restrict__ ln_b,
    const unsigned short* __restrict__ res, unsigned short* __restrict__ out)
{
    __shared__ __align__(16) float4 ws[2][64];
    __shared__ float2 aetp[2][4];
    __shared__ float red[4];
    int n = blockIdx.x;
    int t = threadIdx.x;
    int w = t >> 6, c = t & 63;
    int lc = c & 15, g = c >> 4;
    int h0 = 2 * w;
    if (t < 8) {
        int w2 = t >> 2, ty = t & 3;
        aetp[w2][ty] = make_float2(aet1[ty * 4 + 2 * w2], aet1[ty * 4 + 2 * w2 + 1]);
    }
    int off = row_off[n], deg = row_off[n + 1] - off;
    float2 a_d = *(const float2*)&a_dst[n * 4 + h0];
    __syncthreads();
    float ael0 = 0.f, ael1 = 0.f;
    int degc = 0;
#pragma unroll
    for (int ty = 0; ty < 4; ++ty) {
        int ct = cnt_t[n * 4 + ty];
        degc += ct;
        float2 ae = aetp[w][ty];
        ael0 += (float)ct * ae.x;
        ael1 += (float)ct * ae.y;
    }
    float inv = (degc > 0) ? 1.f / (float)degc : 1.f;
    float2 a_s_self = *(const float2*)&a_src[n * 4 + h0];
    float al0 = a_s_self.x + a_d.x + ael0 * inv;
    float al1 = a_s_self.y + a_d.y + ael1 * inv;
    al0 = LRELU(al0); al1 = LRELU(al1);
    float wself0 = expf(al0), wself1 = expf(al1);

    int col0 = w * 128 + lc * 8;                    // 8 cols per lane
    const unsigned short* xrow = xs1b + col0;       // + s*256 per gather
    float acc[8];
#pragma unroll
    for (int j = 0; j < 8; ++j) acc[j] = 0.f;
    float dp0 = 0.f, dp1 = 0.f;

    for (int base = 0; base < deg; base += 64) {
        int cnt = min(64, deg - base);
        float w0 = 0.f, w1 = 0.f;
        int s = 0;
        if (c < cnt) {
            int idx = off + base + c;
            int pk = csr_pack[idx];
            s = pk & 0x0FFFFFFF;
            float2 wv = *(const float2*)&wbuf[(long)idx * 4 + 2 * w];
            w0 = wv.x; w1 = wv.y;
        }
        dp0 += w0; dp1 += w1;
        ws[w][c] = make_float4(w0, w1, __int_as_float(s), 0.f);
        int cr = (cnt + 7) & ~7;
        for (int i = 0; i < cr; i += 8) {
#pragma unroll
            for (int u = 0; u < 2; ++u) {
                float4 p = ws[w][i + u * 4 + g];
                float wl = (lc < 8) ? p.x : p.y;
                uint4 q = *(const uint4*)&xrow[(long)__float_as_int(p.z) * 256];
                acc[0] += wl * bflo(q.x); acc[1] += wl * bfhi(q.x);
                acc[2] += wl * bflo(q.y); acc[3] += wl * bfhi(q.y);
                acc[4] += wl * bflo(q.z); acc[5] += wl * bfhi(q.z);
                acc[6] += wl * bflo(q.w); acc[7] += wl * bfhi(q.w);
            }
        }
    }
#pragma unroll
    for (int k = 32; k; k >>= 1) {
        dp0 += __shfl_xor(dp0, k, 64);
        dp1 += __shfl_xor(dp1, k, 64);
    }
#pragma unroll
    for (int j = 0; j < 8; ++j) {
        acc[j] += __shfl_xor(acc[j], 16, 64);
        acc[j] += __shfl_xor(acc[j], 32, 64);
    }
    uint4 us = *(const uint4*)&xrow[(long)n * 256];
    float wself_l = (lc < 8) ? wself0 : wself1;
    acc[0] += wself_l * bflo(us.x); acc[1] += wself_l * bfhi(us.x);
    acc[2] += wself_l * bflo(us.y); acc[3] += wself_l * bfhi(us.y);
    acc[4] += wself_l * bflo(us.z); acc[5] += wself_l * bfhi(us.z);
    acc[6] += wself_l * bflo(us.w); acc[7] += wself_l * bfhi(us.w);
    float dsum = ((lc < 8) ? dp0 + wself0 : dp1 + wself1) + 1e-16f;
    float rd = 1.f / dsum;
    uint4 ur = *(const uint4*)&res[(long)n * 256 + col0];
    float v[8];
    v[0] = acc[0] * rd + bflo(ur.x); v[1] = acc[1] * rd + bfhi(ur.x);
    v[2] = acc[2] * rd + bflo(ur.y); v[3] = acc[3] * rd + bfhi(ur.y);
    v[4] = acc[4] * rd + bflo(ur.z); v[5] = acc[5] * rd + bfhi(ur.z);
    v[6] = acc[6] * rd + bflo(ur.w); v[7] = acc[7] * rd + bfhi(ur.w);
    float s1 = 0.f, s2 = 0.f;
#pragma unroll
    for (int j = 0; j < 8; ++j) { s1 += v[j]; s2 += v[j] * v[j]; }
#pragma unroll
    for (int k = 32; k; k >>= 1) {
        s1 += __shfl_xor(s1, k, 64);
        s2 += __shfl_xor(s2, k, 64);
    }
    if (c == 0) { red[w] = s1 * 0.25f; red[2 + w] = s2 * 0.25f; }
    __syncthreads();
    float mu = (red[0] + red[1]) * (1.f / 256.f);
    float var = (red[2] + red[3]) * (1.f / 256.f) - mu * mu;
    float rs = rsqrtf(var + 1e-5f);
    if (g == 0) {
        float4 lg0 = *(const float4*)&ln_g[col0];
        float4 lg1 = *(const float4*)&ln_g[col0 + 4];
        float4 lb0 = *(const float4*)&ln_b[col0];
        float4 lb1 = *(const float4*)&ln_b[col0 + 4];
        float y[8];
        y[0] = fmaxf((v[0] - mu) * rs * lg0.x + lb0.x, 0.f);
        y[1] = fmaxf((v[1] - mu) * rs * lg0.y + lb0.y, 0.f);
        y[2] = fmaxf((v[2] - mu) * rs * lg0.z + lb0.z, 0.f);
        y[3] = fmaxf((v[3] - mu) * rs * lg0.w + lb0.w, 0.f);
        y[4] = fmaxf((v[4] - mu) * rs * lg1.x + lb1.x, 0.f);
        y[5] = fmaxf((v[5] - mu) * rs * lg1.y + lb1.y, 0.f);
        y[6] = fmaxf((v[6] - mu) * rs * lg1.z + lb1.z, 0.f);
        y[7] = fmaxf((v[7] - mu) * rs * lg1.w + lb1.w, 0.f);
        uint4 o;
        o.x = cvtpk(y[0], y[1]); o.y = cvtpk(y[2], y[3]);
        o.z = cvtpk(y[4], y[5]); o.w = cvtpk(y[6], y[7]);
        *(uint4*)&out[(long)n * 256 + col0] = o;
    }
}

// ------------------- GAT layer 2 (H=1, C=64): 2 nodes per 128-thread block.
__global__ __launch_bounds__(128) void k_gat2(
    const unsigned short* __restrict__ xs2b, const float* __restrict__ a_src,
    const float* __restrict__ a_dst, const int* __restrict__ row_off,
    const int* __restrict__ csr_pack,
    const int* __restrict__ cnt_t, const float* __restrict__ aet2,
    const float* __restrict__ ln_g, const float* __restrict__ ln_b,
    float* io, int N)
{
    __shared__ __align__(8) float2 ws[2][64];
    int v_ = threadIdx.x >> 6, c = threadIdx.x & 63;
    int n = blockIdx.x * 2 + v_;
    if (n >= N) return;
    int lc = c & 15, g = c >> 4;
    int off = row_off[n], deg = row_off[n + 1] - off;
    float a_d = a_dst[n];
    float ael = 0.f;
    int degc = 0;
#pragma unroll
    for (int ty = 0; ty < 4; ++ty) {
        int ct = cnt_t[n * 4 + ty];
        degc += ct;
        ael += (float)ct * aet2[ty];
    }
    ael *= (degc > 0 ? 1.f / (float)degc : 1.f);
    float al = a_src[n] + a_d + ael;
    al = LRELU(al);
    float wself = expf(al);

    int colb = lc * 4;
    const unsigned short* xrow = xs2b + colb;
    float acc[4] = {0.f, 0.f, 0.f, 0.f};
    float dp = 0.f;
    for (int base = 0; base < deg; base += 64) {
        int cnt = min(64, deg - base);
        float we = 0.f;
        int s = 0;
        if (c < cnt) {
            int pk = csr_pack[off + base + c];
            s = pk & 0x0FFFFFFF;
            int ty = ((unsigned)pk) >> 28;
            float a = a_src[s] + a_d + aet2[ty];
            a = LRELU(a);
            we = expf(a);
        }
        dp += we;
        ws[v_][c] = make_float2(we, __int_as_float(s));
        int cr = (cnt + 7) & ~7;
        for (int i = 0; i < cr; i += 8) {
#pragma unroll
            for (int u = 0; u < 2; ++u) {
                float2 p = ws[v_][i + u * 4 + g];
                uint2 q = *(const uint2*)&xrow[(long)__float_as_int(p.y) * 64];
                acc[0] += p.x * bflo(q.x); acc[1] += p.x * bfhi(q.x);
                acc[2] += p.x * bflo(q.y); acc[3] += p.x * bfhi(q.y);
            }
        }
    }
#pragma unroll
    for (int k = 32; k; k >>= 1) dp += __shfl_xor(dp, k, 64);
#pragma unroll
    for (int j = 0; j < 4; ++j) {
        acc[j] += __shfl_xor(acc[j], 16, 64);
        acc[j] += __shfl_xor(acc[j], 32, 64);
    }
    uint2 us = *(const uint2*)&xrow[(long)n * 64];
    acc[0] += wself * bflo(us.x); acc[1] += wself * bfhi(us.x);
    acc[2] += wself * bflo(us.y); acc[3] += wself * bfhi(us.y);
    float dsum = dp + wself + 1e-16f;
    float rd = 1.f / dsum;
    float4 r = *(const float4*)&io[(long)n * 64 + colb];
    float v[4];
    v[0] = acc[0] * rd + r.x; v[1] = acc[1] * rd + r.y;
    v[2] = acc[2] * rd + r.z; v[3] = acc[3] * rd + r.w;
    float s1 = v[0] + v[1] + v[2] + v[3];
    float s2 = v[0] * v[0] + v[1] * v[1] + v[2] * v[2] + v[3] * v[3];
#pragma unroll
    for (int k = 32; k; k >>= 1) {
        s1 += __shfl_xor(s1, k, 64);
        s2 += __shfl_xor(s2, k, 64);
    }
    float mu = s1 * (1.f / 256.f);
    float var = s2 * (1.f / 256.f) - mu * mu;
    float rs = rsqrtf(var + 1e-5f);
    if (g == 0) {
        float4 lg = *(const float4*)&ln_g[colb];
        float4 lb = *(const float4*)&ln_b[colb];
        float4 y;
        y.x = (v[0] - mu) * rs * lg.x + lb.x;
        y.y = (v[1] - mu) * rs * lg.y + lb.y;
        y.z = (v[2] - mu) * rs * lg.z + lb.z;
        y.w = (v[3] - mu) * rs * lg.w + lb.w;
        *(float4*)&io[(long)n * 64 + colb] = y;
    }
}

// --------------------------------------------------------------- classifier
__global__ __launch_bounds__(256) void k_cls(
    const float* __restrict__ hid2, const int* __restrict__ asp,
    const float* __restrict__ w, const float* __restrict__ b,
    float* __restrict__ out)
{
    int g = blockIdx.x * 256 + threadIdx.x;
    int i = g / 3, j = g - i * 3;
    int a = asp[i];
    float acc = b[j];
#pragma unroll 8
    for (int cc = 0; cc < 64; ++cc) acc += hid2[(long)a * 64 + cc] * w[cc * 3 + j];
    out[i * 3 + j] = acc;
}

extern "C" void kernel_launch(void* const* d_in, const int* in_sizes, int n_in,
                              void* d_out, int out_size, void* d_ws, size_t ws_size,
                              hipStream_t stream)
{
    const float* features    = (const float*)d_in[0];
    const int*   edge_index  = (const int*)d_in[1];
    const int*   aspect      = (const int*)d_in[2];
    const int*   etypes      = (const int*)d_in[3];
    const int*   ntypes      = (const int*)d_in[4];
    const float* pos         = (const float*)d_in[5];
    const float* fe_w1       = (const float*)d_in[6];
    const float* fe_b1       = (const float*)d_in[7];
    const float* fe_w2       = (const float*)d_in[8];
    const float* fe_b2       = (const float*)d_in[9];
    const float* fe_pos_w    = (const float*)d_in[10];
    const float* fe_pos_b    = (const float*)d_in[11];
    const float* fe_type_emb = (const float*)d_in[12];
    const float* fe_out_w    = (const float*)d_in[13];
    const float* fe_out_b    = (const float*)d_in[14];
    const float* g1_lin_w    = (const float*)d_in[15];
    const float* g1_att_src  = (const float*)d_in[16];
    const float* g1_att_dst  = (const float*)d_in[17];
    const float* g1_edge_emb = (const float*)d_in[18];
    const float* g1_lin_edge = (const float*)d_in[19];
    const float* g1_att_edge = (const float*)d_in[20];
    const float* g1_bias     = (const float*)d_in[21];
    const float* g1_res_w    = (const float*)d_in[22];
    const float* g1_res_b    = (const float*)d_in[23];
    const float* g1_ln_g     = (const float*)d_in[24];
    const float* g1_ln_b     = (const float*)d_in[25];
    const float* g2_lin_w    = (const float*)d_in[26];
    const float* g2_att_src  = (const float*)d_in[27];
    const float* g2_att_dst  = (const float*)d_in[28];
    const float* g2_edge_emb = (const float*)d_in[29];
    const float* g2_lin_edge = (const float*)d_in[30];
    const float* g2_att_edge = (const float*)d_in[31];
    const float* g2_bias     = (const float*)d_in[32];
    const float* g2_res_w    = (const float*)d_in[33];
    const float* g2_res_b    = (const float*)d_in[34];
    const float* g2_ln_g     = (const float*)d_in[35];
    const float* g2_ln_b     = (const float*)d_in[36];
    const float* cls_w       = (const float*)d_in[37];
    const float* cls_b       = (const float*)d_in[38];

    const int N = in_sizes[0] / 768;   // 50000
    const int E = in_sizes[1] / 2;     // 800000
    const int* src = edge_index;
    const int* dst = edge_index + E;

    char* wsb = (char*)d_ws;
    size_t off = 0;
    auto alloc = [&](size_t bytes) -> char* {
        char* p = wsb + off;
        off += (bytes + 255) & ~(size_t)255;
        return p;
    };
    unsigned short* xs1b = (unsigned short*)alloc((size_t)N * 256 * 2);
    unsigned short* xs2b = (unsigned short*)alloc((size_t)N * 64 * 2);
    unsigned short* hid1b= (unsigned short*)alloc((size_t)N * 256 * 2);
    unsigned short* rp1  = (unsigned short*)alloc((size_t)N * 256 * 2);  // res1 bf16
    float* rp2     = (float*)alloc((size_t)N * 64 * 4);   // res_pre2, then hid2
    float* a_src1  = (float*)alloc((size_t)N * 4 * 4);
    float* a_dst1  = (float*)alloc((size_t)N * 4 * 4);
    float* a_src2  = (float*)alloc((size_t)N * 4);
    float* a_dst2  = (float*)alloc((size_t)N * 4);
    int*   cnt_t   = (int*)alloc((size_t)N * 4 * 4);
    int*   row_off = (int*)alloc((size_t)(N + 1) * 4);
    int*   cursor  = (int*)alloc((size_t)N * 4);
    int*   blk     = (int*)alloc(1024);
    int*   csr_pack= (int*)alloc((size_t)E * 4);
    float* wbuf    = (float*)alloc((size_t)E * 4 * 4);    // per-edge weights
    float* aet1    = (float*)alloc(64);
    float* aet2    = (float*)alloc(64);
    unsigned short* bz_fe1 = (unsigned short*)alloc(768 * 64 * 2);
    unsigned short* bz_p1  = (unsigned short*)alloc(64 * 512 * 2);
    unsigned short* bz_p2  = (unsigned short*)alloc(256 * 128 * 2);
    float* C0t     = (float*)alloc(512 * 4);
    float* Tt      = (float*)alloc(3 * 512 * 4);
    float* Pt      = (float*)alloc(512 * 4);

    hipMemsetAsync(cnt_t, 0, (size_t)N * 4 * 4, stream);

    int mb = (N + 63) / 64;   // 782 row-tiles
    int eblk = (E + 255) / 256;
    int nb = (N + 255) / 256;

    k_front<<<705, 256, 0, stream>>>(
        g1_edge_emb, g1_lin_edge, g1_att_edge,
        g2_edge_emb, g2_lin_edge, g2_att_edge, aet1, aet2,
        fe_w1, g2_lin_w, g2_res_w, bz_fe1, bz_p2,
        fe_w2, fe_out_w, fe_b2, fe_pos_b, fe_out_b, fe_type_emb, fe_pos_w,
        g1_lin_w, g1_res_w, g1_bias, g1_res_b, bz_p1, C0t, Tt, Pt,
        dst, etypes, cnt_t, E);
    k_scan1<<<nb, 256, 0, stream>>>(cnt_t, row_off, blk, N);
    k_scan3<<<nb, 256, 0, stream>>>(row_off, cursor, blk, N, E);
    k_fp1<<<mb, 256, 0, stream>>>(
        features, bz_fe1, fe_b1, bz_p1, C0t, Tt, Pt, ntypes, pos,
        g1_att_src, g1_att_dst, xs1b, rp1, a_src1, a_dst1, N);
    k_scatter<<<eblk, 256, 0, stream>>>(src, dst, etypes, cursor, csr_pack,
                                        a_src1, a_dst1, aet1, wbuf, E);
    k_gat1<<<N, 128, 0, stream>>>(xs1b, a_src1, a_dst1, row_off, csr_pack, wbuf,
                                  cnt_t, aet1, g1_ln_g, g1_ln_b, rp1, hid1b);
    k_prep2<<<mb, 256, 0, stream>>>(hid1b, bz_p2, g2_bias, g2_res_b,
                                    g2_att_src, g2_att_dst, xs2b, rp2,
                                    a_src2, a_dst2, N);
    k_gat2<<<(N + 1) / 2, 128, 0, stream>>>(xs2b, a_src2, a_dst2, row_off,
                                            csr_pack, cnt_t, aet2,
                                            g2_ln_g, g2_ln_b, rp2, N);
    k_cls<<<(out_size + 255) / 256, 256, 0, stream>>>(rp2, aspect, cls_w, cls_b,
                                                      (float*)d_out);
}

// Round 8
// 571.033 us; speedup vs baseline: 1.1233x; 1.0385x over previous
//
#include <hip/hip_runtime.h>

// SimplifiedHAFE on MI355X — round 14: revert to r11 + minimal safe prefetch.
//  r12/r13 (macro-unrolled fp1 phase A + up-front prep2 loads) failed
//  numerics twice despite 1:1 arithmetic mapping on paper — abandoned.
//  This round = r11 source (last passing, 593 us) with ONE delta:
//   fp1 phase A uses the distance-1 rolled prefetch pattern PROVEN in
//   rounds 7/8 (prologue load + prefetch of chunk ci+1 issued before
//   chunk ci's convert+MFMA). No macros, no extra unrolling.
//  Everything else byte-identical to r11.

#define LRELU(x) ((x) > 0.f ? (x) : 0.2f * (x))

typedef __attribute__((ext_vector_type(8))) short short8;
typedef __attribute__((ext_vector_type(4))) float floatx4;

#define MFMA16(a, b, c) __builtin_amdgcn_mfma_f32_16x16x32_bf16(a, b, c, 0, 0, 0)

__device__ __forceinline__ unsigned short f2bf(float x) {
    union { float f; unsigned int u; } v; v.f = x;
    unsigned int r = (v.u + 0x7FFFu + ((v.u >> 16) & 1u)) >> 16;  // RNE
    return (unsigned short)r;
}
// pack 2 fp32 -> 2 bf16 (RNE) in one VALU; lo in low 16 bits
__device__ __forceinline__ unsigned int cvtpk(float lo, float hi) {
    unsigned int r;
    asm("v_cvt_pk_bf16_f32 %0, %1, %2" : "=v"(r) : "v"(lo), "v"(hi));
    return r;
}
__device__ __forceinline__ float bflo(unsigned int u) {
    return __uint_as_float(u << 16);
}
__device__ __forceinline__ float bfhi(unsigned int u) {
    return __uint_as_float(u & 0xFFFF0000u);
}
__device__ __forceinline__ float bf1(unsigned short u) {
    return __uint_as_float(((unsigned int)u) << 16);
}

// ---------------- front matter (grid = 705):
//   b0          : edge-type attention tables (aet1, aet2)
//   b1..320     : B pre-swizzles for fe1 (768x64) and prep2 (256x128)
//   b321..448   : fuse2 — bz_p1 = (w2@outw)@[lin|res] frag-order bf16 + C0/T/P
//   b449..704   : edge count histogram (grid-stride; cnt_t pre-zeroed)
__global__ __launch_bounds__(256) void k_front(
    const float* __restrict__ e_emb1, const float* __restrict__ lew1,
    const float* __restrict__ ae1,
    const float* __restrict__ e_emb2, const float* __restrict__ lew2,
    const float* __restrict__ ae2,
    float* __restrict__ aet1, float* __restrict__ aet2,
    const float* __restrict__ w1, const float* __restrict__ B1,
    const float* __restrict__ B2,
    unsigned short* __restrict__ out_fe1, unsigned short* __restrict__ out_p2,
    const float* __restrict__ w2, const float* __restrict__ outw,
    const float* __restrict__ b2, const float* __restrict__ posb,
    const float* __restrict__ outb, const float* __restrict__ temb,
    const float* __restrict__ posw,
    const float* __restrict__ lin_w, const float* __restrict__ res_w,
    const float* __restrict__ bias, const float* __restrict__ res_b,
    unsigned short* __restrict__ bz, float* __restrict__ C0,
    float* __restrict__ T, float* __restrict__ P,
    const int* __restrict__ dst, const int* __restrict__ et,
    int* __restrict__ cnt_t, int E)
{
    int t = threadIdx.x;
    int b = blockIdx.x;
    if (b == 0) {
        __shared__ float M1[16];
        __shared__ float M2[4];
        if (t < 16) {
            int d = t >> 2, h = t & 3;
            float s = 0.f;
            for (int c = 0; c < 64; ++c) s += lew1[d * 256 + h * 64 + c] * ae1[h * 64 + c];
            M1[d * 4 + h] = s;
        }
        if (t < 4) {
            float s = 0.f;
            for (int c = 0; c < 64; ++c) s += lew2[t * 64 + c] * ae2[c];
            M2[t] = s;
        }
        __syncthreads();
        if (t < 16) {
            int ty = t >> 2, h = t & 3;
            float s = 0.f;
            for (int d = 0; d < 4; ++d) s += e_emb1[ty * 4 + d] * M1[d * 4 + h];
            aet1[ty * 4 + h] = s;
        }
        if (t < 4) {
            float s = 0.f;
            for (int d = 0; d < 4; ++d) s += e_emb2[t * 4 + d] * M2[d];
            aet2[t] = s;
        }
    } else if (b <= 320) {
        int idx = (b - 1) * 256 + t;
        if (idx < 768 * 64) {
            int k = idx >> 6, col = idx & 63;
            int c = k >> 6, kl = k & 63, kg = kl >> 3, j = kl & 7;
            out_fe1[((c * 8 + kg) * 64 + col) * 8 + j] = f2bf(w1[k * 64 + col]);
        } else {
            int i2 = idx - 768 * 64;          // 256*128 elements
            int k = i2 >> 7, col = i2 & 127;
            float v = (col < 64) ? B1[k * 64 + col] : B2[k * 64 + col - 64];
            int c = k >> 6, kl = k & 63, kg = kl >> 3, j = kl & 7;
            out_p2[((c * 8 + kg) * 128 + col) * 8 + j] = f2bf(v);
        }
    } else if (b <= 448) {
        __shared__ float sb[4][64];
        __shared__ float sy[4][64];
        int wv = t >> 6, j = t & 63;
        int c = (b - 321) * 4 + wv;       // 0..511
        int cL = c & 255;
        const float* Bsrc = (c < 256) ? lin_w : res_w;
        float bv = Bsrc[j * 256 + cL];
        sb[wv][j] = bv;
        __syncthreads();
        float yj = 0.f;
#pragma unroll 8
        for (int k = 0; k < 64; ++k) yj += outw[j * 64 + k] * sb[wv][k];
        sy[wv][j] = yj;
        __syncthreads();
        float s = 0.f;
#pragma unroll 8
        for (int m = 0; m < 64; ++m) s += w2[j * 64 + m] * sy[wv][m];
        int kg = j >> 3, jj = j & 7, ct = c >> 7, cl = c & 127;
        bz[((ct * 8 + kg) * 128 + cl) * 8 + jj] = f2bf(s);
        float pc = outb[j] * bv + (b2[j] + posb[j]) * yj;
        float p0 = temb[j] * yj, p1 = temb[64 + j] * yj, p2 = temb[128 + j] * yj;
        float pp = posw[j] * yj;
#pragma unroll
        for (int k = 32; k; k >>= 1) {
            pc += __shfl_xor(pc, k, 64); p0 += __shfl_xor(p0, k, 64);
            p1 += __shfl_xor(p1, k, 64); p2 += __shfl_xor(p2, k, 64);
            pp += __shfl_xor(pp, k, 64);
        }
        if (j == 0) {
            C0[c] = pc + ((c >= 256) ? (bias[cL] + res_b[cL]) : 0.f);
            T[c] = p0; T[512 + c] = p1; T[1024 + c] = p2;
            P[c] = pp;
        }
    } else {
        for (int e = (b - 449) * 256 + t; e < E; e += 256 * 256)
            atomicAdd(&cnt_t[dst[e] * 4 + et[e]], 1);
    }
}

// ------------- fp1: fused fe1 + prep1.
// Phase A: relu(X@W1+b1) -> bf16 tile in LDS (64x72-padded). Distance-1
//   rolled prefetch (the r7/r8-proven pattern): chunk ci+1's 4 loads issue
//   before chunk ci's convert+MFMA body.
// Phase B: tile @ BLR[64x512] by column quarters + fe2-tail adds + att dots.
__global__ __launch_bounds__(256) void k_fp1(
    const float* __restrict__ feat, const unsigned short* __restrict__ bzfe,
    const float* __restrict__ b1,
    const unsigned short* __restrict__ bzp1,
    const float* __restrict__ C0, const float* __restrict__ T,
    const float* __restrict__ P, const int* __restrict__ ntypes,
    const float* __restrict__ pos,
    const float* __restrict__ att_s, const float* __restrict__ att_d,
    unsigned short* __restrict__ xsb, unsigned short* __restrict__ resp,
    float* __restrict__ a_src, float* __restrict__ a_dst, int N)
{
    __shared__ __align__(16) unsigned short tl[64 * 72];   // 9 KiB, pad 64->72
    int t = threadIdx.x;
    int wv = t >> 6, lane = t & 63;
    int quad = lane >> 4, l16 = lane & 15;
    long rb = (long)blockIdx.x * 64;

    // ---- phase A: fe1 GEMM (rows rb+wv*16 .. +15, cols 0..63)
    {
        long ra = rb + wv * 16 + l16;
        if (ra >= N) ra = N - 1;
        const float* fbase = feat + ra * 768 + quad * 8;
        floatx4 acc[4];
#pragma unroll
        for (int i = 0; i < 4; ++i) acc[i] = (floatx4){0.f, 0.f, 0.f, 0.f};

        // prologue: chunk 0 loads
        float4 n0 = *(const float4*)(fbase);
        float4 n1 = *(const float4*)(fbase + 4);
        float4 n2 = *(const float4*)(fbase + 32);
        float4 n3 = *(const float4*)(fbase + 36);

        for (int ci = 0; ci < 12; ++ci) {
            float4 c0 = n0, c1 = n1, c2 = n2, c3 = n3;
            if (ci < 11) {   // prefetch next chunk before current compute
                const float* fn = fbase + (ci + 1) * 64;
                n0 = *(const float4*)(fn);
                n1 = *(const float4*)(fn + 4);
                n2 = *(const float4*)(fn + 32);
                n3 = *(const float4*)(fn + 36);
            }
            uint4 u0 = {cvtpk(c0.x, c0.y), cvtpk(c0.z, c0.w),
                        cvtpk(c1.x, c1.y), cvtpk(c1.z, c1.w)};
            uint4 u1 = {cvtpk(c2.x, c2.y), cvtpk(c2.z, c2.w),
                        cvtpk(c3.x, c3.y), cvtpk(c3.z, c3.w)};
            short8 af0 = *(short8*)&u0;
            short8 af1 = *(short8*)&u1;
#pragma unroll
            for (int ct = 0; ct < 4; ++ct) {
                short8 bf = *(const short8*)&bzfe[
                    ((ci * 8 + quad) * 64 + ct * 16 + l16) * 8];
                acc[ct] = MFMA16(af0, bf, acc[ct]);
            }
#pragma unroll
            for (int ct = 0; ct < 4; ++ct) {
                short8 bf = *(const short8*)&bzfe[
                    ((ci * 8 + 4 + quad) * 64 + ct * 16 + l16) * 8];
                acc[ct] = MFMA16(af1, bf, acc[ct]);
            }
        }
#pragma unroll
        for (int ct = 0; ct < 4; ++ct) {
            float bb = b1[ct * 16 + l16];
#pragma unroll
            for (int r = 0; r < 4; ++r) {
                int row = wv * 16 + quad * 4 + r;
                tl[row * 72 + ct * 16 + l16] = f2bf(fmaxf(acc[ct][r] + bb, 0.f));
            }
        }
    }
    __syncthreads();

    // ---- phase B: prep1 GEMM from LDS tile, 4 column quarters
    int rowB = wv * 16 + l16;
    short8 af0 = *(const short8*)&tl[rowB * 72 + quad * 8];
    short8 af1 = *(const short8*)&tl[rowB * 72 + quad * 8 + 32];
    long rwB = rb + wv * 16;
    int nta[4];
    float posa[4];
#pragma unroll
    for (int r = 0; r < 4; ++r) {
        long m = rwB + quad * 4 + r;
        if (m < N) { nta[r] = ntypes[m]; posa[r] = pos[m]; }
        else       { nta[r] = 0; posa[r] = 0.f; }
    }
    for (int by = 0; by < 4; ++by) {
        floatx4 acc[8];
#pragma unroll
        for (int i = 0; i < 8; ++i) acc[i] = (floatx4){0.f, 0.f, 0.f, 0.f};
#pragma unroll
        for (int s = 0; s < 2; ++s) {
            int kg = s * 4 + quad;
            short8 af = s ? af1 : af0;
#pragma unroll
            for (int c8 = 0; c8 < 8; ++c8) {
                short8 bfrag = *(const short8*)&bzp1[
                    ((by * 8 + kg) * 128 + c8 * 16 + l16) * 8];
                acc[c8] = MFMA16(af, bfrag, acc[c8]);
            }
        }
        bool isl = (by < 2);
        int cb = by * 128;
        float ps[2][4] = {{0.f,0.f,0.f,0.f},{0.f,0.f,0.f,0.f}};
        float pd[2][4] = {{0.f,0.f,0.f,0.f},{0.f,0.f,0.f,0.f}};
#pragma unroll
        for (int c8 = 0; c8 < 8; ++c8) {
            int gc = cb + c8 * 16 + l16;
            float c0 = C0[gc], pcf = P[gc];
            float as = 0.f, ad = 0.f;
            if (isl) { as = att_s[gc]; ad = att_d[gc]; }
            int hh = c8 >> 2;
#pragma unroll
            for (int r = 0; r < 4; ++r) {
                long m = rwB + quad * 4 + r;
                float val = acc[c8][r] + c0 + T[nta[r] * 512 + gc] + posa[r] * pcf;
                if (m < N) {
                    if (isl) xsb[m * 256 + gc] = f2bf(val);
                    else     resp[m * 256 + gc - 256] = f2bf(val);
                }
                ps[hh][r] += val * as;
                pd[hh][r] += val * ad;
            }
        }
        if (isl) {
#pragma unroll
            for (int h = 0; h < 2; ++h)
#pragma unroll
                for (int r = 0; r < 4; ++r) {
                    float a = ps[h][r], bq = pd[h][r];
#pragma unroll
                    for (int k = 1; k < 16; k <<= 1) {
                        a += __shfl_xor(a, k, 64);
                        bq += __shfl_xor(bq, k, 64);
                    }
                    long m = rwB + quad * 4 + r;
                    if (l16 == 0 && m < N) {
                        int h4 = by * 2 + h;
                        a_src[m * 4 + h4] = a;
                        a_dst[m * 4 + h4] = bq;
                    }
                }
        }
    }
}

// ------------- prep2: hid1b[Nx256] @ [lin|res][256x128] + fused attention
// dots for layer 2. cols<64 -> xs2 bf16; cols>=64 -> res fp32 (+bias+res_b).
__global__ __launch_bounds__(256) void k_prep2(
    const unsigned short* __restrict__ A, const unsigned short* __restrict__ bswz,
    const float* __restrict__ bias, const float* __restrict__ res_b,
    const float* __restrict__ att_s, const float* __restrict__ att_d,
    unsigned short* __restrict__ xsb, float* __restrict__ resp,
    float* __restrict__ a_src, float* __restrict__ a_dst, int N)
{
    int t = threadIdx.x;
    int wv = t >> 6, lane = t & 63;
    int quad = lane >> 4, l16 = lane & 15;
    long rw = (long)blockIdx.x * 64 + wv * 16;
    long ra = rw + l16;
    if (ra >= N) ra = N - 1;
    const unsigned short* abase = A + ra * 256 + quad * 8;

    floatx4 acc[8];
#pragma unroll
    for (int i = 0; i < 8; ++i) acc[i] = (floatx4){0.f, 0.f, 0.f, 0.f};

    for (int ci = 0; ci < 4; ++ci) {
        short8 af[2];
        af[0] = *(const short8*)(abase + ci * 64);
        af[1] = *(const short8*)(abase + ci * 64 + 32);
#pragma unroll
        for (int s = 0; s < 2; ++s) {
            int kg = s * 4 + quad;
#pragma unroll
            for (int c8 = 0; c8 < 8; ++c8) {
                short8 bfrag = *(const short8*)&bswz[
                    ((ci * 8 + kg) * 128 + c8 * 16 + l16) * 8];
                acc[c8] = MFMA16(af[s], bfrag, acc[c8]);
            }
        }
    }
    float ps[4] = {0.f,0.f,0.f,0.f}, pd[4] = {0.f,0.f,0.f,0.f};
#pragma unroll
    for (int c8 = 0; c8 < 8; ++c8) {
        int gc = c8 * 16 + l16;
        bool isl = gc < 64;
        float badd = isl ? 0.f : (bias[gc - 64] + res_b[gc - 64]);
        float as = isl ? att_s[gc] : 0.f;
        float ad = isl ? att_d[gc] : 0.f;
#pragma unroll
        for (int r = 0; r < 4; ++r) {
            long m = rw + quad * 4 + r;
            float val = acc[c8][r];
            if (m < N) {
                if (isl) xsb[m * 64 + gc] = f2bf(val);
                else     resp[m * 64 + gc - 64] = val + badd;
            }
            if (isl) { ps[r] += val * as; pd[r] += val * ad; }
        }
    }
#pragma unroll
    for (int r = 0; r < 4; ++r) {
        float a = ps[r], b = pd[r];
#pragma unroll
        for (int k = 1; k < 16; k <<= 1) {
            a += __shfl_xor(a, k, 64);
            b += __shfl_xor(b, k, 64);
        }
        long m = rw + quad * 4 + r;
        if (l16 == 0 && m < N) { a_src[m] = a; a_dst[m] = b; }
    }
}

// ---------------------------------------------------------------- CSR build
__global__ __launch_bounds__(256) void k_scan1(
    const int* __restrict__ cnt_t, int* __restrict__ row_off,
    int* __restrict__ blk_sums, int N)
{
    __shared__ int s[256];
    int t = threadIdx.x;
    int i = blockIdx.x * 256 + t;
    int v = 0;
    if (i < N) v = cnt_t[4 * i] + cnt_t[4 * i + 1] + cnt_t[4 * i + 2] + cnt_t[4 * i + 3];
    s[t] = v;
    __syncthreads();
    for (int off = 1; off < 256; off <<= 1) {
        int x = 0;
        if (t >= off) x = s[t - off];
        __syncthreads();
        s[t] += x;
        __syncthreads();
    }
    if (i < N) row_off[i] = s[t] - v;
    if (t == 255) blk_sums[blockIdx.x] = s[255];
}

// scan3 with scan2 absorbed: each block re-sums blk_sums[0..bid-1] (nb<=256).
__global__ __launch_bounds__(256) void k_scan3(
    int* __restrict__ row_off, int* __restrict__ cursor,
    const int* __restrict__ blk_sums, int N, int E)
{
    __shared__ int s[256];
    int t = threadIdx.x;
    int bid = blockIdx.x;
    s[t] = (t < bid) ? blk_sums[t] : 0;
    __syncthreads();
    for (int off = 128; off; off >>= 1) {
        if (t < off) s[t] += s[t + off];
        __syncthreads();
    }
    int prev = s[0];
    int i = bid * 256 + t;
    if (i < N) {
        int o = row_off[i] + prev;
        row_off[i] = o;
        cursor[i] = o;
    }
    if (i == 0) row_off[N] = E;
}

// scatter + gat1 edge-weight precompute: w[pos][h] = exp(lrelu(a_src[s,h] +
// a_dst[d,h] + aet1[ty,h])), fp32 (bitwise identical to the old in-gat1 calc).
__global__ __launch_bounds__(256) void k_scatter(
    const int* __restrict__ src, const int* __restrict__ dst,
    const int* __restrict__ et, int* __restrict__ cursor,
    int* __restrict__ csr_pack,
    const float* __restrict__ a_src, const float* __restrict__ a_dst,
    const float* __restrict__ aet1, float* __restrict__ wbuf, int E)
{
    int e = blockIdx.x * 256 + threadIdx.x;
    if (e < E) {
        int d = dst[e];
        int s = src[e];
        int ty = et[e];
        int pos = atomicAdd(&cursor[d], 1);
        csr_pack[pos] = s | (ty << 28);
        float4 as4 = *(const float4*)&a_src[s * 4];
        float4 ad4 = *(const float4*)&a_dst[d * 4];
        float4 ae = *(const float4*)&aet1[ty * 4];
        float a0 = as4.x + ad4.x + ae.x;
        float a1 = as4.y + ad4.y + ae.y;
        float a2 = as4.z + ad4.z + ae.z;
        float a3 = as4.w + ad4.w + ae.w;
        a0 = LRELU(a0); a1 = LRELU(a1); a2 = LRELU(a2); a3 = LRELU(a3);
        float4 w4 = make_float4(expf(a0), expf(a1), expf(a2), expf(a3));
        *(float4*)&wbuf[(long)pos * 4] = w4;
    }
}

// ---------------- GAT layer 1: 128 thr = 2 waves; wave w owns heads 2w,2w+1.
// Edge weights preloaded from wbuf; gather 4 edges/wave-iter dwordx4.
__global__ __launch_bounds__(128) void k_gat1(
    const unsigned short* __restrict__ xs1b, const float* __restrict__ a_src,
    const float* __restrict__ a_dst, const int* __restrict__ row_off,
    const int* __restrict__ csr_pack, const float* __restrict__ wbuf,
    const int* __restrict__ cnt_t, const float* __restrict__ aet1,
    const float* __restrict__ ln_g, const float* __restrict__ ln_b,
    const unsigned short* __restrict__ res, unsigned short* __restrict__ out)
{
    __shared__ __align__(16) float4 ws[2][64];
    __shared__ float2 aetp[2][4];
    __shared__ float red[4];
    int n = blockIdx.x;
    int t = threadIdx.x;
    int w = t >> 6, c = t & 63;
    int lc = c & 15, g = c >> 4;
    int h0 = 2 * w;
    if (t < 8) {
        int w2 = t >> 2, ty = t & 3;
        aetp[w2][ty] = make_float2(aet1[ty * 4 + 2 * w2], aet1[ty * 4 + 2 * w2 + 1]);
    }
    int off = row_off[n], deg = row_off[n + 1] - off;
    float2 a_d = *(const float2*)&a_dst[n * 4 + h0];
    __syncthreads();
    float ael0 = 0.f, ael1 = 0.f;
    int degc = 0;
#pragma unroll
    for (int ty = 0; ty < 4; ++ty) {
        int ct = cnt_t[n * 4 + ty];
        degc += ct;
        float2 ae = aetp[w][ty];
        ael0 += (float)ct * ae.x;
        ael1 += (float)ct * ae.y;
    }
    float inv = (degc > 0) ? 1.f / (float)degc : 1.f;
    float2 a_s_self = *(const float2*)&a_src[n * 4 + h0];
    float al0 = a_s_self.x + a_d.x + ael0 * inv;
    float al1 = a_s_self.y + a_d.y + ael1 * inv;
    al0 = LRELU(al0); al1 = LRELU(al1);
    float wself0 = expf(al0), wself1 = expf(al1);

    int col0 = w * 128 + lc * 8;                    // 8 cols per lane
    const unsigned short* xrow = xs1b + col0;       // + s*256 per gather
    float acc[8];
#pragma unroll
    for (int j = 0; j < 8; ++j) acc[j] = 0.f;
    float dp0 = 0.f, dp1 = 0.f;

    for (int base = 0; base < deg; base += 64) {
        int cnt = min(64, deg - base);
        float w0 = 0.f, w1 = 0.f;
        int s = 0;
        if (c < cnt) {
            int idx = off + base + c;
            int pk = csr_pack[idx];
            s = pk & 0x0FFFFFFF;
            float2 wv = *(const float2*)&wbuf[(long)idx * 4 + 2 * w];
            w0 = wv.x; w1 = wv.y;
        }
        dp0 += w0; dp1 += w1;
        ws[w][c] = make_float4(w0, w1, __int_as_float(s), 0.f);
        int cr = (cnt + 7) & ~7;
        for (int i = 0; i < cr; i += 8) {
#pragma unroll
            for (int u = 0; u < 2; ++u) {
                float4 p = ws[w][i + u * 4 + g];
                float wl = (lc < 8) ? p.x : p.y;
                uint4 q = *(const uint4*)&xrow[(long)__float_as_int(p.z) * 256];
                acc[0] += wl * bflo(q.x); acc[1] += wl * bfhi(q.x);
                acc[2] += wl * bflo(q.y); acc[3] += wl * bfhi(q.y);
                acc[4] += wl * bflo(q.z); acc[5] += wl * bfhi(q.z);
                acc[6] += wl * bflo(q.w); acc[7] += wl * bfhi(q.w);
            }
        }
    }
#pragma unroll
    for (int k = 32; k; k >>= 1) {
        dp0 += __shfl_xor(dp0, k, 64);
        dp1 += __shfl_xor(dp1, k, 64);
    }
#pragma unroll
    for (int j = 0; j < 8; ++j) {
        acc[j] += __shfl_xor(acc[j], 16, 64);
        acc[j] += __shfl_xor(acc[j], 32, 64);
    }
    uint4 us = *(const uint4*)&xrow[(long)n * 256];
    float wself_l = (lc < 8) ? wself0 : wself1;
    acc[0] += wself_l * bflo(us.x); acc[1] += wself_l * bfhi(us.x);
    acc[2] += wself_l * bflo(us.y); acc[3] += wself_l * bfhi(us.y);
    acc[4] += wself_l * bflo(us.z); acc[5] += wself_l * bfhi(us.z);
    acc[6] += wself_l * bflo(us.w); acc[7] += wself_l * bfhi(us.w);
    float dsum = ((lc < 8) ? dp0 + wself0 : dp1 + wself1) + 1e-16f;
    float rd = 1.f / dsum;
    uint4 ur = *(const uint4*)&res[(long)n * 256 + col0];
    float v[8];
    v[0] = acc[0] * rd + bflo(ur.x); v[1] = acc[1] * rd + bfhi(ur.x);
    v[2] = acc[2] * rd + bflo(ur.y); v[3] = acc[3] * rd + bfhi(ur.y);
    v[4] = acc[4] * rd + bflo(ur.z); v[5] = acc[5] * rd + bfhi(ur.z);
    v[6] = acc[6] * rd + bflo(ur.w); v[7] = acc[7] * rd + bfhi(ur.w);
    float s1 = 0.f, s2 = 0.f;
#pragma unroll
    for (int j = 0; j < 8; ++j) { s1 += v[j]; s2 += v[j] * v[j]; }
#pragma unroll
    for (int k = 32; k; k >>= 1) {
        s1 += __shfl_xor(s1, k, 64);
        s2 += __shfl_xor(s2, k, 64);
    }
    if (c == 0) { red[w] = s1 * 0.25f; red[2 + w] = s2 * 0.25f; }
    __syncthreads();
    float mu = (red[0] + red[1]) * (1.f / 256.f);
    float var = (red[2] + red[3]) * (1.f / 256.f) - mu * mu;
    float rs = rsqrtf(var + 1e-5f);
    if (g == 0) {
        float4 lg0 = *(const float4*)&ln_g[col0];
        float4 lg1 = *(const float4*)&ln_g[col0 + 4];
        float4 lb0 = *(const float4*)&ln_b[col0];
        float4 lb1 = *(const float4*)&ln_b[col0 + 4];
        float y[8];
        y[0] = fmaxf((v[0] - mu) * rs * lg0.x + lb0.x, 0.f);
        y[1] = fmaxf((v[1] - mu) * rs * lg0.y + lb0.y, 0.f);
        y[2] = fmaxf((v[2] - mu) * rs * lg0.z + lb0.z, 0.f);
        y[3] = fmaxf((v[3] - mu) * rs * lg0.w + lb0.w, 0.f);
        y[4] = fmaxf((v[4] - mu) * rs * lg1.x + lb1.x, 0.f);
        y[5] = fmaxf((v[5] - mu) * rs * lg1.y + lb1.y, 0.f);
        y[6] = fmaxf((v[6] - mu) * rs * lg1.z + lb1.z, 0.f);
        y[7] = fmaxf((v[7] - mu) * rs * lg1.w + lb1.w, 0.f);
        uint4 o;
        o.x = cvtpk(y[0], y[1]); o.y = cvtpk(y[2], y[3]);
        o.z = cvtpk(y[4], y[5]); o.w = cvtpk(y[6], y[7]);
        *(uint4*)&out[(long)n * 256 + col0] = o;
    }
}

// ------------------- GAT layer 2 (H=1, C=64): 2 nodes per 128-thread block.
__global__ __launch_bounds__(128) void k_gat2(
    const unsigned short* __restrict__ xs2b, const float* __restrict__ a_src,
    const float* __restrict__ a_dst, const int* __restrict__ row_off,
    const int* __restrict__ csr_pack,
    const int* __restrict__ cnt_t, const float* __restrict__ aet2,
    const float* __restrict__ ln_g, const float* __restrict__ ln_b,
    float* io, int N)
{
    __shared__ __align__(8) float2 ws[2][64];
    int v_ = threadIdx.x >> 6, c = threadIdx.x & 63;
    int n = blockIdx.x * 2 + v_;
    if (n >= N) return;
    int lc = c & 15, g = c >> 4;
    int off = row_off[n], deg = row_off[n + 1] - off;
    float a_d = a_dst[n];
    float ael = 0.f;
    int degc = 0;
#pragma unroll
    for (int ty = 0; ty < 4; ++ty) {
        int ct = cnt_t[n * 4 + ty];
        degc += ct;
        ael += (float)ct * aet2[ty];
    }
    ael *= (degc > 0 ? 1.f / (float)degc : 1.f);
    float al = a_src[n] + a_d + ael;
    al = LRELU(al);
    float wself = expf(al);

    int colb = lc * 4;
    const unsigned short* xrow = xs2b + colb;
    float acc[4] = {0.f, 0.f, 0.f, 0.f};
    float dp = 0.f;
    for (int base = 0; base < deg; base += 64) {
        int cnt = min(64, deg - base);
        float we = 0.f;
        int s = 0;
        if (c < cnt) {
            int pk = csr_pack[off + base + c];
            s = pk & 0x0FFFFFFF;
            int ty = ((unsigned)pk) >> 28;
            float a = a_src[s] + a_d + aet2[ty];
            a = LRELU(a);
            we = expf(a);
        }
        dp += we;
        ws[v_][c] = make_float2(we, __int_as_float(s));
        int cr = (cnt + 7) & ~7;
        for (int i = 0; i < cr; i += 8) {
#pragma unroll
            for (int u = 0; u < 2; ++u) {
                float2 p = ws[v_][i + u * 4 + g];
                uint2 q = *(const uint2*)&xrow[(long)__float_as_int(p.y) * 64];
                acc[0] += p.x * bflo(q.x); acc[1] += p.x * bfhi(q.x);
                acc[2] += p.x * bflo(q.y); acc[3] += p.x * bfhi(q.y);
            }
        }
    }
#pragma unroll
    for (int k = 32; k; k >>= 1) dp += __shfl_xor(dp, k, 64);
#pragma unroll
    for (int j = 0; j < 4; ++j) {
        acc[j] += __shfl_xor(acc[j], 16, 64);
        acc[j] += __shfl_xor(acc[j], 32, 64);
    }
    uint2 us = *(const uint2*)&xrow[(long)n * 64];
    acc[0] += wself * bflo(us.x); acc[1] += wself * bfhi(us.x);
    acc[2] += wself * bflo(us.y); acc[3] += wself * bfhi(us.y);
    float dsum = dp + wself + 1e-16f;
    float rd = 1.f / dsum;
    float4 r = *(const float4*)&io[(long)n * 64 + colb];
    float v[4];
    v[0] = acc[0] * rd + r.x; v[1] = acc[1] * rd + r.y;
    v[2] = acc[2] * rd + r.z; v[3] = acc[3] * rd + r.w;
    float s1 = v[0] + v[1] + v[2] + v[3];
    float s2 = v[0] * v[0] + v[1] * v[1] + v[2] * v[2] + v[3] * v[3];
#pragma unroll
    for (int k = 32; k; k >>= 1) {
        s1 += __shfl_xor(s1, k, 64);
        s2 += __shfl_xor(s2, k, 64);
    }
    float mu = s1 * (1.f / 256.f);
    float var = s2 * (1.f / 256.f) - mu * mu;
    float rs = rsqrtf(var + 1e-5f);
    if (g == 0) {
        float4 lg = *(const float4*)&ln_g[colb];
        float4 lb = *(const float4*)&ln_b[colb];
        float4 y;
        y.x = (v[0] - mu) * rs * lg.x + lb.x;
        y.y = (v[1] - mu) * rs * lg.y + lb.y;
        y.z = (v[2] - mu) * rs * lg.z + lb.z;
        y.w = (v[3] - mu) * rs * lg.w + lb.w;
        *(float4*)&io[(long)n * 64 + colb] = y;
    }
}

// --------------------------------------------------------------- classifier
__global__ __launch_bounds__(256) void k_cls(
    const float* __restrict__ hid2, const int* __restrict__ asp,
    const float* __restrict__ w, const float* __restrict__ b,
    float* __restrict__ out)
{
    int g = blockIdx.x * 256 + threadIdx.x;
    int i = g / 3, j = g - i * 3;
    int a = asp[i];
    float acc = b[j];
#pragma unroll 8
    for (int cc = 0; cc < 64; ++cc) acc += hid2[(long)a * 64 + cc] * w[cc * 3 + j];
    out[i * 3 + j] = acc;
}

extern "C" void kernel_launch(void* const* d_in, const int* in_sizes, int n_in,
                              void* d_out, int out_size, void* d_ws, size_t ws_size,
                              hipStream_t stream)
{
    const float* features    = (const float*)d_in[0];
    const int*   edge_index  = (const int*)d_in[1];
    const int*   aspect      = (const int*)d_in[2];
    const int*   etypes      = (const int*)d_in[3];
    const int*   ntypes      = (const int*)d_in[4];
    const float* pos         = (const float*)d_in[5];
    const float* fe_w1       = (const float*)d_in[6];
    const float* fe_b1       = (const float*)d_in[7];
    const float* fe_w2       = (const float*)d_in[8];
    const float* fe_b2       = (const float*)d_in[9];
    const float* fe_pos_w    = (const float*)d_in[10];
    const float* fe_pos_b    = (const float*)d_in[11];
    const float* fe_type_emb = (const float*)d_in[12];
    const float* fe_out_w    = (const float*)d_in[13];
    const float* fe_out_b    = (const float*)d_in[14];
    const float* g1_lin_w    = (const float*)d_in[15];
    const float* g1_att_src  = (const float*)d_in[16];
    const float* g1_att_dst  = (const float*)d_in[17];
    const float* g1_edge_emb = (const float*)d_in[18];
    const float* g1_lin_edge = (const float*)d_in[19];
    const float* g1_att_edge = (const float*)d_in[20];
    const float* g1_bias     = (const float*)d_in[21];
    const float* g1_res_w    = (const float*)d_in[22];
    const float* g1_res_b    = (const float*)d_in[23];
    const float* g1_ln_g     = (const float*)d_in[24];
    const float* g1_ln_b     = (const float*)d_in[25];
    const float* g2_lin_w    = (const float*)d_in[26];
    const float* g2_att_src  = (const float*)d_in[27];
    const float* g2_att_dst  = (const float*)d_in[28];
    const float* g2_edge_emb = (const float*)d_in[29];
    const float* g2_lin_edge = (const float*)d_in[30];
    const float* g2_att_edge = (const float*)d_in[31];
    const float* g2_bias     = (const float*)d_in[32];
    const float* g2_res_w    = (const float*)d_in[33];
    const float* g2_res_b    = (const float*)d_in[34];
    const float* g2_ln_g     = (const float*)d_in[35];
    const float* g2_ln_b     = (const float*)d_in[36];
    const float* cls_w       = (const float*)d_in[37];
    const float* cls_b       = (const float*)d_in[38];

    const int N = in_sizes[0] / 768;   // 50000
    const int E = in_sizes[1] / 2;     // 800000
    const int* src = edge_index;
    const int* dst = edge_index + E;

    char* wsb = (char*)d_ws;
    size_t off = 0;
    auto alloc = [&](size_t bytes) -> char* {
        char* p = wsb + off;
        off += (bytes + 255) & ~(size_t)255;
        return p;
    };
    unsigned short* xs1b = (unsigned short*)alloc((size_t)N * 256 * 2);
    unsigned short* xs2b = (unsigned short*)alloc((size_t)N * 64 * 2);
    unsigned short* hid1b= (unsigned short*)alloc((size_t)N * 256 * 2);
    unsigned short* rp1  = (unsigned short*)alloc((size_t)N * 256 * 2);  // res1 bf16
    float* rp2     = (float*)alloc((size_t)N * 64 * 4);   // res_pre2, then hid2
    float* a_src1  = (float*)alloc((size_t)N * 4 * 4);
    float* a_dst1  = (float*)alloc((size_t)N * 4 * 4);
    float* a_src2  = (float*)alloc((size_t)N * 4);
    float* a_dst2  = (float*)alloc((size_t)N * 4);
    int*   cnt_t   = (int*)alloc((size_t)N * 4 * 4);
    int*   row_off = (int*)alloc((size_t)(N + 1) * 4);
    int*   cursor  = (int*)alloc((size_t)N * 4);
    int*   blk     = (int*)alloc(1024);
    int*   csr_pack= (int*)alloc((size_t)E * 4);
    float* wbuf    = (float*)alloc((size_t)E * 4 * 4);    // per-edge weights
    float* aet1    = (float*)alloc(64);
    float* aet2    = (float*)alloc(64);
    unsigned short* bz_fe1 = (unsigned short*)alloc(768 * 64 * 2);
    unsigned short* bz_p1  = (unsigned short*)alloc(64 * 512 * 2);
    unsigned short* bz_p2  = (unsigned short*)alloc(256 * 128 * 2);
    float* C0t     = (float*)alloc(512 * 4);
    float* Tt      = (float*)alloc(3 * 512 * 4);
    float* Pt      = (float*)alloc(512 * 4);

    hipMemsetAsync(cnt_t, 0, (size_t)N * 4 * 4, stream);

    int mb = (N + 63) / 64;   // 782 row-tiles
    int eblk = (E + 255) / 256;
    int nb = (N + 255) / 256;

    k_front<<<705, 256, 0, stream>>>(
        g1_edge_emb, g1_lin_edge, g1_att_edge,
        g2_edge_emb, g2_lin_edge, g2_att_edge, aet1, aet2,
        fe_w1, g2_lin_w, g2_res_w, bz_fe1, bz_p2,
        fe_w2, fe_out_w, fe_b2, fe_pos_b, fe_out_b, fe_type_emb, fe_pos_w,
        g1_lin_w, g1_res_w, g1_bias, g1_res_b, bz_p1, C0t, Tt, Pt,
        dst, etypes, cnt_t, E);
    k_scan1<<<nb, 256, 0, stream>>>(cnt_t, row_off, blk, N);
    k_scan3<<<nb, 256, 0, stream>>>(row_off, cursor, blk, N, E);
    k_fp1<<<mb, 256, 0, stream>>>(
        features, bz_fe1, fe_b1, bz_p1, C0t, Tt, Pt, ntypes, pos,
        g1_att_src, g1_att_dst, xs1b, rp1, a_src1, a_dst1, N);
    k_scatter<<<eblk, 256, 0, stream>>>(src, dst, etypes, cursor, csr_pack,
                                        a_src1, a_dst1, aet1, wbuf, E);
    k_gat1<<<N, 128, 0, stream>>>(xs1b, a_src1, a_dst1, row_off, csr_pack, wbuf,
                                  cnt_t, aet1, g1_ln_g, g1_ln_b, rp1, hid1b);
    k_prep2<<<mb, 256, 0, stream>>>(hid1b, bz_p2, g2_bias, g2_res_b,
                                    g2_att_src, g2_att_dst, xs2b, rp2,
                                    a_src2, a_dst2, N);
    k_gat2<<<(N + 1) / 2, 128, 0, stream>>>(xs2b, a_src2, a_dst2, row_off,
                                            csr_pack, cnt_t, aet2,
                                            g2_ln_g, g2_ln_b, rp2, N);
    k_cls<<<(out_size + 255) / 256, 256, 0, stream>>>(rp2, aspect, cls_w, cls_b,
                                                      (float*)d_out);
}

// Round 9
// 566.371 us; speedup vs baseline: 1.1325x; 1.0082x over previous
//
#include <hip/hip_runtime.h>

// SimplifiedHAFE on MI355X — round 15: fp1 B-fragments via LDS (counter split).
//  r14 analysis: vmcnt is in-order, so the 8 global B-fragment loads per
//  chunk serialized behind the A-prefetch — waiting on B forced A complete,
//  killing the overlap. This round stages the per-chunk B tile (8 KB) into
//  LDS with the r5-r8-proven two-barrier reg-copy pattern (T14 split:
//  stage-loads issued one iteration ahead). B reads become lgkmcnt ds_reads;
//  vmcnt holds only 4 A-loads + 2 B-stage loads per chunk (was 12).
//  Cooperative staging also cuts per-CU L2 traffic on bzfe 4x.
//  Everything outside fp1 phase A is byte-identical to r14 (571 us, passed).

#define LRELU(x) ((x) > 0.f ? (x) : 0.2f * (x))

typedef __attribute__((ext_vector_type(8))) short short8;
typedef __attribute__((ext_vector_type(4))) float floatx4;

#define MFMA16(a, b, c) __builtin_amdgcn_mfma_f32_16x16x32_bf16(a, b, c, 0, 0, 0)

__device__ __forceinline__ unsigned short f2bf(float x) {
    union { float f; unsigned int u; } v; v.f = x;
    unsigned int r = (v.u + 0x7FFFu + ((v.u >> 16) & 1u)) >> 16;  // RNE
    return (unsigned short)r;
}
// pack 2 fp32 -> 2 bf16 (RNE) in one VALU; lo in low 16 bits
__device__ __forceinline__ unsigned int cvtpk(float lo, float hi) {
    unsigned int r;
    asm("v_cvt_pk_bf16_f32 %0, %1, %2" : "=v"(r) : "v"(lo), "v"(hi));
    return r;
}
__device__ __forceinline__ float bflo(unsigned int u) {
    return __uint_as_float(u << 16);
}
__device__ __forceinline__ float bfhi(unsigned int u) {
    return __uint_as_float(u & 0xFFFF0000u);
}
__device__ __forceinline__ float bf1(unsigned short u) {
    return __uint_as_float(((unsigned int)u) << 16);
}

// ---------------- front matter (grid = 705):
//   b0          : edge-type attention tables (aet1, aet2)
//   b1..320     : B pre-swizzles for fe1 (768x64) and prep2 (256x128)
//   b321..448   : fuse2 — bz_p1 = (w2@outw)@[lin|res] frag-order bf16 + C0/T/P
//   b449..704   : edge count histogram (grid-stride; cnt_t pre-zeroed)
__global__ __launch_bounds__(256) void k_front(
    const float* __restrict__ e_emb1, const float* __restrict__ lew1,
    const float* __restrict__ ae1,
    const float* __restrict__ e_emb2, const float* __restrict__ lew2,
    const float* __restrict__ ae2,
    float* __restrict__ aet1, float* __restrict__ aet2,
    const float* __restrict__ w1, const float* __restrict__ B1,
    const float* __restrict__ B2,
    unsigned short* __restrict__ out_fe1, unsigned short* __restrict__ out_p2,
    const float* __restrict__ w2, const float* __restrict__ outw,
    const float* __restrict__ b2, const float* __restrict__ posb,
    const float* __restrict__ outb, const float* __restrict__ temb,
    const float* __restrict__ posw,
    const float* __restrict__ lin_w, const float* __restrict__ res_w,
    const float* __restrict__ bias, const float* __restrict__ res_b,
    unsigned short* __restrict__ bz, float* __restrict__ C0,
    float* __restrict__ T, float* __restrict__ P,
    const int* __restrict__ dst, const int* __restrict__ et,
    int* __restrict__ cnt_t, int E)
{
    int t = threadIdx.x;
    int b = blockIdx.x;
    if (b == 0) {
        __shared__ float M1[16];
        __shared__ float M2[4];
        if (t < 16) {
            int d = t >> 2, h = t & 3;
            float s = 0.f;
            for (int c = 0; c < 64; ++c) s += lew1[d * 256 + h * 64 + c] * ae1[h * 64 + c];
            M1[d * 4 + h] = s;
        }
        if (t < 4) {
            float s = 0.f;
            for (int c = 0; c < 64; ++c) s += lew2[t * 64 + c] * ae2[c];
            M2[t] = s;
        }
        __syncthreads();
        if (t < 16) {
            int ty = t >> 2, h = t & 3;
            float s = 0.f;
            for (int d = 0; d < 4; ++d) s += e_emb1[ty * 4 + d] * M1[d * 4 + h];
            aet1[ty * 4 + h] = s;
        }
        if (t < 4) {
            float s = 0.f;
            for (int d = 0; d < 4; ++d) s += e_emb2[t * 4 + d] * M2[d];
            aet2[t] = s;
        }
    } else if (b <= 320) {
        int idx = (b - 1) * 256 + t;
        if (idx < 768 * 64) {
            int k = idx >> 6, col = idx & 63;
            int c = k >> 6, kl = k & 63, kg = kl >> 3, j = kl & 7;
            out_fe1[((c * 8 + kg) * 64 + col) * 8 + j] = f2bf(w1[k * 64 + col]);
        } else {
            int i2 = idx - 768 * 64;          // 256*128 elements
            int k = i2 >> 7, col = i2 & 127;
            float v = (col < 64) ? B1[k * 64 + col] : B2[k * 64 + col - 64];
            int c = k >> 6, kl = k & 63, kg = kl >> 3, j = kl & 7;
            out_p2[((c * 8 + kg) * 128 + col) * 8 + j] = f2bf(v);
        }
    } else if (b <= 448) {
        __shared__ float sb[4][64];
        __shared__ float sy[4][64];
        int wv = t >> 6, j = t & 63;
        int c = (b - 321) * 4 + wv;       // 0..511
        int cL = c & 255;
        const float* Bsrc = (c < 256) ? lin_w : res_w;
        float bv = Bsrc[j * 256 + cL];
        sb[wv][j] = bv;
        __syncthreads();
        float yj = 0.f;
#pragma unroll 8
        for (int k = 0; k < 64; ++k) yj += outw[j * 64 + k] * sb[wv][k];
        sy[wv][j] = yj;
        __syncthreads();
        float s = 0.f;
#pragma unroll 8
        for (int m = 0; m < 64; ++m) s += w2[j * 64 + m] * sy[wv][m];
        int kg = j >> 3, jj = j & 7, ct = c >> 7, cl = c & 127;
        bz[((ct * 8 + kg) * 128 + cl) * 8 + jj] = f2bf(s);
        float pc = outb[j] * bv + (b2[j] + posb[j]) * yj;
        float p0 = temb[j] * yj, p1 = temb[64 + j] * yj, p2 = temb[128 + j] * yj;
        float pp = posw[j] * yj;
#pragma unroll
        for (int k = 32; k; k >>= 1) {
            pc += __shfl_xor(pc, k, 64); p0 += __shfl_xor(p0, k, 64);
            p1 += __shfl_xor(p1, k, 64); p2 += __shfl_xor(p2, k, 64);
            pp += __shfl_xor(pp, k, 64);
        }
        if (j == 0) {
            C0[c] = pc + ((c >= 256) ? (bias[cL] + res_b[cL]) : 0.f);
            T[c] = p0; T[512 + c] = p1; T[1024 + c] = p2;
            P[c] = pp;
        }
    } else {
        for (int e = (b - 449) * 256 + t; e < E; e += 256 * 256)
            atomicAdd(&cnt_t[dst[e] * 4 + et[e]], 1);
    }
}

// ------------- fp1: fused fe1 + prep1.
// Phase A: relu(X@W1+b1) -> bf16 tile in LDS. B-chunk (8 KB) staged into LDS
//   per iteration (two-barrier reg-copy, stage loads issued one iter ahead);
//   A rows prefetched distance-1 in regs. vmcnt holds 6 loads/chunk (was 12),
//   B reads are lgkmcnt ds_reads.
// Phase B: tile @ BLR[64x512] by column quarters + fe2-tail adds + att dots.
__global__ __launch_bounds__(256) void k_fp1(
    const float* __restrict__ feat, const unsigned short* __restrict__ bzfe,
    const float* __restrict__ b1,
    const unsigned short* __restrict__ bzp1,
    const float* __restrict__ C0, const float* __restrict__ T,
    const float* __restrict__ P, const int* __restrict__ ntypes,
    const float* __restrict__ pos,
    const float* __restrict__ att_s, const float* __restrict__ att_d,
    unsigned short* __restrict__ xsb, unsigned short* __restrict__ resp,
    float* __restrict__ a_src, float* __restrict__ a_dst, int N)
{
    __shared__ __align__(16) unsigned short tl[64 * 72];   // 9 KiB, pad 64->72
    __shared__ __align__(16) unsigned short Bl[4096];      // 8 KiB B chunk
    int t = threadIdx.x;
    int wv = t >> 6, lane = t & 63;
    int quad = lane >> 4, l16 = lane & 15;
    long rb = (long)blockIdx.x * 64;

    // ---- phase A: fe1 GEMM (rows rb+wv*16 .. +15, cols 0..63)
    {
        long ra = rb + wv * 16 + l16;
        if (ra >= N) ra = N - 1;
        const float* fbase = feat + ra * 768 + quad * 8;
        floatx4 acc[4];
#pragma unroll
        for (int i = 0; i < 4; ++i) acc[i] = (floatx4){0.f, 0.f, 0.f, 0.f};

        // B staging: thread t owns 32 B (2 uint4) of the 8 KB chunk tile.
        const uint4* bsrc = (const uint4*)bzfe;   // chunk ci = uint4 [ci*512..)
        int bidx = t * 2;
        uint4 bq0 = bsrc[bidx];
        uint4 bq1 = bsrc[bidx + 1];

        // A prologue: chunk 0 loads
        float4 n0 = *(const float4*)(fbase);
        float4 n1 = *(const float4*)(fbase + 4);
        float4 n2 = *(const float4*)(fbase + 32);
        float4 n3 = *(const float4*)(fbase + 36);

        for (int ci = 0; ci < 12; ++ci) {
            __syncthreads();                  // prev iter's Bl ds_reads done
            *(uint4*)&Bl[bidx * 8] = bq0;     // stage chunk ci (loaded last iter)
            *(uint4*)&Bl[(bidx + 1) * 8] = bq1;
            float4 c0 = n0, c1 = n1, c2 = n2, c3 = n3;
            if (ci < 11) {                    // issue next chunk's loads
                bq0 = bsrc[(ci + 1) * 512 + bidx];
                bq1 = bsrc[(ci + 1) * 512 + bidx + 1];
                const float* fn = fbase + (ci + 1) * 64;
                n0 = *(const float4*)(fn);
                n1 = *(const float4*)(fn + 4);
                n2 = *(const float4*)(fn + 32);
                n3 = *(const float4*)(fn + 36);
            }
            __syncthreads();                  // Bl stores visible
            uint4 u0 = {cvtpk(c0.x, c0.y), cvtpk(c0.z, c0.w),
                        cvtpk(c1.x, c1.y), cvtpk(c1.z, c1.w)};
            uint4 u1 = {cvtpk(c2.x, c2.y), cvtpk(c2.z, c2.w),
                        cvtpk(c3.x, c3.y), cvtpk(c3.z, c3.w)};
            short8 af0 = *(short8*)&u0;
            short8 af1 = *(short8*)&u1;
#pragma unroll
            for (int ct = 0; ct < 4; ++ct) {
                short8 bf = *(const short8*)&Bl[(quad * 64 + ct * 16 + l16) * 8];
                acc[ct] = MFMA16(af0, bf, acc[ct]);
            }
#pragma unroll
            for (int ct = 0; ct < 4; ++ct) {
                short8 bf = *(const short8*)&Bl[((4 + quad) * 64 + ct * 16 + l16) * 8];
                acc[ct] = MFMA16(af1, bf, acc[ct]);
            }
        }
#pragma unroll
        for (int ct = 0; ct < 4; ++ct) {
            float bb = b1[ct * 16 + l16];
#pragma unroll
            for (int r = 0; r < 4; ++r) {
                int row = wv * 16 + quad * 4 + r;
                tl[row * 72 + ct * 16 + l16] = f2bf(fmaxf(acc[ct][r] + bb, 0.f));
            }
        }
    }
    __syncthreads();

    // ---- phase B: prep1 GEMM from LDS tile, 4 column quarters
    int rowB = wv * 16 + l16;
    short8 af0 = *(const short8*)&tl[rowB * 72 + quad * 8];
    short8 af1 = *(const short8*)&tl[rowB * 72 + quad * 8 + 32];
    long rwB = rb + wv * 16;
    int nta[4];
    float posa[4];
#pragma unroll
    for (int r = 0; r < 4; ++r) {
        long m = rwB + quad * 4 + r;
        if (m < N) { nta[r] = ntypes[m]; posa[r] = pos[m]; }
        else       { nta[r] = 0; posa[r] = 0.f; }
    }
    for (int by = 0; by < 4; ++by) {
        floatx4 acc[8];
#pragma unroll
        for (int i = 0; i < 8; ++i) acc[i] = (floatx4){0.f, 0.f, 0.f, 0.f};
#pragma unroll
        for (int s = 0; s < 2; ++s) {
            int kg = s * 4 + quad;
            short8 af = s ? af1 : af0;
#pragma unroll
            for (int c8 = 0; c8 < 8; ++c8) {
                short8 bfrag = *(const short8*)&bzp1[
                    ((by * 8 + kg) * 128 + c8 * 16 + l16) * 8];
                acc[c8] = MFMA16(af, bfrag, acc[c8]);
            }
        }
        bool isl = (by < 2);
        int cb = by * 128;
        float ps[2][4] = {{0.f,0.f,0.f,0.f},{0.f,0.f,0.f,0.f}};
        float pd[2][4] = {{0.f,0.f,0.f,0.f},{0.f,0.f,0.f,0.f}};
#pragma unroll
        for (int c8 = 0; c8 < 8; ++c8) {
            int gc = cb + c8 * 16 + l16;
            float c0 = C0[gc], pcf = P[gc];
            float as = 0.f, ad = 0.f;
            if (isl) { as = att_s[gc]; ad = att_d[gc]; }
            int hh = c8 >> 2;
#pragma unroll
            for (int r = 0; r < 4; ++r) {
                long m = rwB + quad * 4 + r;
                float val = acc[c8][r] + c0 + T[nta[r] * 512 + gc] + posa[r] * pcf;
                if (m < N) {
                    if (isl) xsb[m * 256 + gc] = f2bf(val);
                    else     resp[m * 256 + gc - 256] = f2bf(val);
                }
                ps[hh][r] += val * as;
                pd[hh][r] += val * ad;
            }
        }
        if (isl) {
#pragma unroll
            for (int h = 0; h < 2; ++h)
#pragma unroll
                for (int r = 0; r < 4; ++r) {
                    float a = ps[h][r], bq = pd[h][r];
#pragma unroll
                    for (int k = 1; k < 16; k <<= 1) {
                        a += __shfl_xor(a, k, 64);
                        bq += __shfl_xor(bq, k, 64);
                    }
                    long m = rwB + quad * 4 + r;
                    if (l16 == 0 && m < N) {
                        int h4 = by * 2 + h;
                        a_src[m * 4 + h4] = a;
                        a_dst[m * 4 + h4] = bq;
                    }
                }
        }
    }
}

// ------------- prep2: hid1b[Nx256] @ [lin|res][256x128] + fused attention
// dots for layer 2. cols<64 -> xs2 bf16; cols>=64 -> res fp32 (+bias+res_b).
__global__ __launch_bounds__(256) void k_prep2(
    const unsigned short* __restrict__ A, const unsigned short* __restrict__ bswz,
    const float* __restrict__ bias, const float* __restrict__ res_b,
    const float* __restrict__ att_s, const float* __restrict__ att_d,
    unsigned short* __restrict__ xsb, float* __restrict__ resp,
    float* __restrict__ a_src, float* __restrict__ a_dst, int N)
{
    int t = threadIdx.x;
    int wv = t >> 6, lane = t & 63;
    int quad = lane >> 4, l16 = lane & 15;
    long rw = (long)blockIdx.x * 64 + wv * 16;
    long ra = rw + l16;
    if (ra >= N) ra = N - 1;
    const unsigned short* abase = A + ra * 256 + quad * 8;

    floatx4 acc[8];
#pragma unroll
    for (int i = 0; i < 8; ++i) acc[i] = (floatx4){0.f, 0.f, 0.f, 0.f};

    for (int ci = 0; ci < 4; ++ci) {
        short8 af[2];
        af[0] = *(const short8*)(abase + ci * 64);
        af[1] = *(const short8*)(abase + ci * 64 + 32);
#pragma unroll
        for (int s = 0; s < 2; ++s) {
            int kg = s * 4 + quad;
#pragma unroll
            for (int c8 = 0; c8 < 8; ++c8) {
                short8 bfrag = *(const short8*)&bswz[
                    ((ci * 8 + kg) * 128 + c8 * 16 + l16) * 8];
                acc[c8] = MFMA16(af[s], bfrag, acc[c8]);
            }
        }
    }
    float ps[4] = {0.f,0.f,0.f,0.f}, pd[4] = {0.f,0.f,0.f,0.f};
#pragma unroll
    for (int c8 = 0; c8 < 8; ++c8) {
        int gc = c8 * 16 + l16;
        bool isl = gc < 64;
        float badd = isl ? 0.f : (bias[gc - 64] + res_b[gc - 64]);
        float as = isl ? att_s[gc] : 0.f;
        float ad = isl ? att_d[gc] : 0.f;
#pragma unroll
        for (int r = 0; r < 4; ++r) {
            long m = rw + quad * 4 + r;
            float val = acc[c8][r];
            if (m < N) {
                if (isl) xsb[m * 64 + gc] = f2bf(val);
                else     resp[m * 64 + gc - 64] = val + badd;
            }
            if (isl) { ps[r] += val * as; pd[r] += val * ad; }
        }
    }
#pragma unroll
    for (int r = 0; r < 4; ++r) {
        float a = ps[r], b = pd[r];
#pragma unroll
        for (int k = 1; k < 16; k <<= 1) {
            a += __shfl_xor(a, k, 64);
            b += __shfl_xor(b, k, 64);
        }
        long m = rw + quad * 4 + r;
        if (l16 == 0 && m < N) { a_src[m] = a; a_dst[m] = b; }
    }
}

// ---------------------------------------------------------------- CSR build
__global__ __launch_bounds__(256) void k_scan1(
    const int* __restrict__ cnt_t, int* __restrict__ row_off,
    int* __restrict__ blk_sums, int N)
{
    __shared__ int s[256];
    int t = threadIdx.x;
    int i = blockIdx.x * 256 + t;
    int v = 0;
    if (i < N) v = cnt_t[4 * i] + cnt_t[4 * i + 1] + cnt_t[4 * i + 2] + cnt_t[4 * i + 3];
    s[t] = v;
    __syncthreads();
    for (int off = 1; off < 256; off <<= 1) {
        int x = 0;
        if (t >= off) x = s[t - off];
        __syncthreads();
        s[t] += x;
        __syncthreads();
    }
    if (i < N) row_off[i] = s[t] - v;
    if (t == 255) blk_sums[blockIdx.x] = s[255];
}

// scan3 with scan2 absorbed: each block re-sums blk_sums[0..bid-1] (nb<=256).
__global__ __launch_bounds__(256) void k_scan3(
    int* __restrict__ row_off, int* __restrict__ cursor,
    const int* __restrict__ blk_sums, int N, int E)
{
    __shared__ int s[256];
    int t = threadIdx.x;
    int bid = blockIdx.x;
    s[t] = (t < bid) ? blk_sums[t] : 0;
    __syncthreads();
    for (int off = 128; off; off >>= 1) {
        if (t < off) s[t] += s[t + off];
        __syncthreads();
    }
    int prev = s[0];
    int i = bid * 256 + t;
    if (i < N) {
        int o = row_off[i] + prev;
        row_off[i] = o;
        cursor[i] = o;
    }
    if (i == 0) row_off[N] = E;
}

// scatter + gat1 edge-weight precompute: w[pos][h] = exp(lrelu(a_src[s,h] +
// a_dst[d,h] + aet1[ty,h])), fp32 (bitwise identical to the old in-gat1 calc).
__global__ __launch_bounds__(256) void k_scatter(
    const int* __restrict__ src, const int* __restrict__ dst,
    const int* __restrict__ et, int* __restrict__ cursor,
    int* __restrict__ csr_pack,
    const float* __restrict__ a_src, const float* __restrict__ a_dst,
    const float* __restrict__ aet1, float* __restrict__ wbuf, int E)
{
    int e = blockIdx.x * 256 + threadIdx.x;
    if (e < E) {
        int d = dst[e];
        int s = src[e];
        int ty = et[e];
        int pos = atomicAdd(&cursor[d], 1);
        csr_pack[pos] = s | (ty << 28);
        float4 as4 = *(const float4*)&a_src[s * 4];
        float4 ad4 = *(const float4*)&a_dst[d * 4];
        float4 ae = *(const float4*)&aet1[ty * 4];
        float a0 = as4.x + ad4.x + ae.x;
        float a1 = as4.y + ad4.y + ae.y;
        float a2 = as4.z + ad4.z + ae.z;
        float a3 = as4.w + ad4.w + ae.w;
        a0 = LRELU(a0); a1 = LRELU(a1); a2 = LRELU(a2); a3 = LRELU(a3);
        float4 w4 = make_float4(expf(a0), expf(a1), expf(a2), expf(a3));
        *(float4*)&wbuf[(long)pos * 4] = w4;
    }
}

// ---------------- GAT layer 1: 128 thr = 2 waves; wave w owns heads 2w,2w+1.
// Edge weights preloaded from wbuf; gather 4 edges/wave-iter dwordx4.
__global__ __launch_bounds__(128) void k_gat1(
    const unsigned short* __restrict__ xs1b, const float* __restrict__ a_src,
    const float* __restrict__ a_dst, const int* __restrict__ row_off,
    const int* __restrict__ csr_pack, const float* __restrict__ wbuf,
    const int* __restrict__ cnt_t, const float* __restrict__ aet1,
    const float* __restrict__ ln_g, const float* __restrict__ ln_b,
    const unsigned short* __restrict__ res, unsigned short* __restrict__ out)
{
    __shared__ __align__(16) float4 ws[2][64];
    __shared__ float2 aetp[2][4];
    __shared__ float red[4];
    int n = blockIdx.x;
    int t = threadIdx.x;
    int w = t >> 6, c = t & 63;
    int lc = c & 15, g = c >> 4;
    int h0 = 2 * w;
    if (t < 8) {
        int w2 = t >> 2, ty = t & 3;
        aetp[w2][ty] = make_float2(aet1[ty * 4 + 2 * w2], aet1[ty * 4 + 2 * w2 + 1]);
    }
    int off = row_off[n], deg = row_off[n + 1] - off;
    float2 a_d = *(const float2*)&a_dst[n * 4 + h0];
    __syncthreads();
    float ael0 = 0.f, ael1 = 0.f;
    int degc = 0;
#pragma unroll
    for (int ty = 0; ty < 4; ++ty) {
        int ct = cnt_t[n * 4 + ty];
        degc += ct;
        float2 ae = aetp[w][ty];
        ael0 += (float)ct * ae.x;
        ael1 += (float)ct * ae.y;
    }
    float inv = (degc > 0) ? 1.f / (float)degc : 1.f;
    float2 a_s_self = *(const float2*)&a_src[n * 4 + h0];
    float al0 = a_s_self.x + a_d.x + ael0 * inv;
    float al1 = a_s_self.y + a_d.y + ael1 * inv;
    al0 = LRELU(al0); al1 = LRELU(al1);
    float wself0 = expf(al0), wself1 = expf(al1);

    int col0 = w * 128 + lc * 8;                    // 8 cols per lane
    const unsigned short* xrow = xs1b + col0;       // + s*256 per gather
    float acc[8];
#pragma unroll
    for (int j = 0; j < 8; ++j) acc[j] = 0.f;
    float dp0 = 0.f, dp1 = 0.f;

    for (int base = 0; base < deg; base += 64) {
        int cnt = min(64, deg - base);
        float w0 = 0.f, w1 = 0.f;
        int s = 0;
        if (c < cnt) {
            int idx = off + base + c;
            int pk = csr_pack[idx];
            s = pk & 0x0FFFFFFF;
            float2 wv = *(const float2*)&wbuf[(long)idx * 4 + 2 * w];
            w0 = wv.x; w1 = wv.y;
        }
        dp0 += w0; dp1 += w1;
        ws[w][c] = make_float4(w0, w1, __int_as_float(s), 0.f);
        int cr = (cnt + 7) & ~7;
        for (int i = 0; i < cr; i += 8) {
#pragma unroll
            for (int u = 0; u < 2; ++u) {
                float4 p = ws[w][i + u * 4 + g];
                float wl = (lc < 8) ? p.x : p.y;
                uint4 q = *(const uint4*)&xrow[(long)__float_as_int(p.z) * 256];
                acc[0] += wl * bflo(q.x); acc[1] += wl * bfhi(q.x);
                acc[2] += wl * bflo(q.y); acc[3] += wl * bfhi(q.y);
                acc[4] += wl * bflo(q.z); acc[5] += wl * bfhi(q.z);
                acc[6] += wl * bflo(q.w); acc[7] += wl * bfhi(q.w);
            }
        }
    }
#pragma unroll
    for (int k = 32; k; k >>= 1) {
        dp0 += __shfl_xor(dp0, k, 64);
        dp1 += __shfl_xor(dp1, k, 64);
    }
#pragma unroll
    for (int j = 0; j < 8; ++j) {
        acc[j] += __shfl_xor(acc[j], 16, 64);
        acc[j] += __shfl_xor(acc[j], 32, 64);
    }
    uint4 us = *(const uint4*)&xrow[(long)n * 256];
    float wself_l = (lc < 8) ? wself0 : wself1;
    acc[0] += wself_l * bflo(us.x); acc[1] += wself_l * bfhi(us.x);
    acc[2] += wself_l * bflo(us.y); acc[3] += wself_l * bfhi(us.y);
    acc[4] += wself_l * bflo(us.z); acc[5] += wself_l * bfhi(us.z);
    acc[6] += wself_l * bflo(us.w); acc[7] += wself_l * bfhi(us.w);
    float dsum = ((lc < 8) ? dp0 + wself0 : dp1 + wself1) + 1e-16f;
    float rd = 1.f / dsum;
    uint4 ur = *(const uint4*)&res[(long)n * 256 + col0];
    float v[8];
    v[0] = acc[0] * rd + bflo(ur.x); v[1] = acc[1] * rd + bfhi(ur.x);
    v[2] = acc[2] * rd + bflo(ur.y); v[3] = acc[3] * rd + bfhi(ur.y);
    v[4] = acc[4] * rd + bflo(ur.z); v[5] = acc[5] * rd + bfhi(ur.z);
    v[6] = acc[6] * rd + bflo(ur.w); v[7] = acc[7] * rd + bfhi(ur.w);
    float s1 = 0.f, s2 = 0.f;
#pragma unroll
    for (int j = 0; j < 8; ++j) { s1 += v[j]; s2 += v[j] * v[j]; }
#pragma unroll
    for (int k = 32; k; k >>= 1) {
        s1 += __shfl_xor(s1, k, 64);
        s2 += __shfl_xor(s2, k, 64);
    }
    if (c == 0) { red[w] = s1 * 0.25f; red[2 + w] = s2 * 0.25f; }
    __syncthreads();
    float mu = (red[0] + red[1]) * (1.f / 256.f);
    float var = (red[2] + red[3]) * (1.f / 256.f) - mu * mu;
    float rs = rsqrtf(var + 1e-5f);
    if (g == 0) {
        float4 lg0 = *(const float4*)&ln_g[col0];
        float4 lg1 = *(const float4*)&ln_g[col0 + 4];
        float4 lb0 = *(const float4*)&ln_b[col0];
        float4 lb1 = *(const float4*)&ln_b[col0 + 4];
        float y[8];
        y[0] = fmaxf((v[0] - mu) * rs * lg0.x + lb0.x, 0.f);
        y[1] = fmaxf((v[1] - mu) * rs * lg0.y + lb0.y, 0.f);
        y[2] = fmaxf((v[2] - mu) * rs * lg0.z + lb0.z, 0.f);
        y[3] = fmaxf((v[3] - mu) * rs * lg0.w + lb0.w, 0.f);
        y[4] = fmaxf((v[4] - mu) * rs * lg1.x + lb1.x, 0.f);
        y[5] = fmaxf((v[5] - mu) * rs * lg1.y + lb1.y, 0.f);
        y[6] = fmaxf((v[6] - mu) * rs * lg1.z + lb1.z, 0.f);
        y[7] = fmaxf((v[7] - mu) * rs * lg1.w + lb1.w, 0.f);
        uint4 o;
        o.x = cvtpk(y[0], y[1]); o.y = cvtpk(y[2], y[3]);
        o.z = cvtpk(y[4], y[5]); o.w = cvtpk(y[6], y[7]);
        *(uint4*)&out[(long)n * 256 + col0] = o;
    }
}

// ------------------- GAT layer 2 (H=1, C=64): 2 nodes per 128-thread block.
__global__ __launch_bounds__(128) void k_gat2(
    const unsigned short* __restrict__ xs2b, const float* __restrict__ a_src,
    const float* __restrict__ a_dst, const int* __restrict__ row_off,
    const int* __restrict__ csr_pack,
    const int* __restrict__ cnt_t, const float* __restrict__ aet2,
    const float* __restrict__ ln_g, const float* __restrict__ ln_b,
    float* io, int N)
{
    __shared__ __align__(8) float2 ws[2][64];
    int v_ = threadIdx.x >> 6, c = threadIdx.x & 63;
    int n = blockIdx.x * 2 + v_;
    if (n >= N) return;
    int lc = c & 15, g = c >> 4;
    int off = row_off[n], deg = row_off[n + 1] - off;
    float a_d = a_dst[n];
    float ael = 0.f;
    int degc = 0;
#pragma unroll
    for (int ty = 0; ty < 4; ++ty) {
        int ct = cnt_t[n * 4 + ty];
        degc += ct;
        ael += (float)ct * aet2[ty];
    }
    ael *= (degc > 0 ? 1.f / (float)degc : 1.f);
    float al = a_src[n] + a_d + ael;
    al = LRELU(al);
    float wself = expf(al);

    int colb = lc * 4;
    const unsigned short* xrow = xs2b + colb;
    float acc[4] = {0.f, 0.f, 0.f, 0.f};
    float dp = 0.f;
    for (int base = 0; base < deg; base += 64) {
        int cnt = min(64, deg - base);
        float we = 0.f;
        int s = 0;
        if (c < cnt) {
            int pk = csr_pack[off + base + c];
            s = pk & 0x0FFFFFFF;
            int ty = ((unsigned)pk) >> 28;
            float a = a_src[s] + a_d + aet2[ty];
            a = LRELU(a);
            we = expf(a);
        }
        dp += we;
        ws[v_][c] = make_float2(we, __int_as_float(s));
        int cr = (cnt + 7) & ~7;
        for (int i = 0; i < cr; i += 8) {
#pragma unroll
            for (int u = 0; u < 2; ++u) {
                float2 p = ws[v_][i + u * 4 + g];
                uint2 q = *(const uint2*)&xrow[(long)__float_as_int(p.y) * 64];
                acc[0] += p.x * bflo(q.x); acc[1] += p.x * bfhi(q.x);
                acc[2] += p.x * bflo(q.y); acc[3] += p.x * bfhi(q.y);
            }
        }
    }
#pragma unroll
    for (int k = 32; k; k >>= 1) dp += __shfl_xor(dp, k, 64);
#pragma unroll
    for (int j = 0; j < 4; ++j) {
        acc[j] += __shfl_xor(acc[j], 16, 64);
        acc[j] += __shfl_xor(acc[j], 32, 64);
    }
    uint2 us = *(const uint2*)&xrow[(long)n * 64];
    acc[0] += wself * bflo(us.x); acc[1] += wself * bfhi(us.x);
    acc[2] += wself * bflo(us.y); acc[3] += wself * bfhi(us.y);
    float dsum = dp + wself + 1e-16f;
    float rd = 1.f / dsum;
    float4 r = *(const float4*)&io[(long)n * 64 + colb];
    float v[4];
    v[0] = acc[0] * rd + r.x; v[1] = acc[1] * rd + r.y;
    v[2] = acc[2] * rd + r.z; v[3] = acc[3] * rd + r.w;
    float s1 = v[0] + v[1] + v[2] + v[3];
    float s2 = v[0] * v[0] + v[1] * v[1] + v[2] * v[2] + v[3] * v[3];
#pragma unroll
    for (int k = 32; k; k >>= 1) {
        s1 += __shfl_xor(s1, k, 64);
        s2 += __shfl_xor(s2, k, 64);
    }
    float mu = s1 * (1.f / 256.f);
    float var = s2 * (1.f / 256.f) - mu * mu;
    float rs = rsqrtf(var + 1e-5f);
    if (g == 0) {
        float4 lg = *(const float4*)&ln_g[colb];
        float4 lb = *(const float4*)&ln_b[colb];
        float4 y;
        y.x = (v[0] - mu) * rs * lg.x + lb.x;
        y.y = (v[1] - mu) * rs * lg.y + lb.y;
        y.z = (v[2] - mu) * rs * lg.z + lb.z;
        y.w = (v[3] - mu) * rs * lg.w + lb.w;
        *(float4*)&io[(long)n * 64 + colb] = y;
    }
}

// --------------------------------------------------------------- classifier
__global__ __launch_bounds__(256) void k_cls(
    const float* __restrict__ hid2, const int* __restrict__ asp,
    const float* __restrict__ w, const float* __restrict__ b,
    float* __restrict__ out)
{
    int g = blockIdx.x * 256 + threadIdx.x;
    int i = g / 3, j = g - i * 3;
    int a = asp[i];
    float acc = b[j];
#pragma unroll 8
    for (int cc = 0; cc < 64; ++cc) acc += hid2[(long)a * 64 + cc] * w[cc * 3 + j];
    out[i * 3 + j] = acc;
}

extern "C" void kernel_launch(void* const* d_in, const int* in_sizes, int n_in,
                              void* d_out, int out_size, void* d_ws, size_t ws_size,
                              hipStream_t stream)
{
    const float* features    = (const float*)d_in[0];
    const int*   edge_index  = (const int*)d_in[1];
    const int*   aspect      = (const int*)d_in[2];
    const int*   etypes      = (const int*)d_in[3];
    const int*   ntypes      = (const int*)d_in[4];
    const float* pos         = (const float*)d_in[5];
    const float* fe_w1       = (const float*)d_in[6];
    const float* fe_b1       = (const float*)d_in[7];
    const float* fe_w2       = (const float*)d_in[8];
    const float* fe_b2       = (const float*)d_in[9];
    const float* fe_pos_w    = (const float*)d_in[10];
    const float* fe_pos_b    = (const float*)d_in[11];
    const float* fe_type_emb = (const float*)d_in[12];
    const float* fe_out_w    = (const float*)d_in[13];
    const float* fe_out_b    = (const float*)d_in[14];
    const float* g1_lin_w    = (const float*)d_in[15];
    const float* g1_att_src  = (const float*)d_in[16];
    const float* g1_att_dst  = (const float*)d_in[17];
    const float* g1_edge_emb = (const float*)d_in[18];
    const float* g1_lin_edge = (const float*)d_in[19];
    const float* g1_att_edge = (const float*)d_in[20];
    const float* g1_bias     = (const float*)d_in[21];
    const float* g1_res_w    = (const float*)d_in[22];
    const float* g1_res_b    = (const float*)d_in[23];
    const float* g1_ln_g     = (const float*)d_in[24];
    const float* g1_ln_b     = (const float*)d_in[25];
    const float* g2_lin_w    = (const float*)d_in[26];
    const float* g2_att_src  = (const float*)d_in[27];
    const float* g2_att_dst  = (const float*)d_in[28];
    const float* g2_edge_emb = (const float*)d_in[29];
    const float* g2_lin_edge = (const float*)d_in[30];
    const float* g2_att_edge = (const float*)d_in[31];
    const float* g2_bias     = (const float*)d_in[32];
    const float* g2_res_w    = (const float*)d_in[33];
    const float* g2_res_b    = (const float*)d_in[34];
    const float* g2_ln_g     = (const float*)d_in[35];
    const float* g2_ln_b     = (const float*)d_in[36];
    const float* cls_w       = (const float*)d_in[37];
    const float* cls_b       = (const float*)d_in[38];

    const int N = in_sizes[0] / 768;   // 50000
    const int E = in_sizes[1] / 2;     // 800000
    const int* src = edge_index;
    const int* dst = edge_index + E;

    char* wsb = (char*)d_ws;
    size_t off = 0;
    auto alloc = [&](size_t bytes) -> char* {
        char* p = wsb + off;
        off += (bytes + 255) & ~(size_t)255;
        return p;
    };
    unsigned short* xs1b = (unsigned short*)alloc((size_t)N * 256 * 2);
    unsigned short* xs2b = (unsigned short*)alloc((size_t)N * 64 * 2);
    unsigned short* hid1b= (unsigned short*)alloc((size_t)N * 256 * 2);
    unsigned short* rp1  = (unsigned short*)alloc((size_t)N * 256 * 2);  // res1 bf16
    float* rp2     = (float*)alloc((size_t)N * 64 * 4);   // res_pre2, then hid2
    float* a_src1  = (float*)alloc((size_t)N * 4 * 4);
    float* a_dst1  = (float*)alloc((size_t)N * 4 * 4);
    float* a_src2  = (float*)alloc((size_t)N * 4);
    float* a_dst2  = (float*)alloc((size_t)N * 4);
    int*   cnt_t   = (int*)alloc((size_t)N * 4 * 4);
    int*   row_off = (int*)alloc((size_t)(N + 1) * 4);
    int*   cursor  = (int*)alloc((size_t)N * 4);
    int*   blk     = (int*)alloc(1024);
    int*   csr_pack= (int*)alloc((size_t)E * 4);
    float* wbuf    = (float*)alloc((size_t)E * 4 * 4);    // per-edge weights
    float* aet1    = (float*)alloc(64);
    float* aet2    = (float*)alloc(64);
    unsigned short* bz_fe1 = (unsigned short*)alloc(768 * 64 * 2);
    unsigned short* bz_p1  = (unsigned short*)alloc(64 * 512 * 2);
    unsigned short* bz_p2  = (unsigned short*)alloc(256 * 128 * 2);
    float* C0t     = (float*)alloc(512 * 4);
    float* Tt      = (float*)alloc(3 * 512 * 4);
    float* Pt      = (float*)alloc(512 * 4);

    hipMemsetAsync(cnt_t, 0, (size_t)N * 4 * 4, stream);

    int mb = (N + 63) / 64;   // 782 row-tiles
    int eblk = (E + 255) / 256;
    int nb = (N + 255) / 256;

    k_front<<<705, 256, 0, stream>>>(
        g1_edge_emb, g1_lin_edge, g1_att_edge,
        g2_edge_emb, g2_lin_edge, g2_att_edge, aet1, aet2,
        fe_w1, g2_lin_w, g2_res_w, bz_fe1, bz_p2,
        fe_w2, fe_out_w, fe_b2, fe_pos_b, fe_out_b, fe_type_emb, fe_pos_w,
        g1_lin_w, g1_res_w, g1_bias, g1_res_b, bz_p1, C0t, Tt, Pt,
        dst, etypes, cnt_t, E);
    k_scan1<<<nb, 256, 0, stream>>>(cnt_t, row_off, blk, N);
    k_scan3<<<nb, 256, 0, stream>>>(row_off, cursor, blk, N, E);
    k_fp1<<<mb, 256, 0, stream>>>(
        features, bz_fe1, fe_b1, bz_p1, C0t, Tt, Pt, ntypes, pos,
        g1_att_src, g1_att_dst, xs1b, rp1, a_src1, a_dst1, N);
    k_scatter<<<eblk, 256, 0, stream>>>(src, dst, etypes, cursor, csr_pack,
                                        a_src1, a_dst1, aet1, wbuf, E);
    k_gat1<<<N, 128, 0, stream>>>(xs1b, a_src1, a_dst1, row_off, csr_pack, wbuf,
                                  cnt_t, aet1, g1_ln_g, g1_ln_b, rp1, hid1b);
    k_prep2<<<mb, 256, 0, stream>>>(hid1b, bz_p2, g2_bias, g2_res_b,
                                    g2_att_src, g2_att_dst, xs2b, rp2,
                                    a_src2, a_dst2, N);
    k_gat2<<<(N + 1) / 2, 128, 0, stream>>>(xs2b, a_src2, a_dst2, row_off,
                                            csr_pack, cnt_t, aet2,
                                            g2_ln_g, g2_ln_b, rp2, N);
    k_cls<<<(out_size + 255) / 256, 256, 0, stream>>>(rp2, aspect, cls_w, cls_b,
                                                      (float*)d_out);
}